// Round 8
// baseline (1457.210 us; speedup 1.0000x reference)
//
#include <hip/hip_runtime.h>

// NLCE: non-local (channel attention) + Deep-TEN encoding, B=8 C=512 C1=256 D=128 K=32 N=9216.
// All inputs/outputs fp32. Big GEMMs on matrix cores via 2-limb bf16 split
// (hi/lo via v_cvt_pk_bf16_f32; products hi*hi+hi*lo+lo*hi, ~1e-5 rel).
// Round 8 = re-run of round-7 candidate (container-level bench failure, no data).
// Occupancy attack: BN=128 tiles (LDS 40 KB -> 4 blocks/CU, 16 waves) for ALL MFMA
// GEMMs incl. the small chain; gxxt column-split (128x64, 960 blocks).

typedef unsigned short u16;

#define Bb 8
#define Cc 512
#define C1 256
#define Dd 128
#define Kk 32
#define Nn 9216

typedef __attribute__((ext_vector_type(8))) short short8v;
typedef __attribute__((ext_vector_type(4))) short short4v;
typedef __attribute__((ext_vector_type(4))) float f32x4;

__device__ __forceinline__ float b2f(u16 u) {
  union { unsigned int i; float f; } v; v.i = ((unsigned int)u) << 16; return v.f;
}
__device__ __forceinline__ u16 f2b(float f) {
  union { float f; unsigned int i; } v; v.f = f;
  unsigned int x = v.i;
  return (u16)((x + 0x7fffu + ((x >> 16) & 1u)) >> 16);  // RNE
}

__device__ __forceinline__ float4 load4(const float* p) { return *(const float4*)p; }
__device__ __forceinline__ float4 load4(const u16* p) {
  ushort4 q = *(const ushort4*)p;
  return make_float4(b2f(q.x), b2f(q.y), b2f(q.z), b2f(q.w));
}
__device__ __forceinline__ void store4(float* p, float a, float b, float c, float d) {
  *(float4*)p = make_float4(a, b, c, d);
}

__device__ __forceinline__ float waveSum(float v) {
  #pragma unroll
  for (int o = 32; o > 0; o >>= 1) v += __shfl_xor(v, o);
  return v;
}
__device__ __forceinline__ float waveMax(float v) {
  #pragma unroll
  for (int o = 32; o > 0; o >>= 1) v = fmaxf(v, __shfl_xor(v, o));
  return v;
}
__device__ __forceinline__ float blockSum256(float v) {
  __shared__ float sm[4];
  v = waveSum(v);
  if ((threadIdx.x & 63) == 0) sm[threadIdx.x >> 6] = v;
  __syncthreads();
  float r = sm[0] + sm[1] + sm[2] + sm[3];
  __syncthreads();
  return r;
}
__device__ __forceinline__ float blockMax256(float v) {
  __shared__ float sm[4];
  v = waveMax(v);
  if ((threadIdx.x & 63) == 0) sm[threadIdx.x >> 6] = v;
  __syncthreads();
  float r = fmaxf(fmaxf(sm[0], sm[1]), fmaxf(sm[2], sm[3]));
  __syncthreads();
  return r;
}

// ---------------- MFMA split-bf16 common ----------------
__device__ __forceinline__ f32x4 mfma_bf16_16x16x32(short8v a, short8v b, f32x4 c) {
  asm("v_mfma_f32_16x16x32_bf16 %0, %1, %2, %0" : "+v"(c) : "v"(a), "v"(b));
  return c;
}

__device__ __forceinline__ int fsw(int r) { return (r ^ (r >> 2) ^ (r >> 4)) & 3; }

// 2 floats -> packed bf16 hi limbs (h) and lo limbs (l), 1 cvt_pk each + exact residual
__device__ __forceinline__ void cvt2(float x0, float x1, unsigned int& h, unsigned int& l) {
  asm("v_cvt_pk_bf16_f32 %0, %1, %2" : "=v"(h) : "v"(x0), "v"(x1));
  union { unsigned int u; float f; } fa, fb;
  fa.u = h << 16; fb.u = h & 0xffff0000u;
  float r0 = x0 - fa.f, r1 = x1 - fb.f;
  asm("v_cvt_pk_bf16_f32 %0, %1, %2" : "=v"(l) : "v"(r0), "v"(r1));
}

__device__ __forceinline__ void storeC4(float* p, float4 v) { *(float4*)p = v; }
__device__ __forceinline__ void storeC4(u16* p, float4 v) {
  ushort4 q; q.x = f2b(v.x); q.y = f2b(v.y); q.z = f2b(v.z); q.w = f2b(v.w);
  *(ushort4*)p = q;
}

// ---------------- generic MFMA GEMM (BN=128, 4 blocks/CU) ----------------
// C[b] = A[b] @ B[b]; fp32 in, TO out, 2-limb bf16 MFMA inside.
// BM = 128, BN = 128, BK = 32. 256 threads = 4 waves (2x2), wave tile 64x64.
// OMODE 0: row-major C[M][N], +biasRow[gr]; ADDI adds identity (gr==gc).
// OMODE 1: transposed C[N][128] (requires gny==1, M==128), +biasRow[d].
template<typename TO, int OMODE, bool ADDI>
__global__ __launch_bounds__(256, 4) void gemm_mfma(
    const float* __restrict__ A, const float* __restrict__ B, TO* __restrict__ C,
    int N, int K,
    long long sA, long long sB, long long sC,
    const float* __restrict__ biasRow, long long sBias,
    int gnx, int gny)
{
  // element (row,k) at column ((k>>3) ^ fsw(row))*8 + (k&7); stride 40 ushorts (80 B,
  // multiple of 16 -> b128-aligned frag reads).
  __shared__ __align__(16) u16 Asm_[2][128][40];
  __shared__ __align__(16) u16 Bsm_[2][128][40];

  int id = blockIdx.x;
  {
    const int nwg = gridDim.x;
    if ((nwg & 7) == 0) id = (id & 7) * (nwg >> 3) + (id >> 3);  // XCD chunk swizzle
  }
  const int per = gnx * gny;
  const int b = id / per;
  const int rem = id - b * per;
  const int by = rem % gny;        // m-block fastest
  const int bx = rem / gny;        // n-block
  A += b * sA; B += b * sB; C += b * sC;
  const int m0 = by * 128, n0 = bx * 128;

  const int t = threadIdx.x;
  const int w = t >> 6, lane = t & 63;
  const int wr = w >> 1, wc = w & 1;
  const int lr = lane & 15, lq = lane >> 4;

  const int sar = t >> 1, sak = (t & 1) * 16;   // A staging: 128 rows x 32 k
  const int kg2 = t >> 4, ng = t & 15;          // B staging: 2 k-rows x 8 n per thread

  float ra[16];
  float rb[16];

  auto loadA = [&](int k0) {
    const float* p = A + (long long)(m0 + sar) * K + (k0 + sak);
    #pragma unroll
    for (int i = 0; i < 4; ++i) {
      float4 v = *(const float4*)(p + i * 4);
      ra[i*4+0] = v.x; ra[i*4+1] = v.y; ra[i*4+2] = v.z; ra[i*4+3] = v.w;
    }
  };
  auto loadB = [&](int k0) {
    const float* p = B + (long long)(k0 + kg2 * 2) * N + (n0 + ng * 8);
    #pragma unroll
    for (int i = 0; i < 2; ++i) {
      float4 v0 = *(const float4*)(p + (long long)i * N);
      float4 v1 = *(const float4*)(p + (long long)i * N + 4);
      rb[i*8+0]=v0.x; rb[i*8+1]=v0.y; rb[i*8+2]=v0.z; rb[i*8+3]=v0.w;
      rb[i*8+4]=v1.x; rb[i*8+5]=v1.y; rb[i*8+6]=v1.z; rb[i*8+7]=v1.w;
    }
  };

  auto stage = [&]() {
    {   // A rows sar, k-local sak..sak+15 -> two swizzled 8-blocks
      const int f = fsw(sar);
      #pragma unroll
      for (int h = 0; h < 2; ++h) {
        const int col = ((((sak >> 3) + h) ^ f) << 3);
        union { unsigned int u[4]; short8v v; } H, L;
        #pragma unroll
        for (int p = 0; p < 4; ++p) cvt2(ra[h*8+2*p], ra[h*8+2*p+1], H.u[p], L.u[p]);
        *(short8v*)&Asm_[0][sar][col] = H.v;
        *(short8v*)&Asm_[1][sar][col] = L.v;
      }
    }
    {   // B: 2 consecutive k per n, one u32 write per limb per n
      const int blk = kg2 >> 2, sub = 2 * (kg2 & 3);
      #pragma unroll
      for (int j = 0; j < 8; ++j) {
        const int n = ng * 8 + j;
        const int col = ((blk ^ fsw(n)) << 3) + sub;
        unsigned int H, L;
        cvt2(rb[j], rb[8 + j], H, L);
        *(unsigned int*)&Bsm_[0][n][col] = H;
        *(unsigned int*)&Bsm_[1][n][col] = L;
      }
    }
  };

  f32x4 acc[4][4];
  #pragma unroll
  for (int im = 0; im < 4; ++im)
    #pragma unroll
    for (int in = 0; in < 4; ++in)
      acc[im][in] = f32x4{0.f, 0.f, 0.f, 0.f};

  loadA(0); loadB(0);
  for (int k0 = 0; k0 < K; k0 += 32) {
    stage();
    if (k0 + 32 < K) { loadA(k0 + 32); loadB(k0 + 32); }
    __syncthreads();
    short8v af[2][4];
    #pragma unroll
    for (int im = 0; im < 4; ++im) {
      const int r = wr * 64 + im * 16 + lr;
      const int col = ((lq ^ fsw(r)) << 3);
      af[0][im] = *(const short8v*)&Asm_[0][r][col];
      af[1][im] = *(const short8v*)&Asm_[1][r][col];
    }
    #pragma unroll
    for (int in = 0; in < 4; ++in) {
      const int rB = wc * 64 + in * 16 + lr;
      const int colB = ((lq ^ fsw(rB)) << 3);
      short8v bh = *(const short8v*)&Bsm_[0][rB][colB];
      short8v bl = *(const short8v*)&Bsm_[1][rB][colB];
      #pragma unroll
      for (int im = 0; im < 4; ++im) {
        acc[im][in] = mfma_bf16_16x16x32(af[0][im], bh, acc[im][in]);  // hi*hi
        acc[im][in] = mfma_bf16_16x16x32(af[0][im], bl, acc[im][in]);  // hi*lo
        acc[im][in] = mfma_bf16_16x16x32(af[1][im], bh, acc[im][in]);  // lo*hi
      }
    }
    __syncthreads();
  }
  asm volatile("s_nop 7\n\ts_nop 7\n\ts_nop 7");  // MFMA->VALU/VMEM read hazard guard

  if constexpr (OMODE == 1) {
    // transposed store: C[n][128]; d = wr*64+im*16+lq*4+{0..3} contiguous per lane
    const float* bb = biasRow + (long long)b * sBias;
    #pragma unroll
    for (int im = 0; im < 4; ++im) {
      #pragma unroll
      for (int in = 0; in < 4; ++in) {
        const f32x4 a = acc[im][in];
        const int gc = n0 + wc * 64 + in * 16 + lr;
        const int d0b = wr * 64 + im * 16 + lq * 4;
        float4 v = make_float4(a[0] + bb[d0b + 0], a[1] + bb[d0b + 1],
                               a[2] + bb[d0b + 2], a[3] + bb[d0b + 3]);
        storeC4(&C[(long long)gc * Dd + d0b], v);
      }
    }
  } else {
    #pragma unroll
    for (int im = 0; im < 4; ++im) {
      #pragma unroll
      for (int in = 0; in < 4; ++in) {
        const f32x4 a = acc[im][in];
        const int gc = n0 + wc * 64 + in * 16 + lr;   // C/D: col = lane&15
        #pragma unroll
        for (int p = 0; p < 4; ++p) {
          const int gr = m0 + wr * 64 + im * 16 + lq * 4 + p;  // row = (lane>>4)*4+reg
          float v = a[p];
          if (biasRow) v += biasRow[b * sBias + gr];
          if (ADDI && gr == gc) v += 1.f;
          C[(long long)gr * N + gc] = v;
        }
      }
    }
  }
}

// ---------------- G = X X^T, symmetric, split-K partials (no atomics) --------
// 128x64 blocks: pair selects (i-tile, j-tile), jh selects column half of j-tile.
__device__ __constant__ int PIa[10] = {0,0,0,0,1,1,1,2,2,3};
__device__ __constant__ int PJa[10] = {0,1,2,3,1,2,3,2,3,3};

__global__ __launch_bounds__(256, 4) void gxxt_kernel(
    const float* __restrict__ X, float* __restrict__ part,
    int numKS, int kChunk)
{
  __shared__ __align__(16) u16 Asm_[2][128][40];
  __shared__ __align__(16) u16 Bsm_[2][64][40];

  int id = blockIdx.x;
  {
    const int nwg = gridDim.x;
    if ((nwg & 7) == 0) id = (id & 7) * (nwg >> 3) + (id >> 3);  // one batch per XCD
  }
  const int sub = id % 20;
  const int pair = sub >> 1, jh = sub & 1;
  const int rest = id / 20;
  const int ks = rest % numKS;
  const int b = rest / numKS;
  const int i0 = PIa[pair] * 128, j0 = PJa[pair] * 128;
  const bool same = (i0 == j0);
  const float* Xb = X + (long long)b * Cc * Nn;
  const int kBeg = ks * kChunk, kEnd = kBeg + kChunk;

  const int t = threadIdx.x;
  const int w = t >> 6, lane = t & 63;
  const int wr = w >> 1, wc = w & 1;
  const int lr = lane & 15, lq = lane >> 4;
  const int sar = t >> 1, sak = (t & 1) * 16;   // A: 128 rows x 32 k
  const int sbr = t >> 2, sbk = (t & 3) * 8;    // B: 64 rows x 32 k (8 k per thread)

  float ra[16], rb[8];

  auto loadA = [&](int k0) {
    const float* p = Xb + (long long)(i0 + sar) * Nn + (k0 + sak);
    #pragma unroll
    for (int i = 0; i < 4; ++i) {
      float4 v = *(const float4*)(p + i * 4);
      ra[i*4+0] = v.x; ra[i*4+1] = v.y; ra[i*4+2] = v.z; ra[i*4+3] = v.w;
    }
  };
  auto loadB = [&](int k0) {
    const float* p = Xb + (long long)(j0 + jh * 64 + sbr) * Nn + (k0 + sbk);
    float4 v0 = *(const float4*)(p);
    float4 v1 = *(const float4*)(p + 4);
    rb[0]=v0.x; rb[1]=v0.y; rb[2]=v0.z; rb[3]=v0.w;
    rb[4]=v1.x; rb[5]=v1.y; rb[6]=v1.z; rb[7]=v1.w;
  };
  auto stageA = [&]() {
    const int f = fsw(sar);
    #pragma unroll
    for (int h = 0; h < 2; ++h) {
      const int col = ((((sak >> 3) + h) ^ f) << 3);
      union { unsigned int u[4]; short8v v; } Hv, Lv;
      #pragma unroll
      for (int p = 0; p < 4; ++p) cvt2(ra[h*8+2*p], ra[h*8+2*p+1], Hv.u[p], Lv.u[p]);
      *(short8v*)&Asm_[0][sar][col] = Hv.v;
      *(short8v*)&Asm_[1][sar][col] = Lv.v;
    }
  };
  auto stageB = [&]() {
    const int col = (((sbk >> 3) ^ fsw(sbr)) << 3);
    union { unsigned int u[4]; short8v v; } Hv, Lv;
    #pragma unroll
    for (int p = 0; p < 4; ++p) cvt2(rb[2*p], rb[2*p+1], Hv.u[p], Lv.u[p]);
    *(short8v*)&Bsm_[0][sbr][col] = Hv.v;
    *(short8v*)&Bsm_[1][sbr][col] = Lv.v;
  };

  f32x4 acc[4][2];
  #pragma unroll
  for (int im = 0; im < 4; ++im)
    #pragma unroll
    for (int in = 0; in < 2; ++in)
      acc[im][in] = f32x4{0.f, 0.f, 0.f, 0.f};

  loadA(kBeg);
  if (!same) loadB(kBeg);
  for (int k0 = kBeg; k0 < kEnd; k0 += 32) {
    stageA();
    if (!same) stageB();
    if (k0 + 32 < kEnd) { loadA(k0 + 32); if (!same) loadB(k0 + 32); }
    __syncthreads();
    short8v af[2][4];
    #pragma unroll
    for (int im = 0; im < 4; ++im) {
      const int r = wr * 64 + im * 16 + lr;
      const int col = ((lq ^ fsw(r)) << 3);
      af[0][im] = *(const short8v*)&Asm_[0][r][col];
      af[1][im] = *(const short8v*)&Asm_[1][r][col];
    }
    #pragma unroll
    for (int in = 0; in < 2; ++in) {
      const int rloc = wc * 32 + in * 16 + lr;
      short8v bh, bl;
      if (same) {
        const int r = jh * 64 + rloc;
        const int colB = ((lq ^ fsw(r)) << 3);
        bh = *(const short8v*)&Asm_[0][r][colB];
        bl = *(const short8v*)&Asm_[1][r][colB];
      } else {
        const int colB = ((lq ^ fsw(rloc)) << 3);
        bh = *(const short8v*)&Bsm_[0][rloc][colB];
        bl = *(const short8v*)&Bsm_[1][rloc][colB];
      }
      #pragma unroll
      for (int im = 0; im < 4; ++im) {
        acc[im][in] = mfma_bf16_16x16x32(af[0][im], bh, acc[im][in]);
        acc[im][in] = mfma_bf16_16x16x32(af[0][im], bl, acc[im][in]);
        acc[im][in] = mfma_bf16_16x16x32(af[1][im], bh, acc[im][in]);
      }
    }
    __syncthreads();
  }
  asm volatile("s_nop 7\n\ts_nop 7\n\ts_nop 7");

  float* Cp = part + ((long long)(ks * Bb + b) * 10 + pair) * 16384 + jh * 64;
  #pragma unroll
  for (int im = 0; im < 4; ++im) {
    #pragma unroll
    for (int in = 0; in < 2; ++in) {
      const f32x4 a = acc[im][in];
      const int gc = wc * 32 + in * 16 + lr;
      #pragma unroll
      for (int p = 0; p < 4; ++p) {
        const int gr = wr * 64 + im * 16 + lq * 4 + p;
        Cp[gr * 128 + gc] = a[p];
      }
    }
  }
}

// Reduce partials -> G (both triangles). One block per (b, pair).
__global__ __launch_bounds__(256) void gred_kernel(const float* __restrict__ part,
    float* __restrict__ G, int numKS) {
  __shared__ float sm[64][129];
  const int pair = blockIdx.x % 10, b = blockIdx.x / 10;
  const int i0 = PIa[pair] * 128, j0 = PJa[pair] * 128;
  float* Gb = G + (long long)b * Cc * Cc;
  const long long ksStr = (long long)Bb * 10 * 16384;
  const float* p0 = part + ((long long)b * 10 + pair) * 16384;
  const int t = threadIdx.x;
  for (int half = 0; half < 2; ++half) {
    const int r0 = half * 64;
    __syncthreads();
    for (int rep = 0; rep < 32; ++rep) {
      int idx = r0 * 128 + rep * 256 + t;
      float s = 0.f;
      for (int ks = 0; ks < numKS; ++ks) s += p0[(long long)ks * ksStr + idx];
      int r = (idx >> 7) - r0, c = idx & 127;
      sm[r][c] = s;
      Gb[(long long)(i0 + r0 + r) * Cc + (j0 + c)] = s;
    }
    if (i0 != j0) {
      __syncthreads();
      for (int rep = 0; rep < 32; ++rep) {
        int o = rep * 256 + t;
        int rr = o >> 6, cc = o & 63;
        Gb[(long long)(j0 + rr) * Cc + (i0 + r0 + cc)] = sm[cc][rr];
      }
    }
  }
}

// ---------------- generic 64x64 tiled GEMM, fp32 (L only) ----------------
template<bool TRANSB>
__global__ __launch_bounds__(256) void gemm64(
    const float* __restrict__ A, const float* __restrict__ B, float* __restrict__ C,
    int M, int N, int K,
    long long sA, long long sB, long long sC,
    const float* __restrict__ biasRow, long long sBias)
{
  const int bz = blockIdx.z;
  A += (long long)bz * sA;
  B += (long long)bz * sB;
  C += (long long)bz * sC;
  const int m0 = blockIdx.y * 64, n0 = blockIdx.x * 64;
  __shared__ __align__(16) float As[16][64];
  __shared__ __align__(16) float Bs[16][64];
  const int t = threadIdx.x;
  const int lr = t >> 2, lk = (t & 3) << 2;
  const int tm = (t >> 4) << 2, tn = (t & 15) << 2;
  float acc[4][4] = {};
  for (int k0 = 0; k0 < K; k0 += 16) {
    {
      float4 a = load4(A + (long long)(m0 + lr) * K + (k0 + lk));
      As[lk + 0][lr] = a.x; As[lk + 1][lr] = a.y; As[lk + 2][lr] = a.z; As[lk + 3][lr] = a.w;
    }
    if (TRANSB) {
      float4 b = load4(B + (long long)(n0 + lr) * K + (k0 + lk));
      Bs[lk + 0][lr] = b.x; Bs[lk + 1][lr] = b.y; Bs[lk + 2][lr] = b.z; Bs[lk + 3][lr] = b.w;
    } else {
      const int kr = t >> 4, nc = (t & 15) << 2;
      float4 b = load4(B + (long long)(k0 + kr) * N + (n0 + nc));
      *(float4*)&Bs[kr][nc] = b;
    }
    __syncthreads();
    #pragma unroll
    for (int kk = 0; kk < 16; ++kk) {
      const float4 av = *(const float4*)&As[kk][tm];
      const float4 bv = *(const float4*)&Bs[kk][tn];
      acc[0][0] = fmaf(av.x, bv.x, acc[0][0]);
      acc[0][1] = fmaf(av.x, bv.y, acc[0][1]);
      acc[0][2] = fmaf(av.x, bv.z, acc[0][2]);
      acc[0][3] = fmaf(av.x, bv.w, acc[0][3]);
      acc[1][0] = fmaf(av.y, bv.x, acc[1][0]);
      acc[1][1] = fmaf(av.y, bv.y, acc[1][1]);
      acc[1][2] = fmaf(av.y, bv.z, acc[1][2]);
      acc[1][3] = fmaf(av.y, bv.w, acc[1][3]);
      acc[2][0] = fmaf(av.z, bv.x, acc[2][0]);
      acc[2][1] = fmaf(av.z, bv.y, acc[2][1]);
      acc[2][2] = fmaf(av.z, bv.z, acc[2][2]);
      acc[2][3] = fmaf(av.z, bv.w, acc[2][3]);
      acc[3][0] = fmaf(av.w, bv.x, acc[3][0]);
      acc[3][1] = fmaf(av.w, bv.y, acc[3][1]);
      acc[3][2] = fmaf(av.w, bv.z, acc[3][2]);
      acc[3][3] = fmaf(av.w, bv.w, acc[3][3]);
    }
    __syncthreads();
  }
  #pragma unroll
  for (int i = 0; i < 4; ++i) {
    const int m = m0 + tm + i;
    float bias = biasRow ? biasRow[bz * sBias + m] : 0.f;
    store4(C + (long long)m * N + (n0 + tn),
           acc[i][0] + bias, acc[i][1] + bias, acc[i][2] + bias, acc[i][3] + bias);
  }
}

// ---------------- small kernels ----------------
__global__ __launch_bounds__(256) void rowsum_kernel(const float* __restrict__ X,
                                                     float* __restrict__ s, int N) {
  long long row = blockIdx.x;
  const float* p = X + row * N;
  float acc = 0.f;
  for (int i = threadIdx.x * 4; i < N; i += 1024) {
    float4 v = *(const float4*)(p + i);
    acc += (v.x + v.y) + (v.z + v.w);
  }
  acc = blockSum256(acc);
  if (threadIdx.x == 0) s[row] = acc;
}

// u[b,i] = sum Wth[i,:]*s[b,:]  (sel 0), v[b,i] = sum Wph[i,:]*s[b,:] (sel 1)
__global__ __launch_bounds__(256) void gemv2_kernel(const float* __restrict__ Wth,
    const float* __restrict__ Wph, const float* __restrict__ s,
    float* __restrict__ u, float* __restrict__ v) {
  int b = blockIdx.x & 7, sel = blockIdx.x >> 3;
  const float* W = sel ? Wph : Wth;
  float* out = sel ? v : u;
  __shared__ float ssm[Cc];
  for (int i = threadIdx.x; i < Cc; i += 256) ssm[i] = s[b * Cc + i];
  __syncthreads();
  int i = threadIdx.x;
  const float* wr = W + i * Cc;
  float acc = 0.f;
  for (int k = 0; k < Cc; ++k) acc = fmaf(wr[k], ssm[k], acc);
  out[b * C1 + i] = acc;
}

// softmax over rows of L with bias terms; also emits w[b,i] = sum_j f * bg[j]
__global__ __launch_bounds__(256) void softmax_kernel(float* __restrict__ L,
    const float* __restrict__ bth, const float* __restrict__ bph,
    const float* __restrict__ u, const float* __restrict__ v,
    const float* __restrict__ bg, float* __restrict__ w) {
  __shared__ float bgs[C1];
  int row = blockIdx.x;                 // b*256 + i
  int b = row >> 8, i = row & 255;
  int j = threadIdx.x;
  bgs[j] = bg[j];
  float bt = bth[i], bp = bph[j];
  long long idx = (long long)row * C1 + j;
  float val = L[idx] + bt * v[b * C1 + j] + u[b * C1 + i] * bp + (float)Nn * bt * bp;
  float mx = blockMax256(val);
  float p = expf(val - mx);
  float sm = blockSum256(p);
  float f = p / sm;
  L[idx] = f;
  float ws = blockSum256(f * bgs[j]);
  if (j == 0) w[row] = ws;
}

__global__ __launch_bounds__(256) void q_kernel(const float* __restrict__ W2,
                                                const float* __restrict__ b2v,
                                                const float* __restrict__ w,
                                                float* __restrict__ q) {
  int gi = blockIdx.x * 256 + threadIdx.x;
  int b = gi >> 9, c = gi & 511;
  __shared__ float wsm[C1];
  wsm[threadIdx.x] = w[b * C1 + threadIdx.x];
  __syncthreads();
  const float* wr = W2 + c * C1;
  float acc = b2v[c];
  for (int i = 0; i < C1; ++i) acc = fmaf(wr[i], wsm[i], acc);
  q[gi] = acc;
}

// zqb[b][d] = b3[d] + sum_c W3[d][c] * q[b][c]
__global__ __launch_bounds__(256) void zqbias_kernel(const float* __restrict__ W3,
    const float* __restrict__ b3, const float* __restrict__ q, float* __restrict__ zqb) {
  int gi = blockIdx.x * 256 + threadIdx.x;   // [0, 1024)
  int b = gi >> 7, d = gi & 127;
  const float* wr = W3 + d * Cc;
  const float* qr = q + b * Cc;
  float acc = b3[d];
  for (int c = 0; c < Cc; ++c) acc = fmaf(wr[c], qr[c], acc);
  zqb[gi] = acc;
}

// Deep-TEN soft-assign + aggregation. zq is PIXEL-MAJOR [B][N][D].
// Eraw8/Asum8: 8-slot replicated accumulators (slot = n-tile & 7) to cut atomic contention.
template<typename ZT>
__global__ __launch_bounds__(256) void enc_kernel(
    const ZT* __restrict__ zq,      // [B][N][D]
    const float* __restrict__ cw,   // [K][D]
    const float* __restrict__ sc,   // [K]
    float* __restrict__ Eraw8,      // [8][B][K][D] pre-zeroed
    float* __restrict__ Asum8)      // [8][B][K]    pre-zeroed
{
  __shared__ float csm[Kk][Dd + 1];
  __shared__ float cc[Kk], ssm[Kk];
  __shared__ float sA[Kk][256 + 1];
  __shared__ float zs[16][Dd + 4];
  const int tid = threadIdx.x;
  const int b = blockIdx.y;
  const int slot = blockIdx.x & 7;
  const int n0 = blockIdx.x * 256;

  #pragma unroll
  for (int r = 0; r < 16; ++r) {
    int idx = r * 256 + tid;
    csm[idx >> 7][idx & 127] = cw[idx];
  }
  if (tid < Kk) ssm[tid] = sc[tid];
  __syncthreads();
  if (tid < Kk) {
    float a = 0.f;
    for (int d = 0; d < Dd; ++d) { float cv = csm[tid][d]; a = fmaf(cv, cv, a); }
    cc[tid] = a;
  }
  __syncthreads();

  // pass 1: one pixel per thread, contiguous row read
  const ZT* zrow = zq + ((long long)b * Nn + n0 + tid) * Dd;
  float dots[Kk];
  #pragma unroll
  for (int k = 0; k < Kk; ++k) dots[k] = 0.f;
  float xx = 0.f;
  for (int d = 0; d < Dd; d += 4) {
    float4 xv = load4(zrow + d);
    xx = fmaf(xv.x, xv.x, xx); xx = fmaf(xv.y, xv.y, xx);
    xx = fmaf(xv.z, xv.z, xx); xx = fmaf(xv.w, xv.w, xx);
    #pragma unroll
    for (int k = 0; k < Kk; ++k) {
      float dk = dots[k];
      dk = fmaf(csm[k][d + 0], xv.x, dk);
      dk = fmaf(csm[k][d + 1], xv.y, dk);
      dk = fmaf(csm[k][d + 2], xv.z, dk);
      dk = fmaf(csm[k][d + 3], xv.w, dk);
      dots[k] = dk;
    }
  }
  float mx = -1e30f;
  #pragma unroll
  for (int k = 0; k < Kk; ++k) {
    float l = ssm[k] * (xx - 2.f * dots[k] + cc[k]);
    dots[k] = l;
    mx = fmaxf(mx, l);
  }
  float sum = 0.f;
  #pragma unroll
  for (int k = 0; k < Kk; ++k) { float p = expf(dots[k] - mx); dots[k] = p; sum += p; }
  float inv = 1.f / sum;
  #pragma unroll
  for (int k = 0; k < Kk; ++k) sA[k][tid] = dots[k] * inv;
  __syncthreads();
  if (tid < Kk) {
    float s = 0.f;
    for (int p = 0; p < 256; ++p) s += sA[tid][p];
    atomicAdd(&Asum8[((long long)slot * Bb + b) * Kk + tid], s);
  }

  // pass 2: E_part[k][d0..d0+15] over this tile's 256 pixels (16 px per stage)
  float acc[16];
  #pragma unroll
  for (int j = 0; j < 16; ++j) acc[j] = 0.f;
  const int k = tid & 31, d0 = (tid >> 5) * 16;
  const int spx = tid >> 4, sd = (tid & 15) * 8;   // staging: 16 px x 128 d, coalesced
  for (int it = 0; it < 16; ++it) {
    __syncthreads();
    {
      const ZT* src = zq + ((long long)b * Nn + n0 + it * 16 + spx) * Dd + sd;
      float4 a4 = load4(src);
      float4 b4 = load4(src + 4);
      *(float4*)&zs[spx][sd] = a4;
      *(float4*)&zs[spx][sd + 4] = b4;
    }
    __syncthreads();
    #pragma unroll
    for (int p = 0; p < 16; ++p) {
      float a = sA[k][it * 16 + p];
      #pragma unroll
      for (int j = 0; j < 16; ++j) acc[j] = fmaf(a, zs[p][d0 + j], acc[j]);
    }
  }
  float* Ep = Eraw8 + (((long long)slot * Bb + b) * Kk + k) * Dd + d0;
  #pragma unroll
  for (int j = 0; j < 16; ++j) atomicAdd(Ep + j, acc[j]);
}

// per-k BN over (b,d) with 8-slot reduction, relu, Es[b,d] += e
__global__ __launch_bounds__(256) void bn_kernel(const float* __restrict__ Eraw8,
    const float* __restrict__ Asum8, const float* __restrict__ cw, float* __restrict__ Es) {
  __shared__ float sas[8];
  int k = blockIdx.x, tid = threadIdx.x;
  if (tid < 8) {
    float a = 0.f;
    for (int sl = 0; sl < 8; ++sl) a += Asum8[((long long)sl * Bb + tid) * Kk + k];
    sas[tid] = a;
  }
  __syncthreads();
  float vals[4], s = 0.f, s2 = 0.f;
  #pragma unroll
  for (int r = 0; r < 4; ++r) {
    int i = r * 256 + tid;
    int b = i >> 7, d = i & 127;
    float e = 0.f;
    for (int sl = 0; sl < 8; ++sl)
      e += Eraw8[(((long long)sl * Bb + b) * Kk + k) * Dd + d];
    e -= sas[b] * cw[k * Dd + d];
    vals[r] = e; s += e; s2 = fmaf(e, e, s2);
  }
  s = blockSum256(s);
  s2 = blockSum256(s2);
  float mean = s * (1.f / 1024.f);
  float var = fmaxf(s2 * (1.f / 1024.f) - mean * mean, 0.f);
  float rs = rsqrtf(var + 1e-5f);
  #pragma unroll
  for (int r = 0; r < 4; ++r) {
    int i = r * 256 + tid;
    int b = i >> 7, d = i & 127;
    float e = (vals[r] - mean) * rs;
    if (e > 0.f) atomicAdd(&Es[b * Dd + d], e);
  }
}

// gamma = sigmoid(Es @ Wfc^T + bfc); also folds gamma into q (q <- q*gamma)
__global__ __launch_bounds__(256) void gamma_kernel(const float* __restrict__ Es,
    const float* __restrict__ Wfc, const float* __restrict__ bfc,
    float* __restrict__ gam, float* __restrict__ q) {
  int gi = blockIdx.x * 256 + threadIdx.x;
  int b = gi >> 9, c = gi & 511;
  __shared__ float esm[Dd];
  if (threadIdx.x < Dd) esm[threadIdx.x] = Es[b * Dd + threadIdx.x];
  __syncthreads();
  const float* wr = Wfc + c * Dd;
  float acc = bfc[c];
  for (int d = 0; d < Dd; ++d) acc = fmaf(wr[d], esm[d], acc);
  float g = 1.f / (1.f + expf(-acc));
  gam[gi] = g;
  q[gi] *= g;
}

// P[b][c][:] *= gam[b][c]  (fold output scale into the GEMM A-operand)
__global__ __launch_bounds__(256) void scaleP_kernel(float* __restrict__ P,
    const float* __restrict__ gam) {
  long long f = ((long long)blockIdx.x * 256 + threadIdx.x) * 4;  // 8*512*512 total
  int b = (int)(f >> 18), c = (int)((f >> 9) & 511);
  float g = gam[b * Cc + c];
  float4 v = *(const float4*)(P + f);
  store4(P + f, v.x * g, v.y * g, v.z * g, v.w * g);
}

// ---------------- host launcher ----------------
extern "C" void kernel_launch(void* const* d_in, const int* in_sizes, int n_in,
                              void* d_out, int out_size, void* d_ws, size_t ws_size,
                              hipStream_t stream) {
  const float* X   = (const float*)d_in[0];
  const float* Wth = (const float*)d_in[1];
  const float* bth = (const float*)d_in[2];
  const float* Wph = (const float*)d_in[3];
  const float* bph = (const float*)d_in[4];
  const float* Wg  = (const float*)d_in[5];
  const float* bg  = (const float*)d_in[6];
  const float* W2  = (const float*)d_in[7];
  const float* b2v = (const float*)d_in[8];
  const float* W3  = (const float*)d_in[9];
  const float* b3v = (const float*)d_in[10];
  const float* CW  = (const float*)d_in[11];
  const float* SC  = (const float*)d_in[12];
  const float* Wfc = (const float*)d_in[13];
  const float* bfc = (const float*)d_in[14];
  float* out = (float*)d_out;
  float* wsf = (float*)d_ws;

  const long long szL   = (long long)Bb * C1 * C1;   // 524288
  const long long szRA  = (long long)Bb * Cc * Cc;   // 2097152
  const long long szRB  = (long long)Bb * C1 * Cc;   // 1048576
  long long off = 0;
  float* s_   = wsf + off; off += Bb * Cc;
  float* u_   = wsf + off; off += Bb * C1;
  float* v_   = wsf + off; off += Bb * C1;
  float* w_   = wsf + off; off += Bb * C1;
  float* q_   = wsf + off; off += Bb * Cc;
  float* Eraw_= wsf + off; off += (long long)Bb * Kk * Dd;   // legacy slot (unused)
  float* Es_  = wsf + off; off += Bb * Dd;
  float* Asum_= wsf + off; off += Bb * Kk;                   // legacy slot (unused)
  float* gam_ = wsf + off; off += Bb * Cc;
  float* L_   = wsf + off; off += szL;
  float* regA = wsf + off; off += szRA;
  float* regB = wsf + off; off += szRB;
  const long long baseFloats = off;
  // tail region: G split-K partials, later aliased by zq (pixel-major [B][N][D])
  float* tail = wsf + off;
  const long long ZQ_F  = (long long)Bb * Dd * Nn;      // 9437184
  const long long tailFloats = (long long)(ws_size / 4) - baseFloats;
  const bool big = tailFloats >= ZQ_F;    // big: fp32 zq + splitK=6; small: bf16 zq + splitK=2
  const int numKS = big ? 6 : 2;          // partials: numKS*8*10*16384 floats (7.9M / 2.6M)
  float* part = tail;
  float* zqf  = tail;
  u16*   zqh  = (u16*)tail;
  float* R_   = L_;     // alias: f dead after Mm-GEMM; R born after P-GEMM
  float* zqb_ = u_;     // alias: u dead after softmax
  float* E8_  = regB;                       // 8*8*32*128 = 262144 floats (regB dead post-P)
  float* A8_  = regB + 262144;              // 8*8*32 = 2048 floats
  (void)Eraw_; (void)Asum_;

  const long long strX = (long long)Cc * Nn;
  const long long sG = (long long)Cc * Cc;
  const long long sU = (long long)C1 * Cc;
  const long long sL = (long long)C1 * C1;
  const long long sR = (long long)Dd * Cc;

  rowsum_kernel<<<Bb * Cc, 256, 0, stream>>>(X, s_, Nn);
  // G = X X^T (symmetric): 128x64 tile-pair-half partials -> reduce into regA
  gxxt_kernel<<<dim3(20 * numKS * Bb), 256, 0, stream>>>(X, part, numKS, Nn / numKS);
  gred_kernel<<<dim3(10 * Bb), 256, 0, stream>>>(part, regA, numKS);
  // U = Wth @ G -> regB  (M=256 N=512 K=512)
  gemm_mfma<float, 0, false><<<dim3(64), 256, 0, stream>>>(
      Wth, regA, regB, Cc, Cc, 0, sG, sU, nullptr, 0, 4, 2);
  gemv2_kernel<<<16, 256, 0, stream>>>(Wth, Wph, s_, u_, v_);
  // L = U @ Wph^T  (small, fp32)
  gemm64<true><<<dim3(4, 4, Bb), 256, 0, stream>>>(
      regB, Wph, L_, C1, C1, Cc, sU, 0, sL, nullptr, 0);
  softmax_kernel<<<Bb * C1, 256, 0, stream>>>(L_, bth, bph, u_, v_, bg, w_);
  // Mm = f @ Wg -> regB (U dead)  (M=256 N=512 K=256)
  gemm_mfma<float, 0, false><<<dim3(64), 256, 0, stream>>>(
      L_, Wg, regB, Cc, C1, sL, 0, sU, nullptr, 0, 4, 2);
  q_kernel<<<16, 256, 0, stream>>>(W2, b2v, w_, q_);
  // P' = W2 @ Mm + I -> regA (G dead; identity fused in epilogue)
  gemm_mfma<float, 0, true><<<dim3(128), 256, 0, stream>>>(
      W2, regB, regA, Cc, C1, 0, sU, sG, nullptr, 0, 4, 4);
  // regB dead: becomes 8-slot enc accumulators
  hipMemsetAsync(regB, 0, (size_t)(262144 + 2048) * 4, stream);
  hipMemsetAsync(Es_, 0, (size_t)(Bb * Dd) * 4, stream);
  // R = W3 @ P' -> R_ (alias L_)  (M=128 N=512 K=512) ; zq bias = W3 q + b3
  gemm_mfma<float, 0, false><<<dim3(32), 256, 0, stream>>>(
      W3, regA, R_, Cc, Cc, 0, sG, sR, nullptr, 0, 4, 1);
  zqbias_kernel<<<4, 256, 0, stream>>>(W3, b3v, q_, zqb_);
  // zq = R @ X + zqb, stored pixel-major [B][N][D]  (partials dead -> tail reused)
  if (big) {
    gemm_mfma<float, 1, false><<<dim3(576), 256, 0, stream>>>(
        R_, X, zqf, Nn, Cc, sR, strX, (long long)Dd * Nn, zqb_, Dd, 72, 1);
    enc_kernel<float><<<dim3(36, Bb), 256, 0, stream>>>(zqf, CW, SC, E8_, A8_);
  } else {
    gemm_mfma<u16, 1, false><<<dim3(576), 256, 0, stream>>>(
        R_, X, zqh, Nn, Cc, sR, strX, (long long)Dd * Nn, zqb_, Dd, 72, 1);
    enc_kernel<u16><<<dim3(36, Bb), 256, 0, stream>>>(zqh, CW, SC, E8_, A8_);
  }
  bn_kernel<<<Kk, 256, 0, stream>>>(E8_, A8_, CW, Es_);
  gamma_kernel<<<16, 256, 0, stream>>>(Es_, Wfc, bfc, gam_, q_);   // q <- q*gamma
  // fold gamma into P' rows, then z*gamma = (gamma.P') @ X + (gamma.q) -> out
  scaleP_kernel<<<2048, 256, 0, stream>>>(regA, gam_);
  gemm_mfma<float, 0, false><<<dim3(2304), 256, 0, stream>>>(
      regA, X, out, Nn, Cc, sG, strX, strX, q_, Cc, 72, 4);
  (void)in_sizes; (void)n_in; (void)out_size;
}

// Round 9
// 957.792 us; speedup vs baseline: 1.5214x; 1.5214x over previous
//
#include <hip/hip_runtime.h>

// NLCE: non-local (channel attention) + Deep-TEN encoding, B=8 C=512 C1=256 D=128 K=32 N=9216.
// All inputs/outputs fp32. Big GEMMs on matrix cores via 2-limb bf16 split
// (hi/lo via v_cvt_pk_bf16_f32; products hi*hi+hi*lo+lo*hi, ~1e-5 rel).
// Round 9: round-8 tiles (BN=128, LDS 40 KB) with launch_bounds(256,3) — cap 170
// regs/wave fits the ~165 need (64 acc AGPR + ~100 VGPR); round 8's (256,4)=128-reg
// cap spilled staging regs to scratch (VGPR_Count 64, WRITE 610 MB, 443 us).

typedef unsigned short u16;

#define Bb 8
#define Cc 512
#define C1 256
#define Dd 128
#define Kk 32
#define Nn 9216

typedef __attribute__((ext_vector_type(8))) short short8v;
typedef __attribute__((ext_vector_type(4))) short short4v;
typedef __attribute__((ext_vector_type(4))) float f32x4;

__device__ __forceinline__ float b2f(u16 u) {
  union { unsigned int i; float f; } v; v.i = ((unsigned int)u) << 16; return v.f;
}
__device__ __forceinline__ u16 f2b(float f) {
  union { float f; unsigned int i; } v; v.f = f;
  unsigned int x = v.i;
  return (u16)((x + 0x7fffu + ((x >> 16) & 1u)) >> 16);  // RNE
}

__device__ __forceinline__ float4 load4(const float* p) { return *(const float4*)p; }
__device__ __forceinline__ float4 load4(const u16* p) {
  ushort4 q = *(const ushort4*)p;
  return make_float4(b2f(q.x), b2f(q.y), b2f(q.z), b2f(q.w));
}
__device__ __forceinline__ void store4(float* p, float a, float b, float c, float d) {
  *(float4*)p = make_float4(a, b, c, d);
}

__device__ __forceinline__ float waveSum(float v) {
  #pragma unroll
  for (int o = 32; o > 0; o >>= 1) v += __shfl_xor(v, o);
  return v;
}
__device__ __forceinline__ float waveMax(float v) {
  #pragma unroll
  for (int o = 32; o > 0; o >>= 1) v = fmaxf(v, __shfl_xor(v, o));
  return v;
}
__device__ __forceinline__ float blockSum256(float v) {
  __shared__ float sm[4];
  v = waveSum(v);
  if ((threadIdx.x & 63) == 0) sm[threadIdx.x >> 6] = v;
  __syncthreads();
  float r = sm[0] + sm[1] + sm[2] + sm[3];
  __syncthreads();
  return r;
}
__device__ __forceinline__ float blockMax256(float v) {
  __shared__ float sm[4];
  v = waveMax(v);
  if ((threadIdx.x & 63) == 0) sm[threadIdx.x >> 6] = v;
  __syncthreads();
  float r = fmaxf(fmaxf(sm[0], sm[1]), fmaxf(sm[2], sm[3]));
  __syncthreads();
  return r;
}

// ---------------- MFMA split-bf16 common ----------------
__device__ __forceinline__ f32x4 mfma_bf16_16x16x32(short8v a, short8v b, f32x4 c) {
  asm("v_mfma_f32_16x16x32_bf16 %0, %1, %2, %0" : "+v"(c) : "v"(a), "v"(b));
  return c;
}

__device__ __forceinline__ int fsw(int r) { return (r ^ (r >> 2) ^ (r >> 4)) & 3; }

// 2 floats -> packed bf16 hi limbs (h) and lo limbs (l), 1 cvt_pk each + exact residual
__device__ __forceinline__ void cvt2(float x0, float x1, unsigned int& h, unsigned int& l) {
  asm("v_cvt_pk_bf16_f32 %0, %1, %2" : "=v"(h) : "v"(x0), "v"(x1));
  union { unsigned int u; float f; } fa, fb;
  fa.u = h << 16; fb.u = h & 0xffff0000u;
  float r0 = x0 - fa.f, r1 = x1 - fb.f;
  asm("v_cvt_pk_bf16_f32 %0, %1, %2" : "=v"(l) : "v"(r0), "v"(r1));
}

__device__ __forceinline__ void storeC4(float* p, float4 v) { *(float4*)p = v; }
__device__ __forceinline__ void storeC4(u16* p, float4 v) {
  ushort4 q; q.x = f2b(v.x); q.y = f2b(v.y); q.z = f2b(v.z); q.w = f2b(v.w);
  *(ushort4*)p = q;
}

// ---------------- generic MFMA GEMM (BN=128) ----------------
// C[b] = A[b] @ B[b]; fp32 in, TO out, 2-limb bf16 MFMA inside.
// BM = 128, BN = 128, BK = 32. 256 threads = 4 waves (2x2), wave tile 64x64.
// OMODE 0: row-major C[M][N], +biasRow[gr]; ADDI adds identity (gr==gc).
// OMODE 1: transposed C[N][128] (requires gny==1, M==128), +biasRow[d].
template<typename TO, int OMODE, bool ADDI>
__global__ __launch_bounds__(256, 3) void gemm_mfma(
    const float* __restrict__ A, const float* __restrict__ B, TO* __restrict__ C,
    int N, int K,
    long long sA, long long sB, long long sC,
    const float* __restrict__ biasRow, long long sBias,
    int gnx, int gny)
{
  // element (row,k) at column ((k>>3) ^ fsw(row))*8 + (k&7); stride 40 ushorts (80 B,
  // multiple of 16 -> b128-aligned frag reads).
  __shared__ __align__(16) u16 Asm_[2][128][40];
  __shared__ __align__(16) u16 Bsm_[2][128][40];

  int id = blockIdx.x;
  {
    const int nwg = gridDim.x;
    if ((nwg & 7) == 0) id = (id & 7) * (nwg >> 3) + (id >> 3);  // XCD chunk swizzle
  }
  const int per = gnx * gny;
  const int b = id / per;
  const int rem = id - b * per;
  const int by = rem % gny;        // m-block fastest
  const int bx = rem / gny;        // n-block
  A += b * sA; B += b * sB; C += b * sC;
  const int m0 = by * 128, n0 = bx * 128;

  const int t = threadIdx.x;
  const int w = t >> 6, lane = t & 63;
  const int wr = w >> 1, wc = w & 1;
  const int lr = lane & 15, lq = lane >> 4;

  const int sar = t >> 1, sak = (t & 1) * 16;   // A staging: 128 rows x 32 k
  const int kg2 = t >> 4, ng = t & 15;          // B staging: 2 k-rows x 8 n per thread

  float ra[16];
  float rb[16];

  auto loadA = [&](int k0) {
    const float* p = A + (long long)(m0 + sar) * K + (k0 + sak);
    #pragma unroll
    for (int i = 0; i < 4; ++i) {
      float4 v = *(const float4*)(p + i * 4);
      ra[i*4+0] = v.x; ra[i*4+1] = v.y; ra[i*4+2] = v.z; ra[i*4+3] = v.w;
    }
  };
  auto loadB = [&](int k0) {
    const float* p = B + (long long)(k0 + kg2 * 2) * N + (n0 + ng * 8);
    #pragma unroll
    for (int i = 0; i < 2; ++i) {
      float4 v0 = *(const float4*)(p + (long long)i * N);
      float4 v1 = *(const float4*)(p + (long long)i * N + 4);
      rb[i*8+0]=v0.x; rb[i*8+1]=v0.y; rb[i*8+2]=v0.z; rb[i*8+3]=v0.w;
      rb[i*8+4]=v1.x; rb[i*8+5]=v1.y; rb[i*8+6]=v1.z; rb[i*8+7]=v1.w;
    }
  };

  auto stage = [&]() {
    {   // A rows sar, k-local sak..sak+15 -> two swizzled 8-blocks
      const int f = fsw(sar);
      #pragma unroll
      for (int h = 0; h < 2; ++h) {
        const int col = ((((sak >> 3) + h) ^ f) << 3);
        union { unsigned int u[4]; short8v v; } H, L;
        #pragma unroll
        for (int p = 0; p < 4; ++p) cvt2(ra[h*8+2*p], ra[h*8+2*p+1], H.u[p], L.u[p]);
        *(short8v*)&Asm_[0][sar][col] = H.v;
        *(short8v*)&Asm_[1][sar][col] = L.v;
      }
    }
    {   // B: 2 consecutive k per n, one u32 write per limb per n
      const int blk = kg2 >> 2, sub = 2 * (kg2 & 3);
      #pragma unroll
      for (int j = 0; j < 8; ++j) {
        const int n = ng * 8 + j;
        const int col = ((blk ^ fsw(n)) << 3) + sub;
        unsigned int H, L;
        cvt2(rb[j], rb[8 + j], H, L);
        *(unsigned int*)&Bsm_[0][n][col] = H;
        *(unsigned int*)&Bsm_[1][n][col] = L;
      }
    }
  };

  f32x4 acc[4][4];
  #pragma unroll
  for (int im = 0; im < 4; ++im)
    #pragma unroll
    for (int in = 0; in < 4; ++in)
      acc[im][in] = f32x4{0.f, 0.f, 0.f, 0.f};

  loadA(0); loadB(0);
  for (int k0 = 0; k0 < K; k0 += 32) {
    stage();
    if (k0 + 32 < K) { loadA(k0 + 32); loadB(k0 + 32); }
    __syncthreads();
    short8v af[2][4];
    #pragma unroll
    for (int im = 0; im < 4; ++im) {
      const int r = wr * 64 + im * 16 + lr;
      const int col = ((lq ^ fsw(r)) << 3);
      af[0][im] = *(const short8v*)&Asm_[0][r][col];
      af[1][im] = *(const short8v*)&Asm_[1][r][col];
    }
    #pragma unroll
    for (int in = 0; in < 4; ++in) {
      const int rB = wc * 64 + in * 16 + lr;
      const int colB = ((lq ^ fsw(rB)) << 3);
      short8v bh = *(const short8v*)&Bsm_[0][rB][colB];
      short8v bl = *(const short8v*)&Bsm_[1][rB][colB];
      #pragma unroll
      for (int im = 0; im < 4; ++im) {
        acc[im][in] = mfma_bf16_16x16x32(af[0][im], bh, acc[im][in]);  // hi*hi
        acc[im][in] = mfma_bf16_16x16x32(af[0][im], bl, acc[im][in]);  // hi*lo
        acc[im][in] = mfma_bf16_16x16x32(af[1][im], bh, acc[im][in]);  // lo*hi
      }
    }
    __syncthreads();
  }
  asm volatile("s_nop 7\n\ts_nop 7\n\ts_nop 7");  // MFMA->VALU/VMEM read hazard guard

  if constexpr (OMODE == 1) {
    // transposed store: C[n][128]; d = wr*64+im*16+lq*4+{0..3} contiguous per lane
    const float* bb = biasRow + (long long)b * sBias;
    #pragma unroll
    for (int im = 0; im < 4; ++im) {
      #pragma unroll
      for (int in = 0; in < 4; ++in) {
        const f32x4 a = acc[im][in];
        const int gc = n0 + wc * 64 + in * 16 + lr;
        const int d0b = wr * 64 + im * 16 + lq * 4;
        float4 v = make_float4(a[0] + bb[d0b + 0], a[1] + bb[d0b + 1],
                               a[2] + bb[d0b + 2], a[3] + bb[d0b + 3]);
        storeC4(&C[(long long)gc * Dd + d0b], v);
      }
    }
  } else {
    #pragma unroll
    for (int im = 0; im < 4; ++im) {
      #pragma unroll
      for (int in = 0; in < 4; ++in) {
        const f32x4 a = acc[im][in];
        const int gc = n0 + wc * 64 + in * 16 + lr;   // C/D: col = lane&15
        #pragma unroll
        for (int p = 0; p < 4; ++p) {
          const int gr = m0 + wr * 64 + im * 16 + lq * 4 + p;  // row = (lane>>4)*4+reg
          float v = a[p];
          if (biasRow) v += biasRow[b * sBias + gr];
          if (ADDI && gr == gc) v += 1.f;
          C[(long long)gr * N + gc] = v;
        }
      }
    }
  }
}

// ---------------- G = X X^T, symmetric, split-K partials (no atomics) --------
// 128x64 blocks: pair selects (i-tile, j-tile), jh selects column half of j-tile.
__device__ __constant__ int PIa[10] = {0,0,0,0,1,1,1,2,2,3};
__device__ __constant__ int PJa[10] = {0,1,2,3,1,2,3,2,3,3};

__global__ __launch_bounds__(256, 3) void gxxt_kernel(
    const float* __restrict__ X, float* __restrict__ part,
    int numKS, int kChunk)
{
  __shared__ __align__(16) u16 Asm_[2][128][40];
  __shared__ __align__(16) u16 Bsm_[2][64][40];

  int id = blockIdx.x;
  {
    const int nwg = gridDim.x;
    if ((nwg & 7) == 0) id = (id & 7) * (nwg >> 3) + (id >> 3);  // one batch per XCD
  }
  const int sub = id % 20;
  const int pair = sub >> 1, jh = sub & 1;
  const int rest = id / 20;
  const int ks = rest % numKS;
  const int b = rest / numKS;
  const int i0 = PIa[pair] * 128, j0 = PJa[pair] * 128;
  const bool same = (i0 == j0);
  const float* Xb = X + (long long)b * Cc * Nn;
  const int kBeg = ks * kChunk, kEnd = kBeg + kChunk;

  const int t = threadIdx.x;
  const int w = t >> 6, lane = t & 63;
  const int wr = w >> 1, wc = w & 1;
  const int lr = lane & 15, lq = lane >> 4;
  const int sar = t >> 1, sak = (t & 1) * 16;   // A: 128 rows x 32 k
  const int sbr = t >> 2, sbk = (t & 3) * 8;    // B: 64 rows x 32 k (8 k per thread)

  float ra[16], rb[8];

  auto loadA = [&](int k0) {
    const float* p = Xb + (long long)(i0 + sar) * Nn + (k0 + sak);
    #pragma unroll
    for (int i = 0; i < 4; ++i) {
      float4 v = *(const float4*)(p + i * 4);
      ra[i*4+0] = v.x; ra[i*4+1] = v.y; ra[i*4+2] = v.z; ra[i*4+3] = v.w;
    }
  };
  auto loadB = [&](int k0) {
    const float* p = Xb + (long long)(j0 + jh * 64 + sbr) * Nn + (k0 + sbk);
    float4 v0 = *(const float4*)(p);
    float4 v1 = *(const float4*)(p + 4);
    rb[0]=v0.x; rb[1]=v0.y; rb[2]=v0.z; rb[3]=v0.w;
    rb[4]=v1.x; rb[5]=v1.y; rb[6]=v1.z; rb[7]=v1.w;
  };
  auto stageA = [&]() {
    const int f = fsw(sar);
    #pragma unroll
    for (int h = 0; h < 2; ++h) {
      const int col = ((((sak >> 3) + h) ^ f) << 3);
      union { unsigned int u[4]; short8v v; } Hv, Lv;
      #pragma unroll
      for (int p = 0; p < 4; ++p) cvt2(ra[h*8+2*p], ra[h*8+2*p+1], Hv.u[p], Lv.u[p]);
      *(short8v*)&Asm_[0][sar][col] = Hv.v;
      *(short8v*)&Asm_[1][sar][col] = Lv.v;
    }
  };
  auto stageB = [&]() {
    const int col = (((sbk >> 3) ^ fsw(sbr)) << 3);
    union { unsigned int u[4]; short8v v; } Hv, Lv;
    #pragma unroll
    for (int p = 0; p < 4; ++p) cvt2(rb[2*p], rb[2*p+1], Hv.u[p], Lv.u[p]);
    *(short8v*)&Bsm_[0][sbr][col] = Hv.v;
    *(short8v*)&Bsm_[1][sbr][col] = Lv.v;
  };

  f32x4 acc[4][2];
  #pragma unroll
  for (int im = 0; im < 4; ++im)
    #pragma unroll
    for (int in = 0; in < 2; ++in)
      acc[im][in] = f32x4{0.f, 0.f, 0.f, 0.f};

  loadA(kBeg);
  if (!same) loadB(kBeg);
  for (int k0 = kBeg; k0 < kEnd; k0 += 32) {
    stageA();
    if (!same) stageB();
    if (k0 + 32 < kEnd) { loadA(k0 + 32); if (!same) loadB(k0 + 32); }
    __syncthreads();
    short8v af[2][4];
    #pragma unroll
    for (int im = 0; im < 4; ++im) {
      const int r = wr * 64 + im * 16 + lr;
      const int col = ((lq ^ fsw(r)) << 3);
      af[0][im] = *(const short8v*)&Asm_[0][r][col];
      af[1][im] = *(const short8v*)&Asm_[1][r][col];
    }
    #pragma unroll
    for (int in = 0; in < 2; ++in) {
      const int rloc = wc * 32 + in * 16 + lr;
      short8v bh, bl;
      if (same) {
        const int r = jh * 64 + rloc;
        const int colB = ((lq ^ fsw(r)) << 3);
        bh = *(const short8v*)&Asm_[0][r][colB];
        bl = *(const short8v*)&Asm_[1][r][colB];
      } else {
        const int colB = ((lq ^ fsw(rloc)) << 3);
        bh = *(const short8v*)&Bsm_[0][rloc][colB];
        bl = *(const short8v*)&Bsm_[1][rloc][colB];
      }
      #pragma unroll
      for (int im = 0; im < 4; ++im) {
        acc[im][in] = mfma_bf16_16x16x32(af[0][im], bh, acc[im][in]);
        acc[im][in] = mfma_bf16_16x16x32(af[0][im], bl, acc[im][in]);
        acc[im][in] = mfma_bf16_16x16x32(af[1][im], bh, acc[im][in]);
      }
    }
    __syncthreads();
  }
  asm volatile("s_nop 7\n\ts_nop 7\n\ts_nop 7");

  float* Cp = part + ((long long)(ks * Bb + b) * 10 + pair) * 16384 + jh * 64;
  #pragma unroll
  for (int im = 0; im < 4; ++im) {
    #pragma unroll
    for (int in = 0; in < 2; ++in) {
      const f32x4 a = acc[im][in];
      const int gc = wc * 32 + in * 16 + lr;
      #pragma unroll
      for (int p = 0; p < 4; ++p) {
        const int gr = wr * 64 + im * 16 + lq * 4 + p;
        Cp[gr * 128 + gc] = a[p];
      }
    }
  }
}

// Reduce partials -> G (both triangles). One block per (b, pair).
__global__ __launch_bounds__(256) void gred_kernel(const float* __restrict__ part,
    float* __restrict__ G, int numKS) {
  __shared__ float sm[64][129];
  const int pair = blockIdx.x % 10, b = blockIdx.x / 10;
  const int i0 = PIa[pair] * 128, j0 = PJa[pair] * 128;
  float* Gb = G + (long long)b * Cc * Cc;
  const long long ksStr = (long long)Bb * 10 * 16384;
  const float* p0 = part + ((long long)b * 10 + pair) * 16384;
  const int t = threadIdx.x;
  for (int half = 0; half < 2; ++half) {
    const int r0 = half * 64;
    __syncthreads();
    for (int rep = 0; rep < 32; ++rep) {
      int idx = r0 * 128 + rep * 256 + t;
      float s = 0.f;
      for (int ks = 0; ks < numKS; ++ks) s += p0[(long long)ks * ksStr + idx];
      int r = (idx >> 7) - r0, c = idx & 127;
      sm[r][c] = s;
      Gb[(long long)(i0 + r0 + r) * Cc + (j0 + c)] = s;
    }
    if (i0 != j0) {
      __syncthreads();
      for (int rep = 0; rep < 32; ++rep) {
        int o = rep * 256 + t;
        int rr = o >> 6, cc = o & 63;
        Gb[(long long)(j0 + rr) * Cc + (i0 + r0 + cc)] = sm[cc][rr];
      }
    }
  }
}

// ---------------- generic 64x64 tiled GEMM, fp32 (L only) ----------------
template<bool TRANSB>
__global__ __launch_bounds__(256) void gemm64(
    const float* __restrict__ A, const float* __restrict__ B, float* __restrict__ C,
    int M, int N, int K,
    long long sA, long long sB, long long sC,
    const float* __restrict__ biasRow, long long sBias)
{
  const int bz = blockIdx.z;
  A += (long long)bz * sA;
  B += (long long)bz * sB;
  C += (long long)bz * sC;
  const int m0 = blockIdx.y * 64, n0 = blockIdx.x * 64;
  __shared__ __align__(16) float As[16][64];
  __shared__ __align__(16) float Bs[16][64];
  const int t = threadIdx.x;
  const int lr = t >> 2, lk = (t & 3) << 2;
  const int tm = (t >> 4) << 2, tn = (t & 15) << 2;
  float acc[4][4] = {};
  for (int k0 = 0; k0 < K; k0 += 16) {
    {
      float4 a = load4(A + (long long)(m0 + lr) * K + (k0 + lk));
      As[lk + 0][lr] = a.x; As[lk + 1][lr] = a.y; As[lk + 2][lr] = a.z; As[lk + 3][lr] = a.w;
    }
    if (TRANSB) {
      float4 b = load4(B + (long long)(n0 + lr) * K + (k0 + lk));
      Bs[lk + 0][lr] = b.x; Bs[lk + 1][lr] = b.y; Bs[lk + 2][lr] = b.z; Bs[lk + 3][lr] = b.w;
    } else {
      const int kr = t >> 4, nc = (t & 15) << 2;
      float4 b = load4(B + (long long)(k0 + kr) * N + (n0 + nc));
      *(float4*)&Bs[kr][nc] = b;
    }
    __syncthreads();
    #pragma unroll
    for (int kk = 0; kk < 16; ++kk) {
      const float4 av = *(const float4*)&As[kk][tm];
      const float4 bv = *(const float4*)&Bs[kk][tn];
      acc[0][0] = fmaf(av.x, bv.x, acc[0][0]);
      acc[0][1] = fmaf(av.x, bv.y, acc[0][1]);
      acc[0][2] = fmaf(av.x, bv.z, acc[0][2]);
      acc[0][3] = fmaf(av.x, bv.w, acc[0][3]);
      acc[1][0] = fmaf(av.y, bv.x, acc[1][0]);
      acc[1][1] = fmaf(av.y, bv.y, acc[1][1]);
      acc[1][2] = fmaf(av.y, bv.z, acc[1][2]);
      acc[1][3] = fmaf(av.y, bv.w, acc[1][3]);
      acc[2][0] = fmaf(av.z, bv.x, acc[2][0]);
      acc[2][1] = fmaf(av.z, bv.y, acc[2][1]);
      acc[2][2] = fmaf(av.z, bv.z, acc[2][2]);
      acc[2][3] = fmaf(av.z, bv.w, acc[2][3]);
      acc[3][0] = fmaf(av.w, bv.x, acc[3][0]);
      acc[3][1] = fmaf(av.w, bv.y, acc[3][1]);
      acc[3][2] = fmaf(av.w, bv.z, acc[3][2]);
      acc[3][3] = fmaf(av.w, bv.w, acc[3][3]);
    }
    __syncthreads();
  }
  #pragma unroll
  for (int i = 0; i < 4; ++i) {
    const int m = m0 + tm + i;
    float bias = biasRow ? biasRow[bz * sBias + m] : 0.f;
    store4(C + (long long)m * N + (n0 + tn),
           acc[i][0] + bias, acc[i][1] + bias, acc[i][2] + bias, acc[i][3] + bias);
  }
}

// ---------------- small kernels ----------------
__global__ __launch_bounds__(256) void rowsum_kernel(const float* __restrict__ X,
                                                     float* __restrict__ s, int N) {
  long long row = blockIdx.x;
  const float* p = X + row * N;
  float acc = 0.f;
  for (int i = threadIdx.x * 4; i < N; i += 1024) {
    float4 v = *(const float4*)(p + i);
    acc += (v.x + v.y) + (v.z + v.w);
  }
  acc = blockSum256(acc);
  if (threadIdx.x == 0) s[row] = acc;
}

// u[b,i] = sum Wth[i,:]*s[b,:]  (sel 0), v[b,i] = sum Wph[i,:]*s[b,:] (sel 1)
__global__ __launch_bounds__(256) void gemv2_kernel(const float* __restrict__ Wth,
    const float* __restrict__ Wph, const float* __restrict__ s,
    float* __restrict__ u, float* __restrict__ v) {
  int b = blockIdx.x & 7, sel = blockIdx.x >> 3;
  const float* W = sel ? Wph : Wth;
  float* out = sel ? v : u;
  __shared__ float ssm[Cc];
  for (int i = threadIdx.x; i < Cc; i += 256) ssm[i] = s[b * Cc + i];
  __syncthreads();
  int i = threadIdx.x;
  const float* wr = W + i * Cc;
  float acc = 0.f;
  for (int k = 0; k < Cc; ++k) acc = fmaf(wr[k], ssm[k], acc);
  out[b * C1 + i] = acc;
}

// softmax over rows of L with bias terms; also emits w[b,i] = sum_j f * bg[j]
__global__ __launch_bounds__(256) void softmax_kernel(float* __restrict__ L,
    const float* __restrict__ bth, const float* __restrict__ bph,
    const float* __restrict__ u, const float* __restrict__ v,
    const float* __restrict__ bg, float* __restrict__ w) {
  __shared__ float bgs[C1];
  int row = blockIdx.x;                 // b*256 + i
  int b = row >> 8, i = row & 255;
  int j = threadIdx.x;
  bgs[j] = bg[j];
  float bt = bth[i], bp = bph[j];
  long long idx = (long long)row * C1 + j;
  float val = L[idx] + bt * v[b * C1 + j] + u[b * C1 + i] * bp + (float)Nn * bt * bp;
  float mx = blockMax256(val);
  float p = expf(val - mx);
  float sm = blockSum256(p);
  float f = p / sm;
  L[idx] = f;
  float ws = blockSum256(f * bgs[j]);
  if (j == 0) w[row] = ws;
}

__global__ __launch_bounds__(256) void q_kernel(const float* __restrict__ W2,
                                                const float* __restrict__ b2v,
                                                const float* __restrict__ w,
                                                float* __restrict__ q) {
  int gi = blockIdx.x * 256 + threadIdx.x;
  int b = gi >> 9, c = gi & 511;
  __shared__ float wsm[C1];
  wsm[threadIdx.x] = w[b * C1 + threadIdx.x];
  __syncthreads();
  const float* wr = W2 + c * C1;
  float acc = b2v[c];
  for (int i = 0; i < C1; ++i) acc = fmaf(wr[i], wsm[i], acc);
  q[gi] = acc;
}

// zqb[b][d] = b3[d] + sum_c W3[d][c] * q[b][c]
__global__ __launch_bounds__(256) void zqbias_kernel(const float* __restrict__ W3,
    const float* __restrict__ b3, const float* __restrict__ q, float* __restrict__ zqb) {
  int gi = blockIdx.x * 256 + threadIdx.x;   // [0, 1024)
  int b = gi >> 7, d = gi & 127;
  const float* wr = W3 + d * Cc;
  const float* qr = q + b * Cc;
  float acc = b3[d];
  for (int c = 0; c < Cc; ++c) acc = fmaf(wr[c], qr[c], acc);
  zqb[gi] = acc;
}

// Deep-TEN soft-assign + aggregation. zq is PIXEL-MAJOR [B][N][D].
// Eraw8/Asum8: 8-slot replicated accumulators (slot = n-tile & 7) to cut atomic contention.
template<typename ZT>
__global__ __launch_bounds__(256) void enc_kernel(
    const ZT* __restrict__ zq,      // [B][N][D]
    const float* __restrict__ cw,   // [K][D]
    const float* __restrict__ sc,   // [K]
    float* __restrict__ Eraw8,      // [8][B][K][D] pre-zeroed
    float* __restrict__ Asum8)      // [8][B][K]    pre-zeroed
{
  __shared__ float csm[Kk][Dd + 1];
  __shared__ float cc[Kk], ssm[Kk];
  __shared__ float sA[Kk][256 + 1];
  __shared__ float zs[16][Dd + 4];
  const int tid = threadIdx.x;
  const int b = blockIdx.y;
  const int slot = blockIdx.x & 7;
  const int n0 = blockIdx.x * 256;

  #pragma unroll
  for (int r = 0; r < 16; ++r) {
    int idx = r * 256 + tid;
    csm[idx >> 7][idx & 127] = cw[idx];
  }
  if (tid < Kk) ssm[tid] = sc[tid];
  __syncthreads();
  if (tid < Kk) {
    float a = 0.f;
    for (int d = 0; d < Dd; ++d) { float cv = csm[tid][d]; a = fmaf(cv, cv, a); }
    cc[tid] = a;
  }
  __syncthreads();

  // pass 1: one pixel per thread, contiguous row read
  const ZT* zrow = zq + ((long long)b * Nn + n0 + tid) * Dd;
  float dots[Kk];
  #pragma unroll
  for (int k = 0; k < Kk; ++k) dots[k] = 0.f;
  float xx = 0.f;
  for (int d = 0; d < Dd; d += 4) {
    float4 xv = load4(zrow + d);
    xx = fmaf(xv.x, xv.x, xx); xx = fmaf(xv.y, xv.y, xx);
    xx = fmaf(xv.z, xv.z, xx); xx = fmaf(xv.w, xv.w, xx);
    #pragma unroll
    for (int k = 0; k < Kk; ++k) {
      float dk = dots[k];
      dk = fmaf(csm[k][d + 0], xv.x, dk);
      dk = fmaf(csm[k][d + 1], xv.y, dk);
      dk = fmaf(csm[k][d + 2], xv.z, dk);
      dk = fmaf(csm[k][d + 3], xv.w, dk);
      dots[k] = dk;
    }
  }
  float mx = -1e30f;
  #pragma unroll
  for (int k = 0; k < Kk; ++k) {
    float l = ssm[k] * (xx - 2.f * dots[k] + cc[k]);
    dots[k] = l;
    mx = fmaxf(mx, l);
  }
  float sum = 0.f;
  #pragma unroll
  for (int k = 0; k < Kk; ++k) { float p = expf(dots[k] - mx); dots[k] = p; sum += p; }
  float inv = 1.f / sum;
  #pragma unroll
  for (int k = 0; k < Kk; ++k) sA[k][tid] = dots[k] * inv;
  __syncthreads();
  if (tid < Kk) {
    float s = 0.f;
    for (int p = 0; p < 256; ++p) s += sA[tid][p];
    atomicAdd(&Asum8[((long long)slot * Bb + b) * Kk + tid], s);
  }

  // pass 2: E_part[k][d0..d0+15] over this tile's 256 pixels (16 px per stage)
  float acc[16];
  #pragma unroll
  for (int j = 0; j < 16; ++j) acc[j] = 0.f;
  const int k = tid & 31, d0 = (tid >> 5) * 16;
  const int spx = tid >> 4, sd = (tid & 15) * 8;   // staging: 16 px x 128 d, coalesced
  for (int it = 0; it < 16; ++it) {
    __syncthreads();
    {
      const ZT* src = zq + ((long long)b * Nn + n0 + it * 16 + spx) * Dd + sd;
      float4 a4 = load4(src);
      float4 b4 = load4(src + 4);
      *(float4*)&zs[spx][sd] = a4;
      *(float4*)&zs[spx][sd + 4] = b4;
    }
    __syncthreads();
    #pragma unroll
    for (int p = 0; p < 16; ++p) {
      float a = sA[k][it * 16 + p];
      #pragma unroll
      for (int j = 0; j < 16; ++j) acc[j] = fmaf(a, zs[p][d0 + j], acc[j]);
    }
  }
  float* Ep = Eraw8 + (((long long)slot * Bb + b) * Kk + k) * Dd + d0;
  #pragma unroll
  for (int j = 0; j < 16; ++j) atomicAdd(Ep + j, acc[j]);
}

// per-k BN over (b,d) with 8-slot reduction, relu, Es[b,d] += e
__global__ __launch_bounds__(256) void bn_kernel(const float* __restrict__ Eraw8,
    const float* __restrict__ Asum8, const float* __restrict__ cw, float* __restrict__ Es) {
  __shared__ float sas[8];
  int k = blockIdx.x, tid = threadIdx.x;
  if (tid < 8) {
    float a = 0.f;
    for (int sl = 0; sl < 8; ++sl) a += Asum8[((long long)sl * Bb + tid) * Kk + k];
    sas[tid] = a;
  }
  __syncthreads();
  float vals[4], s = 0.f, s2 = 0.f;
  #pragma unroll
  for (int r = 0; r < 4; ++r) {
    int i = r * 256 + tid;
    int b = i >> 7, d = i & 127;
    float e = 0.f;
    for (int sl = 0; sl < 8; ++sl)
      e += Eraw8[(((long long)sl * Bb + b) * Kk + k) * Dd + d];
    e -= sas[b] * cw[k * Dd + d];
    vals[r] = e; s += e; s2 = fmaf(e, e, s2);
  }
  s = blockSum256(s);
  s2 = blockSum256(s2);
  float mean = s * (1.f / 1024.f);
  float var = fmaxf(s2 * (1.f / 1024.f) - mean * mean, 0.f);
  float rs = rsqrtf(var + 1e-5f);
  #pragma unroll
  for (int r = 0; r < 4; ++r) {
    int i = r * 256 + tid;
    int b = i >> 7, d = i & 127;
    float e = (vals[r] - mean) * rs;
    if (e > 0.f) atomicAdd(&Es[b * Dd + d], e);
  }
}

// gamma = sigmoid(Es @ Wfc^T + bfc); also folds gamma into q (q <- q*gamma)
__global__ __launch_bounds__(256) void gamma_kernel(const float* __restrict__ Es,
    const float* __restrict__ Wfc, const float* __restrict__ bfc,
    float* __restrict__ gam, float* __restrict__ q) {
  int gi = blockIdx.x * 256 + threadIdx.x;
  int b = gi >> 9, c = gi & 511;
  __shared__ float esm[Dd];
  if (threadIdx.x < Dd) esm[threadIdx.x] = Es[b * Dd + threadIdx.x];
  __syncthreads();
  const float* wr = Wfc + c * Dd;
  float acc = bfc[c];
  for (int d = 0; d < Dd; ++d) acc = fmaf(wr[d], esm[d], acc);
  float g = 1.f / (1.f + expf(-acc));
  gam[gi] = g;
  q[gi] *= g;
}

// P[b][c][:] *= gam[b][c]  (fold output scale into the GEMM A-operand)
__global__ __launch_bounds__(256) void scaleP_kernel(float* __restrict__ P,
    const float* __restrict__ gam) {
  long long f = ((long long)blockIdx.x * 256 + threadIdx.x) * 4;  // 8*512*512 total
  int b = (int)(f >> 18), c = (int)((f >> 9) & 511);
  float g = gam[b * Cc + c];
  float4 v = *(const float4*)(P + f);
  store4(P + f, v.x * g, v.y * g, v.z * g, v.w * g);
}

// ---------------- host launcher ----------------
extern "C" void kernel_launch(void* const* d_in, const int* in_sizes, int n_in,
                              void* d_out, int out_size, void* d_ws, size_t ws_size,
                              hipStream_t stream) {
  const float* X   = (const float*)d_in[0];
  const float* Wth = (const float*)d_in[1];
  const float* bth = (const float*)d_in[2];
  const float* Wph = (const float*)d_in[3];
  const float* bph = (const float*)d_in[4];
  const float* Wg  = (const float*)d_in[5];
  const float* bg  = (const float*)d_in[6];
  const float* W2  = (const float*)d_in[7];
  const float* b2v = (const float*)d_in[8];
  const float* W3  = (const float*)d_in[9];
  const float* b3v = (const float*)d_in[10];
  const float* CW  = (const float*)d_in[11];
  const float* SC  = (const float*)d_in[12];
  const float* Wfc = (const float*)d_in[13];
  const float* bfc = (const float*)d_in[14];
  float* out = (float*)d_out;
  float* wsf = (float*)d_ws;

  const long long szL   = (long long)Bb * C1 * C1;   // 524288
  const long long szRA  = (long long)Bb * Cc * Cc;   // 2097152
  const long long szRB  = (long long)Bb * C1 * Cc;   // 1048576
  long long off = 0;
  float* s_   = wsf + off; off += Bb * Cc;
  float* u_   = wsf + off; off += Bb * C1;
  float* v_   = wsf + off; off += Bb * C1;
  float* w_   = wsf + off; off += Bb * C1;
  float* q_   = wsf + off; off += Bb * Cc;
  float* Eraw_= wsf + off; off += (long long)Bb * Kk * Dd;   // legacy slot (unused)
  float* Es_  = wsf + off; off += Bb * Dd;
  float* Asum_= wsf + off; off += Bb * Kk;                   // legacy slot (unused)
  float* gam_ = wsf + off; off += Bb * Cc;
  float* L_   = wsf + off; off += szL;
  float* regA = wsf + off; off += szRA;
  float* regB = wsf + off; off += szRB;
  const long long baseFloats = off;
  // tail region: G split-K partials, later aliased by zq (pixel-major [B][N][D])
  float* tail = wsf + off;
  const long long ZQ_F  = (long long)Bb * Dd * Nn;      // 9437184
  const long long tailFloats = (long long)(ws_size / 4) - baseFloats;
  const bool big = tailFloats >= ZQ_F;    // big: fp32 zq + splitK=6; small: bf16 zq + splitK=2
  const int numKS = big ? 6 : 2;          // partials: numKS*8*10*16384 floats (7.9M / 2.6M)
  float* part = tail;
  float* zqf  = tail;
  u16*   zqh  = (u16*)tail;
  float* R_   = L_;     // alias: f dead after Mm-GEMM; R born after P-GEMM
  float* zqb_ = u_;     // alias: u dead after softmax
  float* E8_  = regB;                       // 8*8*32*128 = 262144 floats (regB dead post-P)
  float* A8_  = regB + 262144;              // 8*8*32 = 2048 floats
  (void)Eraw_; (void)Asum_;

  const long long strX = (long long)Cc * Nn;
  const long long sG = (long long)Cc * Cc;
  const long long sU = (long long)C1 * Cc;
  const long long sL = (long long)C1 * C1;
  const long long sR = (long long)Dd * Cc;

  rowsum_kernel<<<Bb * Cc, 256, 0, stream>>>(X, s_, Nn);
  // G = X X^T (symmetric): 128x64 tile-pair-half partials -> reduce into regA
  gxxt_kernel<<<dim3(20 * numKS * Bb), 256, 0, stream>>>(X, part, numKS, Nn / numKS);
  gred_kernel<<<dim3(10 * Bb), 256, 0, stream>>>(part, regA, numKS);
  // U = Wth @ G -> regB  (M=256 N=512 K=512)
  gemm_mfma<float, 0, false><<<dim3(64), 256, 0, stream>>>(
      Wth, regA, regB, Cc, Cc, 0, sG, sU, nullptr, 0, 4, 2);
  gemv2_kernel<<<16, 256, 0, stream>>>(Wth, Wph, s_, u_, v_);
  // L = U @ Wph^T  (small, fp32)
  gemm64<true><<<dim3(4, 4, Bb), 256, 0, stream>>>(
      regB, Wph, L_, C1, C1, Cc, sU, 0, sL, nullptr, 0);
  softmax_kernel<<<Bb * C1, 256, 0, stream>>>(L_, bth, bph, u_, v_, bg, w_);
  // Mm = f @ Wg -> regB (U dead)  (M=256 N=512 K=256)
  gemm_mfma<float, 0, false><<<dim3(64), 256, 0, stream>>>(
      L_, Wg, regB, Cc, C1, sL, 0, sU, nullptr, 0, 4, 2);
  q_kernel<<<16, 256, 0, stream>>>(W2, b2v, w_, q_);
  // P' = W2 @ Mm + I -> regA (G dead; identity fused in epilogue)
  gemm_mfma<float, 0, true><<<dim3(128), 256, 0, stream>>>(
      W2, regB, regA, Cc, C1, 0, sU, sG, nullptr, 0, 4, 4);
  // regB dead: becomes 8-slot enc accumulators
  hipMemsetAsync(regB, 0, (size_t)(262144 + 2048) * 4, stream);
  hipMemsetAsync(Es_, 0, (size_t)(Bb * Dd) * 4, stream);
  // R = W3 @ P' -> R_ (alias L_)  (M=128 N=512 K=512) ; zq bias = W3 q + b3
  gemm_mfma<float, 0, false><<<dim3(32), 256, 0, stream>>>(
      W3, regA, R_, Cc, Cc, 0, sG, sR, nullptr, 0, 4, 1);
  zqbias_kernel<<<4, 256, 0, stream>>>(W3, b3v, q_, zqb_);
  // zq = R @ X + zqb, stored pixel-major [B][N][D]  (partials dead -> tail reused)
  if (big) {
    gemm_mfma<float, 1, false><<<dim3(576), 256, 0, stream>>>(
        R_, X, zqf, Nn, Cc, sR, strX, (long long)Dd * Nn, zqb_, Dd, 72, 1);
    enc_kernel<float><<<dim3(36, Bb), 256, 0, stream>>>(zqf, CW, SC, E8_, A8_);
  } else {
    gemm_mfma<u16, 1, false><<<dim3(576), 256, 0, stream>>>(
        R_, X, zqh, Nn, Cc, sR, strX, (long long)Dd * Nn, zqb_, Dd, 72, 1);
    enc_kernel<u16><<<dim3(36, Bb), 256, 0, stream>>>(zqh, CW, SC, E8_, A8_);
  }
  bn_kernel<<<Kk, 256, 0, stream>>>(E8_, A8_, CW, Es_);
  gamma_kernel<<<16, 256, 0, stream>>>(Es_, Wfc, bfc, gam_, q_);   // q <- q*gamma
  // fold gamma into P' rows, then z*gamma = (gamma.P') @ X + (gamma.q) -> out
  scaleP_kernel<<<2048, 256, 0, stream>>>(regA, gam_);
  gemm_mfma<float, 0, false><<<dim3(2304), 256, 0, stream>>>(
      regA, X, out, Nn, Cc, sG, strX, strX, q_, Cc, 72, 4);
  (void)in_sizes; (void)n_in; (void)out_size;
}

// Round 10
// 947.516 us; speedup vs baseline: 1.5379x; 1.0108x over previous
//
#include <hip/hip_runtime.h>

// NLCE: non-local (channel attention) + Deep-TEN encoding, B=8 C=512 C1=256 D=128 K=32 N=9216.
// All inputs/outputs fp32. Big GEMMs on matrix cores via 2-limb bf16 split
// (hi/lo via v_cvt_pk_bf16_f32; products hi*hi+hi*lo+lo*hi, ~1e-5 rel).
// Round 10: B-LDS 8-row pad (+16B) kills 4-way bank conflict on B staging writes;
// gamma folded into z-GEMM A-staging (scaleA, kills scaleP); rowsum folded into
// gxxt diag blocks; merged memsets; gxxt numKS=4 (single resident round).

typedef unsigned short u16;

#define Bb 8
#define Cc 512
#define C1 256
#define Dd 128
#define Kk 32
#define Nn 9216

// padded B-LDS index (ushorts): row stride 40 + 8-ushort pad every 8 rows
#define BIDX(n, c) (((n) * 40) + (((n) >> 3) * 8) + (c))

typedef __attribute__((ext_vector_type(8))) short short8v;
typedef __attribute__((ext_vector_type(4))) short short4v;
typedef __attribute__((ext_vector_type(4))) float f32x4;

__device__ __forceinline__ float b2f(u16 u) {
  union { unsigned int i; float f; } v; v.i = ((unsigned int)u) << 16; return v.f;
}
__device__ __forceinline__ u16 f2b(float f) {
  union { float f; unsigned int i; } v; v.f = f;
  unsigned int x = v.i;
  return (u16)((x + 0x7fffu + ((x >> 16) & 1u)) >> 16);  // RNE
}

__device__ __forceinline__ float4 load4(const float* p) { return *(const float4*)p; }
__device__ __forceinline__ float4 load4(const u16* p) {
  ushort4 q = *(const ushort4*)p;
  return make_float4(b2f(q.x), b2f(q.y), b2f(q.z), b2f(q.w));
}
__device__ __forceinline__ void store4(float* p, float a, float b, float c, float d) {
  *(float4*)p = make_float4(a, b, c, d);
}

__device__ __forceinline__ float waveSum(float v) {
  #pragma unroll
  for (int o = 32; o > 0; o >>= 1) v += __shfl_xor(v, o);
  return v;
}
__device__ __forceinline__ float waveMax(float v) {
  #pragma unroll
  for (int o = 32; o > 0; o >>= 1) v = fmaxf(v, __shfl_xor(v, o));
  return v;
}
__device__ __forceinline__ float blockSum256(float v) {
  __shared__ float sm[4];
  v = waveSum(v);
  if ((threadIdx.x & 63) == 0) sm[threadIdx.x >> 6] = v;
  __syncthreads();
  float r = sm[0] + sm[1] + sm[2] + sm[3];
  __syncthreads();
  return r;
}
__device__ __forceinline__ float blockMax256(float v) {
  __shared__ float sm[4];
  v = waveMax(v);
  if ((threadIdx.x & 63) == 0) sm[threadIdx.x >> 6] = v;
  __syncthreads();
  float r = fmaxf(fmaxf(sm[0], sm[1]), fmaxf(sm[2], sm[3]));
  __syncthreads();
  return r;
}

// ---------------- MFMA split-bf16 common ----------------
__device__ __forceinline__ f32x4 mfma_bf16_16x16x32(short8v a, short8v b, f32x4 c) {
  asm("v_mfma_f32_16x16x32_bf16 %0, %1, %2, %0" : "+v"(c) : "v"(a), "v"(b));
  return c;
}

__device__ __forceinline__ int fsw(int r) { return (r ^ (r >> 2) ^ (r >> 4)) & 3; }

// 2 floats -> packed bf16 hi limbs (h) and lo limbs (l), 1 cvt_pk each + exact residual
__device__ __forceinline__ void cvt2(float x0, float x1, unsigned int& h, unsigned int& l) {
  asm("v_cvt_pk_bf16_f32 %0, %1, %2" : "=v"(h) : "v"(x0), "v"(x1));
  union { unsigned int u; float f; } fa, fb;
  fa.u = h << 16; fb.u = h & 0xffff0000u;
  float r0 = x0 - fa.f, r1 = x1 - fb.f;
  asm("v_cvt_pk_bf16_f32 %0, %1, %2" : "=v"(l) : "v"(r0), "v"(r1));
}

__device__ __forceinline__ void storeC4(float* p, float4 v) { *(float4*)p = v; }
__device__ __forceinline__ void storeC4(u16* p, float4 v) {
  ushort4 q; q.x = f2b(v.x); q.y = f2b(v.y); q.z = f2b(v.z); q.w = f2b(v.w);
  *(ushort4*)p = q;
}

// ---------------- generic MFMA GEMM (BN=128) ----------------
// C[b] = A[b] @ B[b]; fp32 in, TO out, 2-limb bf16 MFMA inside.
// BM = 128, BN = 128, BK = 32. 256 threads = 4 waves (2x2), wave tile 64x64.
// OMODE 0: row-major C[M][N], +biasRow[gr]; ADDI adds identity (gr==gc).
// OMODE 1: transposed C[N][128] (requires gny==1, M==128), +biasRow[d].
// scaleA: per-A-row scale (stride sBias), applied during staging (gamma fold).
template<typename TO, int OMODE, bool ADDI>
__global__ __launch_bounds__(256, 3) void gemm_mfma(
    const float* __restrict__ A, const float* __restrict__ B, TO* __restrict__ C,
    int N, int K,
    long long sA, long long sB, long long sC,
    const float* __restrict__ biasRow, long long sBias,
    const float* __restrict__ scaleA,
    int gnx, int gny)
{
  // A: (row,k) at column ((k>>3) ^ fsw(row))*8 + (k&7); stride 40 ushorts.
  // B: same column map but padded rows via BIDX (breaks 8-row bank aliasing).
  __shared__ __align__(16) u16 Asm_[2][128][40];
  __shared__ __align__(16) u16 Bsm_[2][5248];   // 128*40 + 16*8

  int id = blockIdx.x;
  {
    const int nwg = gridDim.x;
    if ((nwg & 7) == 0) id = (id & 7) * (nwg >> 3) + (id >> 3);  // XCD chunk swizzle
  }
  const int per = gnx * gny;
  const int b = id / per;
  const int rem = id - b * per;
  const int by = rem % gny;        // m-block fastest
  const int bx = rem / gny;        // n-block
  A += b * sA; B += b * sB; C += b * sC;
  const int m0 = by * 128, n0 = bx * 128;

  const int t = threadIdx.x;
  const int w = t >> 6, lane = t & 63;
  const int wr = w >> 1, wc = w & 1;
  const int lr = lane & 15, lq = lane >> 4;

  const int sar = t >> 1, sak = (t & 1) * 16;   // A staging: 128 rows x 32 k
  const int kg2 = t >> 4, ng = t & 15;          // B staging: 2 k-rows x 8 n per thread

  const float gA = scaleA ? scaleA[b * sBias + m0 + sar] : 1.f;

  float ra[16];
  float rb[16];

  auto loadA = [&](int k0) {
    const float* p = A + (long long)(m0 + sar) * K + (k0 + sak);
    #pragma unroll
    for (int i = 0; i < 4; ++i) {
      float4 v = *(const float4*)(p + i * 4);
      ra[i*4+0] = v.x; ra[i*4+1] = v.y; ra[i*4+2] = v.z; ra[i*4+3] = v.w;
    }
  };
  auto loadB = [&](int k0) {
    const float* p = B + (long long)(k0 + kg2 * 2) * N + (n0 + ng * 8);
    #pragma unroll
    for (int i = 0; i < 2; ++i) {
      float4 v0 = *(const float4*)(p + (long long)i * N);
      float4 v1 = *(const float4*)(p + (long long)i * N + 4);
      rb[i*8+0]=v0.x; rb[i*8+1]=v0.y; rb[i*8+2]=v0.z; rb[i*8+3]=v0.w;
      rb[i*8+4]=v1.x; rb[i*8+5]=v1.y; rb[i*8+6]=v1.z; rb[i*8+7]=v1.w;
    }
  };

  auto stage = [&]() {
    {   // A rows sar, k-local sak..sak+15 -> two swizzled 8-blocks (x gA)
      const int f = fsw(sar);
      #pragma unroll
      for (int h = 0; h < 2; ++h) {
        const int col = ((((sak >> 3) + h) ^ f) << 3);
        union { unsigned int u[4]; short8v v; } H, L;
        #pragma unroll
        for (int p = 0; p < 4; ++p)
          cvt2(ra[h*8+2*p] * gA, ra[h*8+2*p+1] * gA, H.u[p], L.u[p]);
        *(short8v*)&Asm_[0][sar][col] = H.v;
        *(short8v*)&Asm_[1][sar][col] = L.v;
      }
    }
    {   // B: 2 consecutive k per n, one u32 write per limb per n (padded rows)
      const int blk = kg2 >> 2, sub = 2 * (kg2 & 3);
      #pragma unroll
      for (int j = 0; j < 8; ++j) {
        const int n = ng * 8 + j;
        const int col = ((blk ^ fsw(n)) << 3) + sub;
        unsigned int H, L;
        cvt2(rb[j], rb[8 + j], H, L);
        *(unsigned int*)&Bsm_[0][BIDX(n, col)] = H;
        *(unsigned int*)&Bsm_[1][BIDX(n, col)] = L;
      }
    }
  };

  f32x4 acc[4][4];
  #pragma unroll
  for (int im = 0; im < 4; ++im)
    #pragma unroll
    for (int in = 0; in < 4; ++in)
      acc[im][in] = f32x4{0.f, 0.f, 0.f, 0.f};

  loadA(0); loadB(0);
  for (int k0 = 0; k0 < K; k0 += 32) {
    stage();
    if (k0 + 32 < K) { loadA(k0 + 32); loadB(k0 + 32); }
    __syncthreads();
    short8v af[2][4];
    #pragma unroll
    for (int im = 0; im < 4; ++im) {
      const int r = wr * 64 + im * 16 + lr;
      const int col = ((lq ^ fsw(r)) << 3);
      af[0][im] = *(const short8v*)&Asm_[0][r][col];
      af[1][im] = *(const short8v*)&Asm_[1][r][col];
    }
    #pragma unroll
    for (int in = 0; in < 4; ++in) {
      const int rB = wc * 64 + in * 16 + lr;
      const int colB = ((lq ^ fsw(rB)) << 3);
      short8v bh = *(const short8v*)&Bsm_[0][BIDX(rB, colB)];
      short8v bl = *(const short8v*)&Bsm_[1][BIDX(rB, colB)];
      #pragma unroll
      for (int im = 0; im < 4; ++im) {
        acc[im][in] = mfma_bf16_16x16x32(af[0][im], bh, acc[im][in]);  // hi*hi
        acc[im][in] = mfma_bf16_16x16x32(af[0][im], bl, acc[im][in]);  // hi*lo
        acc[im][in] = mfma_bf16_16x16x32(af[1][im], bh, acc[im][in]);  // lo*hi
      }
    }
    __syncthreads();
  }
  asm volatile("s_nop 7\n\ts_nop 7\n\ts_nop 7");  // MFMA->VALU/VMEM read hazard guard

  if constexpr (OMODE == 1) {
    // transposed store: C[n][128]; d = wr*64+im*16+lq*4+{0..3} contiguous per lane
    const float* bb = biasRow + (long long)b * sBias;
    #pragma unroll
    for (int im = 0; im < 4; ++im) {
      #pragma unroll
      for (int in = 0; in < 4; ++in) {
        const f32x4 a = acc[im][in];
        const int gc = n0 + wc * 64 + in * 16 + lr;
        const int d0b = wr * 64 + im * 16 + lq * 4;
        float4 v = make_float4(a[0] + bb[d0b + 0], a[1] + bb[d0b + 1],
                               a[2] + bb[d0b + 2], a[3] + bb[d0b + 3]);
        storeC4(&C[(long long)gc * Dd + d0b], v);
      }
    }
  } else {
    #pragma unroll
    for (int im = 0; im < 4; ++im) {
      #pragma unroll
      for (int in = 0; in < 4; ++in) {
        const f32x4 a = acc[im][in];
        const int gc = n0 + wc * 64 + in * 16 + lr;   // C/D: col = lane&15
        #pragma unroll
        for (int p = 0; p < 4; ++p) {
          const int gr = m0 + wr * 64 + im * 16 + lq * 4 + p;  // row = (lane>>4)*4+reg
          float v = a[p];
          if (biasRow) v += biasRow[b * sBias + gr];
          if (ADDI && gr == gc) v += 1.f;
          C[(long long)gr * N + gc] = v;
        }
      }
    }
  }
}

// ---------------- G = X X^T, symmetric, split-K partials (no atomics) --------
// 128x64 blocks: pair selects (i-tile, j-tile), jh selects column half of j-tile.
// Diag/jh==0 blocks also accumulate row sums of X into sOut (rowsum fold).
__device__ __constant__ int PIa[10] = {0,0,0,0,1,1,1,2,2,3};
__device__ __constant__ int PJa[10] = {0,1,2,3,1,2,3,2,3,3};

__global__ __launch_bounds__(256, 3) void gxxt_kernel(
    const float* __restrict__ X, float* __restrict__ part,
    int numKS, int kChunk, float* __restrict__ sOut)
{
  __shared__ __align__(16) u16 Asm_[2][128][40];
  __shared__ __align__(16) u16 Bsm_[2][2624];   // 64*40 + 8*8

  int id = blockIdx.x;
  {
    const int nwg = gridDim.x;
    if ((nwg & 7) == 0) id = (id & 7) * (nwg >> 3) + (id >> 3);  // one batch per XCD
  }
  const int sub = id % 20;
  const int pair = sub >> 1, jh = sub & 1;
  const int rest = id / 20;
  const int ks = rest % numKS;
  const int b = rest / numKS;
  const int i0 = PIa[pair] * 128, j0 = PJa[pair] * 128;
  const bool same = (i0 == j0);
  const bool doSum = same && (jh == 0);
  const float* Xb = X + (long long)b * Cc * Nn;
  const int kBeg = ks * kChunk, kEnd = kBeg + kChunk;

  const int t = threadIdx.x;
  const int w = t >> 6, lane = t & 63;
  const int wr = w >> 1, wc = w & 1;
  const int lr = lane & 15, lq = lane >> 4;
  const int sar = t >> 1, sak = (t & 1) * 16;   // A: 128 rows x 32 k
  const int sbr = t >> 2, sbk = (t & 3) * 8;    // B: 64 rows x 32 k (8 k per thread)

  float ra[16], rb[8];
  float rs = 0.f;

  auto loadA = [&](int k0) {
    const float* p = Xb + (long long)(i0 + sar) * Nn + (k0 + sak);
    #pragma unroll
    for (int i = 0; i < 4; ++i) {
      float4 v = *(const float4*)(p + i * 4);
      ra[i*4+0] = v.x; ra[i*4+1] = v.y; ra[i*4+2] = v.z; ra[i*4+3] = v.w;
    }
  };
  auto loadB = [&](int k0) {
    const float* p = Xb + (long long)(j0 + jh * 64 + sbr) * Nn + (k0 + sbk);
    float4 v0 = *(const float4*)(p);
    float4 v1 = *(const float4*)(p + 4);
    rb[0]=v0.x; rb[1]=v0.y; rb[2]=v0.z; rb[3]=v0.w;
    rb[4]=v1.x; rb[5]=v1.y; rb[6]=v1.z; rb[7]=v1.w;
  };
  auto stageA = [&]() {
    const int f = fsw(sar);
    #pragma unroll
    for (int h = 0; h < 2; ++h) {
      const int col = ((((sak >> 3) + h) ^ f) << 3);
      union { unsigned int u[4]; short8v v; } Hv, Lv;
      #pragma unroll
      for (int p = 0; p < 4; ++p) cvt2(ra[h*8+2*p], ra[h*8+2*p+1], Hv.u[p], Lv.u[p]);
      *(short8v*)&Asm_[0][sar][col] = Hv.v;
      *(short8v*)&Asm_[1][sar][col] = Lv.v;
    }
  };
  auto stageB = [&]() {
    const int col = (((sbk >> 3) ^ fsw(sbr)) << 3);
    union { unsigned int u[4]; short8v v; } Hv, Lv;
    #pragma unroll
    for (int p = 0; p < 4; ++p) cvt2(rb[2*p], rb[2*p+1], Hv.u[p], Lv.u[p]);
    *(short8v*)&Bsm_[0][BIDX(sbr, col)] = Hv.v;
    *(short8v*)&Bsm_[1][BIDX(sbr, col)] = Lv.v;
  };

  f32x4 acc[4][2];
  #pragma unroll
  for (int im = 0; im < 4; ++im)
    #pragma unroll
    for (int in = 0; in < 2; ++in)
      acc[im][in] = f32x4{0.f, 0.f, 0.f, 0.f};

  loadA(kBeg);
  if (!same) loadB(kBeg);
  for (int k0 = kBeg; k0 < kEnd; k0 += 32) {
    if (doSum) {
      #pragma unroll
      for (int j = 0; j < 16; ++j) rs += ra[j];
    }
    stageA();
    if (!same) stageB();
    if (k0 + 32 < kEnd) { loadA(k0 + 32); if (!same) loadB(k0 + 32); }
    __syncthreads();
    short8v af[2][4];
    #pragma unroll
    for (int im = 0; im < 4; ++im) {
      const int r = wr * 64 + im * 16 + lr;
      const int col = ((lq ^ fsw(r)) << 3);
      af[0][im] = *(const short8v*)&Asm_[0][r][col];
      af[1][im] = *(const short8v*)&Asm_[1][r][col];
    }
    #pragma unroll
    for (int in = 0; in < 2; ++in) {
      const int rloc = wc * 32 + in * 16 + lr;
      short8v bh, bl;
      if (same) {
        const int r = jh * 64 + rloc;
        const int colB = ((lq ^ fsw(r)) << 3);
        bh = *(const short8v*)&Asm_[0][r][colB];
        bl = *(const short8v*)&Asm_[1][r][colB];
      } else {
        const int colB = ((lq ^ fsw(rloc)) << 3);
        bh = *(const short8v*)&Bsm_[0][BIDX(rloc, colB)];
        bl = *(const short8v*)&Bsm_[1][BIDX(rloc, colB)];
      }
      #pragma unroll
      for (int im = 0; im < 4; ++im) {
        acc[im][in] = mfma_bf16_16x16x32(af[0][im], bh, acc[im][in]);
        acc[im][in] = mfma_bf16_16x16x32(af[0][im], bl, acc[im][in]);
        acc[im][in] = mfma_bf16_16x16x32(af[1][im], bh, acc[im][in]);
      }
    }
    __syncthreads();
  }
  asm volatile("s_nop 7\n\ts_nop 7\n\ts_nop 7");

  if (doSum) atomicAdd(&sOut[b * Cc + i0 + sar], rs);

  float* Cp = part + ((long long)(ks * Bb + b) * 10 + pair) * 16384 + jh * 64;
  #pragma unroll
  for (int im = 0; im < 4; ++im) {
    #pragma unroll
    for (int in = 0; in < 2; ++in) {
      const f32x4 a = acc[im][in];
      const int gc = wc * 32 + in * 16 + lr;
      #pragma unroll
      for (int p = 0; p < 4; ++p) {
        const int gr = wr * 64 + im * 16 + lq * 4 + p;
        Cp[gr * 128 + gc] = a[p];
      }
    }
  }
}

// Reduce partials -> G (both triangles). One block per (b, pair).
__global__ __launch_bounds__(256) void gred_kernel(const float* __restrict__ part,
    float* __restrict__ G, int numKS) {
  __shared__ float sm[64][129];
  const int pair = blockIdx.x % 10, b = blockIdx.x / 10;
  const int i0 = PIa[pair] * 128, j0 = PJa[pair] * 128;
  float* Gb = G + (long long)b * Cc * Cc;
  const long long ksStr = (long long)Bb * 10 * 16384;
  const float* p0 = part + ((long long)b * 10 + pair) * 16384;
  const int t = threadIdx.x;
  for (int half = 0; half < 2; ++half) {
    const int r0 = half * 64;
    __syncthreads();
    for (int rep = 0; rep < 32; ++rep) {
      int idx = r0 * 128 + rep * 256 + t;
      float s = 0.f;
      for (int ks = 0; ks < numKS; ++ks) s += p0[(long long)ks * ksStr + idx];
      int r = (idx >> 7) - r0, c = idx & 127;
      sm[r][c] = s;
      Gb[(long long)(i0 + r0 + r) * Cc + (j0 + c)] = s;
    }
    if (i0 != j0) {
      __syncthreads();
      for (int rep = 0; rep < 32; ++rep) {
        int o = rep * 256 + t;
        int rr = o >> 6, cc = o & 63;
        Gb[(long long)(j0 + rr) * Cc + (i0 + r0 + cc)] = sm[cc][rr];
      }
    }
  }
}

// ---------------- generic 64x64 tiled GEMM, fp32 (L only) ----------------
template<bool TRANSB>
__global__ __launch_bounds__(256) void gemm64(
    const float* __restrict__ A, const float* __restrict__ B, float* __restrict__ C,
    int M, int N, int K,
    long long sA, long long sB, long long sC,
    const float* __restrict__ biasRow, long long sBias)
{
  const int bz = blockIdx.z;
  A += (long long)bz * sA;
  B += (long long)bz * sB;
  C += (long long)bz * sC;
  const int m0 = blockIdx.y * 64, n0 = blockIdx.x * 64;
  __shared__ __align__(16) float As[16][64];
  __shared__ __align__(16) float Bs[16][64];
  const int t = threadIdx.x;
  const int lr = t >> 2, lk = (t & 3) << 2;
  const int tm = (t >> 4) << 2, tn = (t & 15) << 2;
  float acc[4][4] = {};
  for (int k0 = 0; k0 < K; k0 += 16) {
    {
      float4 a = load4(A + (long long)(m0 + lr) * K + (k0 + lk));
      As[lk + 0][lr] = a.x; As[lk + 1][lr] = a.y; As[lk + 2][lr] = a.z; As[lk + 3][lr] = a.w;
    }
    if (TRANSB) {
      float4 b = load4(B + (long long)(n0 + lr) * K + (k0 + lk));
      Bs[lk + 0][lr] = b.x; Bs[lk + 1][lr] = b.y; Bs[lk + 2][lr] = b.z; Bs[lk + 3][lr] = b.w;
    } else {
      const int kr = t >> 4, nc = (t & 15) << 2;
      float4 b = load4(B + (long long)(k0 + kr) * N + (n0 + nc));
      *(float4*)&Bs[kr][nc] = b;
    }
    __syncthreads();
    #pragma unroll
    for (int kk = 0; kk < 16; ++kk) {
      const float4 av = *(const float4*)&As[kk][tm];
      const float4 bv = *(const float4*)&Bs[kk][tn];
      acc[0][0] = fmaf(av.x, bv.x, acc[0][0]);
      acc[0][1] = fmaf(av.x, bv.y, acc[0][1]);
      acc[0][2] = fmaf(av.x, bv.z, acc[0][2]);
      acc[0][3] = fmaf(av.x, bv.w, acc[0][3]);
      acc[1][0] = fmaf(av.y, bv.x, acc[1][0]);
      acc[1][1] = fmaf(av.y, bv.y, acc[1][1]);
      acc[1][2] = fmaf(av.y, bv.z, acc[1][2]);
      acc[1][3] = fmaf(av.y, bv.w, acc[1][3]);
      acc[2][0] = fmaf(av.z, bv.x, acc[2][0]);
      acc[2][1] = fmaf(av.z, bv.y, acc[2][1]);
      acc[2][2] = fmaf(av.z, bv.z, acc[2][2]);
      acc[2][3] = fmaf(av.z, bv.w, acc[2][3]);
      acc[3][0] = fmaf(av.w, bv.x, acc[3][0]);
      acc[3][1] = fmaf(av.w, bv.y, acc[3][1]);
      acc[3][2] = fmaf(av.w, bv.z, acc[3][2]);
      acc[3][3] = fmaf(av.w, bv.w, acc[3][3]);
    }
    __syncthreads();
  }
  #pragma unroll
  for (int i = 0; i < 4; ++i) {
    const int m = m0 + tm + i;
    float bias = biasRow ? biasRow[bz * sBias + m] : 0.f;
    store4(C + (long long)m * N + (n0 + tn),
           acc[i][0] + bias, acc[i][1] + bias, acc[i][2] + bias, acc[i][3] + bias);
  }
}

// ---------------- small kernels ----------------
// u[b,i] = sum Wth[i,:]*s[b,:]  (sel 0), v[b,i] = sum Wph[i,:]*s[b,:] (sel 1)
__global__ __launch_bounds__(256) void gemv2_kernel(const float* __restrict__ Wth,
    const float* __restrict__ Wph, const float* __restrict__ s,
    float* __restrict__ u, float* __restrict__ v) {
  int b = blockIdx.x & 7, sel = blockIdx.x >> 3;
  const float* W = sel ? Wph : Wth;
  float* out = sel ? v : u;
  __shared__ float ssm[Cc];
  for (int i = threadIdx.x; i < Cc; i += 256) ssm[i] = s[b * Cc + i];
  __syncthreads();
  int i = threadIdx.x;
  const float* wr = W + i * Cc;
  float acc = 0.f;
  for (int k = 0; k < Cc; ++k) acc = fmaf(wr[k], ssm[k], acc);
  out[b * C1 + i] = acc;
}

// softmax over rows of L with bias terms; also emits w[b,i] = sum_j f * bg[j]
__global__ __launch_bounds__(256) void softmax_kernel(float* __restrict__ L,
    const float* __restrict__ bth, const float* __restrict__ bph,
    const float* __restrict__ u, const float* __restrict__ v,
    const float* __restrict__ bg, float* __restrict__ w) {
  __shared__ float bgs[C1];
  int row = blockIdx.x;                 // b*256 + i
  int b = row >> 8, i = row & 255;
  int j = threadIdx.x;
  bgs[j] = bg[j];
  float bt = bth[i], bp = bph[j];
  long long idx = (long long)row * C1 + j;
  float val = L[idx] + bt * v[b * C1 + j] + u[b * C1 + i] * bp + (float)Nn * bt * bp;
  float mx = blockMax256(val);
  float p = expf(val - mx);
  float sm = blockSum256(p);
  float f = p / sm;
  L[idx] = f;
  float ws = blockSum256(f * bgs[j]);
  if (j == 0) w[row] = ws;
}

__global__ __launch_bounds__(256) void q_kernel(const float* __restrict__ W2,
                                                const float* __restrict__ b2v,
                                                const float* __restrict__ w,
                                                float* __restrict__ q) {
  int gi = blockIdx.x * 256 + threadIdx.x;
  int b = gi >> 9, c = gi & 511;
  __shared__ float wsm[C1];
  wsm[threadIdx.x] = w[b * C1 + threadIdx.x];
  __syncthreads();
  const float* wr = W2 + c * C1;
  float acc = b2v[c];
  for (int i = 0; i < C1; ++i) acc = fmaf(wr[i], wsm[i], acc);
  q[gi] = acc;
}

// zqb[b][d] = b3[d] + sum_c W3[d][c] * q[b][c]
__global__ __launch_bounds__(256) void zqbias_kernel(const float* __restrict__ W3,
    const float* __restrict__ b3, const float* __restrict__ q, float* __restrict__ zqb) {
  int gi = blockIdx.x * 256 + threadIdx.x;   // [0, 1024)
  int b = gi >> 7, d = gi & 127;
  const float* wr = W3 + d * Cc;
  const float* qr = q + b * Cc;
  float acc = b3[d];
  for (int c = 0; c < Cc; ++c) acc = fmaf(wr[c], qr[c], acc);
  zqb[gi] = acc;
}

// Deep-TEN soft-assign + aggregation. zq is PIXEL-MAJOR [B][N][D].
// Eraw8/Asum8: 8-slot replicated accumulators (slot = n-tile & 7) to cut atomic contention.
template<typename ZT>
__global__ __launch_bounds__(256) void enc_kernel(
    const ZT* __restrict__ zq,      // [B][N][D]
    const float* __restrict__ cw,   // [K][D]
    const float* __restrict__ sc,   // [K]
    float* __restrict__ Eraw8,      // [8][B][K][D] pre-zeroed
    float* __restrict__ Asum8)      // [8][B][K]    pre-zeroed
{
  __shared__ float csm[Kk][Dd + 1];
  __shared__ float cc[Kk], ssm[Kk];
  __shared__ float sA[Kk][256 + 1];
  __shared__ float zs[16][Dd + 4];
  const int tid = threadIdx.x;
  const int b = blockIdx.y;
  const int slot = blockIdx.x & 7;
  const int n0 = blockIdx.x * 256;

  #pragma unroll
  for (int r = 0; r < 16; ++r) {
    int idx = r * 256 + tid;
    csm[idx >> 7][idx & 127] = cw[idx];
  }
  if (tid < Kk) ssm[tid] = sc[tid];
  __syncthreads();
  if (tid < Kk) {
    float a = 0.f;
    for (int d = 0; d < Dd; ++d) { float cv = csm[tid][d]; a = fmaf(cv, cv, a); }
    cc[tid] = a;
  }
  __syncthreads();

  // pass 1: one pixel per thread, contiguous row read
  const ZT* zrow = zq + ((long long)b * Nn + n0 + tid) * Dd;
  float dots[Kk];
  #pragma unroll
  for (int k = 0; k < Kk; ++k) dots[k] = 0.f;
  float xx = 0.f;
  for (int d = 0; d < Dd; d += 4) {
    float4 xv = load4(zrow + d);
    xx = fmaf(xv.x, xv.x, xx); xx = fmaf(xv.y, xv.y, xx);
    xx = fmaf(xv.z, xv.z, xx); xx = fmaf(xv.w, xv.w, xx);
    #pragma unroll
    for (int k = 0; k < Kk; ++k) {
      float dk = dots[k];
      dk = fmaf(csm[k][d + 0], xv.x, dk);
      dk = fmaf(csm[k][d + 1], xv.y, dk);
      dk = fmaf(csm[k][d + 2], xv.z, dk);
      dk = fmaf(csm[k][d + 3], xv.w, dk);
      dots[k] = dk;
    }
  }
  float mx = -1e30f;
  #pragma unroll
  for (int k = 0; k < Kk; ++k) {
    float l = ssm[k] * (xx - 2.f * dots[k] + cc[k]);
    dots[k] = l;
    mx = fmaxf(mx, l);
  }
  float sum = 0.f;
  #pragma unroll
  for (int k = 0; k < Kk; ++k) { float p = expf(dots[k] - mx); dots[k] = p; sum += p; }
  float inv = 1.f / sum;
  #pragma unroll
  for (int k = 0; k < Kk; ++k) sA[k][tid] = dots[k] * inv;
  __syncthreads();
  if (tid < Kk) {
    float s = 0.f;
    for (int p = 0; p < 256; ++p) s += sA[tid][p];
    atomicAdd(&Asum8[((long long)slot * Bb + b) * Kk + tid], s);
  }

  // pass 2: E_part[k][d0..d0+15] over this tile's 256 pixels (16 px per stage)
  float acc[16];
  #pragma unroll
  for (int j = 0; j < 16; ++j) acc[j] = 0.f;
  const int k = tid & 31, d0 = (tid >> 5) * 16;
  const int spx = tid >> 4, sd = (tid & 15) * 8;   // staging: 16 px x 128 d, coalesced
  for (int it = 0; it < 16; ++it) {
    __syncthreads();
    {
      const ZT* src = zq + ((long long)b * Nn + n0 + it * 16 + spx) * Dd + sd;
      float4 a4 = load4(src);
      float4 b4 = load4(src + 4);
      *(float4*)&zs[spx][sd] = a4;
      *(float4*)&zs[spx][sd + 4] = b4;
    }
    __syncthreads();
    #pragma unroll
    for (int p = 0; p < 16; ++p) {
      float a = sA[k][it * 16 + p];
      #pragma unroll
      for (int j = 0; j < 16; ++j) acc[j] = fmaf(a, zs[p][d0 + j], acc[j]);
    }
  }
  float* Ep = Eraw8 + (((long long)slot * Bb + b) * Kk + k) * Dd + d0;
  #pragma unroll
  for (int j = 0; j < 16; ++j) atomicAdd(Ep + j, acc[j]);
}

// per-k BN over (b,d) with 8-slot reduction, relu, Es[b,d] += e
__global__ __launch_bounds__(256) void bn_kernel(const float* __restrict__ Eraw8,
    const float* __restrict__ Asum8, const float* __restrict__ cw, float* __restrict__ Es) {
  __shared__ float sas[8];
  int k = blockIdx.x, tid = threadIdx.x;
  if (tid < 8) {
    float a = 0.f;
    for (int sl = 0; sl < 8; ++sl) a += Asum8[((long long)sl * Bb + tid) * Kk + k];
    sas[tid] = a;
  }
  __syncthreads();
  float vals[4], s = 0.f, s2 = 0.f;
  #pragma unroll
  for (int r = 0; r < 4; ++r) {
    int i = r * 256 + tid;
    int b = i >> 7, d = i & 127;
    float e = 0.f;
    for (int sl = 0; sl < 8; ++sl)
      e += Eraw8[(((long long)sl * Bb + b) * Kk + k) * Dd + d];
    e -= sas[b] * cw[k * Dd + d];
    vals[r] = e; s += e; s2 = fmaf(e, e, s2);
  }
  s = blockSum256(s);
  s2 = blockSum256(s2);
  float mean = s * (1.f / 1024.f);
  float var = fmaxf(s2 * (1.f / 1024.f) - mean * mean, 0.f);
  float rs = rsqrtf(var + 1e-5f);
  #pragma unroll
  for (int r = 0; r < 4; ++r) {
    int i = r * 256 + tid;
    int b = i >> 7, d = i & 127;
    float e = (vals[r] - mean) * rs;
    if (e > 0.f) atomicAdd(&Es[b * Dd + d], e);
  }
}

// gamma = sigmoid(Es @ Wfc^T + bfc); also folds gamma into q (q <- q*gamma)
__global__ __launch_bounds__(256) void gamma_kernel(const float* __restrict__ Es,
    const float* __restrict__ Wfc, const float* __restrict__ bfc,
    float* __restrict__ gam, float* __restrict__ q) {
  int gi = blockIdx.x * 256 + threadIdx.x;
  int b = gi >> 9, c = gi & 511;
  __shared__ float esm[Dd];
  if (threadIdx.x < Dd) esm[threadIdx.x] = Es[b * Dd + threadIdx.x];
  __syncthreads();
  const float* wr = Wfc + c * Dd;
  float acc = bfc[c];
  for (int d = 0; d < Dd; ++d) acc = fmaf(wr[d], esm[d], acc);
  float g = 1.f / (1.f + expf(-acc));
  gam[gi] = g;
  q[gi] *= g;
}

// ---------------- host launcher ----------------
extern "C" void kernel_launch(void* const* d_in, const int* in_sizes, int n_in,
                              void* d_out, int out_size, void* d_ws, size_t ws_size,
                              hipStream_t stream) {
  const float* X   = (const float*)d_in[0];
  const float* Wth = (const float*)d_in[1];
  const float* bth = (const float*)d_in[2];
  const float* Wph = (const float*)d_in[3];
  const float* bph = (const float*)d_in[4];
  const float* Wg  = (const float*)d_in[5];
  const float* bg  = (const float*)d_in[6];
  const float* W2  = (const float*)d_in[7];
  const float* b2v = (const float*)d_in[8];
  const float* W3  = (const float*)d_in[9];
  const float* b3v = (const float*)d_in[10];
  const float* CW  = (const float*)d_in[11];
  const float* SC  = (const float*)d_in[12];
  const float* Wfc = (const float*)d_in[13];
  const float* bfc = (const float*)d_in[14];
  float* out = (float*)d_out;
  float* wsf = (float*)d_ws;

  const long long szL   = (long long)Bb * C1 * C1;   // 524288
  const long long szRA  = (long long)Bb * Cc * Cc;   // 2097152
  const long long szRB  = (long long)Bb * C1 * Cc;   // 1048576
  long long off = 0;
  float* s_   = wsf + off; off += Bb * Cc;
  float* u_   = wsf + off; off += Bb * C1;
  float* v_   = wsf + off; off += Bb * C1;
  float* w_   = wsf + off; off += Bb * C1;
  float* q_   = wsf + off; off += Bb * Cc;
  float* Eraw_= wsf + off; off += (long long)Bb * Kk * Dd;   // legacy slot (unused)
  float* EsL_ = wsf + off; off += Bb * Dd;                   // legacy slot (unused)
  float* Asum_= wsf + off; off += Bb * Kk;                   // legacy slot (unused)
  float* gam_ = wsf + off; off += Bb * Cc;
  float* L_   = wsf + off; off += szL;
  float* regA = wsf + off; off += szRA;
  float* regB = wsf + off; off += szRB;
  const long long baseFloats = off;
  // tail region: G split-K partials, later aliased by zq (pixel-major [B][N][D])
  float* tail = wsf + off;
  const long long ZQ_F  = (long long)Bb * Dd * Nn;      // 9437184
  const long long tailFloats = (long long)(ws_size / 4) - baseFloats;
  const bool big = tailFloats >= ZQ_F;    // big: fp32 zq + splitK=4; small: bf16 zq + splitK=2
  const int numKS = big ? 4 : 2;          // partials: numKS*8*10*16384 floats (5.2M / 2.6M)
  float* part = tail;
  float* zqf  = tail;
  u16*   zqh  = (u16*)tail;
  float* R_   = L_;     // alias: f dead after Mm-GEMM; R born after P-GEMM
  float* zqb_ = u_;     // alias: u dead after softmax
  float* E8_  = regB;                       // 8*8*32*128 = 262144 floats (regB dead post-P)
  float* A8_  = regB + 262144;              // 8*8*32 = 2048 floats
  float* Es_  = regB + 264192;              // 8*128 = 1024 floats (merged memset region)
  (void)Eraw_; (void)Asum_; (void)EsL_;

  const long long strX = (long long)Cc * Nn;
  const long long sG = (long long)Cc * Cc;
  const long long sU = (long long)C1 * Cc;
  const long long sL = (long long)C1 * C1;
  const long long sR = (long long)Dd * Cc;

  // G = X X^T (symmetric): 128x64 tile-pair-half partials -> reduce into regA.
  // Diagonal jh==0 blocks also accumulate X row sums into s_ (rowsum fold).
  hipMemsetAsync(s_, 0, (size_t)(Bb * Cc) * 4, stream);
  gxxt_kernel<<<dim3(20 * numKS * Bb), 256, 0, stream>>>(X, part, numKS, Nn / numKS, s_);
  gred_kernel<<<dim3(10 * Bb), 256, 0, stream>>>(part, regA, numKS);
  // U = Wth @ G -> regB  (M=256 N=512 K=512)
  gemm_mfma<float, 0, false><<<dim3(64), 256, 0, stream>>>(
      Wth, regA, regB, Cc, Cc, 0, sG, sU, nullptr, 0, nullptr, 4, 2);
  gemv2_kernel<<<16, 256, 0, stream>>>(Wth, Wph, s_, u_, v_);
  // L = U @ Wph^T  (small, fp32)
  gemm64<true><<<dim3(4, 4, Bb), 256, 0, stream>>>(
      regB, Wph, L_, C1, C1, Cc, sU, 0, sL, nullptr, 0);
  softmax_kernel<<<Bb * C1, 256, 0, stream>>>(L_, bth, bph, u_, v_, bg, w_);
  // Mm = f @ Wg -> regB (U dead)  (M=256 N=512 K=256)
  gemm_mfma<float, 0, false><<<dim3(64), 256, 0, stream>>>(
      L_, Wg, regB, Cc, C1, sL, 0, sU, nullptr, 0, nullptr, 4, 2);
  q_kernel<<<16, 256, 0, stream>>>(W2, b2v, w_, q_);
  // P' = W2 @ Mm + I -> regA (G dead; identity fused in epilogue)
  gemm_mfma<float, 0, true><<<dim3(128), 256, 0, stream>>>(
      W2, regB, regA, Cc, C1, 0, sU, sG, nullptr, 0, nullptr, 4, 4);
  // regB dead: becomes 8-slot enc accumulators + Es (one merged memset)
  hipMemsetAsync(regB, 0, (size_t)(262144 + 2048 + 1024) * 4, stream);
  // R = W3 @ P' -> R_ (alias L_)  (M=128 N=512 K=512) ; zq bias = W3 q + b3
  gemm_mfma<float, 0, false><<<dim3(32), 256, 0, stream>>>(
      W3, regA, R_, Cc, Cc, 0, sG, sR, nullptr, 0, nullptr, 4, 1);
  zqbias_kernel<<<4, 256, 0, stream>>>(W3, b3v, q_, zqb_);
  // zq = R @ X + zqb, stored pixel-major [B][N][D]  (partials dead -> tail reused)
  if (big) {
    gemm_mfma<float, 1, false><<<dim3(576), 256, 0, stream>>>(
        R_, X, zqf, Nn, Cc, sR, strX, (long long)Dd * Nn, zqb_, Dd, nullptr, 72, 1);
    enc_kernel<float><<<dim3(36, Bb), 256, 0, stream>>>(zqf, CW, SC, E8_, A8_);
  } else {
    gemm_mfma<u16, 1, false><<<dim3(576), 256, 0, stream>>>(
        R_, X, zqh, Nn, Cc, sR, strX, (long long)Dd * Nn, zqb_, Dd, nullptr, 72, 1);
    enc_kernel<u16><<<dim3(36, Bb), 256, 0, stream>>>(zqh, CW, SC, E8_, A8_);
  }
  bn_kernel<<<Kk, 256, 0, stream>>>(E8_, A8_, CW, Es_);
  gamma_kernel<<<16, 256, 0, stream>>>(Es_, Wfc, bfc, gam_, q_);   // q <- q*gamma
  // z*gamma = (gamma.P') @ X + (gamma.q) -> out  (gamma applied in A-staging)
  gemm_mfma<float, 0, false><<<dim3(2304), 256, 0, stream>>>(
      regA, X, out, Nn, Cc, sG, strX, strX, q_, Cc, gam_, 72, 4);
  (void)in_sizes; (void)n_in; (void)out_size;
}

// Round 11
// 943.291 us; speedup vs baseline: 1.5448x; 1.0045x over previous
//
#include <hip/hip_runtime.h>

// NLCE: non-local (channel attention) + Deep-TEN encoding, B=8 C=512 C1=256 D=128 K=32 N=9216.
// All inputs/outputs fp32. Big GEMMs on matrix cores via 2-limb bf16 split
// (hi/lo via v_cvt_pk_bf16_f32; products hi*hi+hi*lo+lo*hi, ~1e-5 rel).
// Round 11: revert round-10 B-LDS pad (measured +20us z regression, conflicts UP);
// keep the fusion package (gamma into z-GEMM A-staging, rowsum into gxxt diag
// blocks, merged memsets, gxxt numKS=4). LDS layout = round-9 (best measured z).

typedef unsigned short u16;

#define Bb 8
#define Cc 512
#define C1 256
#define Dd 128
#define Kk 32
#define Nn 9216

typedef __attribute__((ext_vector_type(8))) short short8v;
typedef __attribute__((ext_vector_type(4))) short short4v;
typedef __attribute__((ext_vector_type(4))) float f32x4;

__device__ __forceinline__ float b2f(u16 u) {
  union { unsigned int i; float f; } v; v.i = ((unsigned int)u) << 16; return v.f;
}
__device__ __forceinline__ u16 f2b(float f) {
  union { float f; unsigned int i; } v; v.f = f;
  unsigned int x = v.i;
  return (u16)((x + 0x7fffu + ((x >> 16) & 1u)) >> 16);  // RNE
}

__device__ __forceinline__ float4 load4(const float* p) { return *(const float4*)p; }
__device__ __forceinline__ float4 load4(const u16* p) {
  ushort4 q = *(const ushort4*)p;
  return make_float4(b2f(q.x), b2f(q.y), b2f(q.z), b2f(q.w));
}
__device__ __forceinline__ void store4(float* p, float a, float b, float c, float d) {
  *(float4*)p = make_float4(a, b, c, d);
}

__device__ __forceinline__ float waveSum(float v) {
  #pragma unroll
  for (int o = 32; o > 0; o >>= 1) v += __shfl_xor(v, o);
  return v;
}
__device__ __forceinline__ float waveMax(float v) {
  #pragma unroll
  for (int o = 32; o > 0; o >>= 1) v = fmaxf(v, __shfl_xor(v, o));
  return v;
}
__device__ __forceinline__ float blockSum256(float v) {
  __shared__ float sm[4];
  v = waveSum(v);
  if ((threadIdx.x & 63) == 0) sm[threadIdx.x >> 6] = v;
  __syncthreads();
  float r = sm[0] + sm[1] + sm[2] + sm[3];
  __syncthreads();
  return r;
}
__device__ __forceinline__ float blockMax256(float v) {
  __shared__ float sm[4];
  v = waveMax(v);
  if ((threadIdx.x & 63) == 0) sm[threadIdx.x >> 6] = v;
  __syncthreads();
  float r = fmaxf(fmaxf(sm[0], sm[1]), fmaxf(sm[2], sm[3]));
  __syncthreads();
  return r;
}

// ---------------- MFMA split-bf16 common ----------------
__device__ __forceinline__ f32x4 mfma_bf16_16x16x32(short8v a, short8v b, f32x4 c) {
  asm("v_mfma_f32_16x16x32_bf16 %0, %1, %2, %0" : "+v"(c) : "v"(a), "v"(b));
  return c;
}

__device__ __forceinline__ int fsw(int r) { return (r ^ (r >> 2) ^ (r >> 4)) & 3; }

// 2 floats -> packed bf16 hi limbs (h) and lo limbs (l), 1 cvt_pk each + exact residual
__device__ __forceinline__ void cvt2(float x0, float x1, unsigned int& h, unsigned int& l) {
  asm("v_cvt_pk_bf16_f32 %0, %1, %2" : "=v"(h) : "v"(x0), "v"(x1));
  union { unsigned int u; float f; } fa, fb;
  fa.u = h << 16; fb.u = h & 0xffff0000u;
  float r0 = x0 - fa.f, r1 = x1 - fb.f;
  asm("v_cvt_pk_bf16_f32 %0, %1, %2" : "=v"(l) : "v"(r0), "v"(r1));
}

__device__ __forceinline__ void storeC4(float* p, float4 v) { *(float4*)p = v; }
__device__ __forceinline__ void storeC4(u16* p, float4 v) {
  ushort4 q; q.x = f2b(v.x); q.y = f2b(v.y); q.z = f2b(v.z); q.w = f2b(v.w);
  *(ushort4*)p = q;
}

// ---------------- generic MFMA GEMM (BN=128) ----------------
// C[b] = A[b] @ B[b]; fp32 in, TO out, 2-limb bf16 MFMA inside.
// BM = 128, BN = 128, BK = 32. 256 threads = 4 waves (2x2), wave tile 64x64.
// OMODE 0: row-major C[M][N], +biasRow[gr]; ADDI adds identity (gr==gc).
// OMODE 1: transposed C[N][128] (requires gny==1, M==128), +biasRow[d].
// scaleA: per-A-row scale (stride sBias), applied during staging (gamma fold).
template<typename TO, int OMODE, bool ADDI>
__global__ __launch_bounds__(256, 3) void gemm_mfma(
    const float* __restrict__ A, const float* __restrict__ B, TO* __restrict__ C,
    int N, int K,
    long long sA, long long sB, long long sC,
    const float* __restrict__ biasRow, long long sBias,
    const float* __restrict__ scaleA,
    int gnx, int gny)
{
  // element (row,k) at column ((k>>3) ^ fsw(row))*8 + (k&7); stride 40 ushorts (80 B,
  // multiple of 16 -> b128-aligned frag reads).
  __shared__ __align__(16) u16 Asm_[2][128][40];
  __shared__ __align__(16) u16 Bsm_[2][128][40];

  int id = blockIdx.x;
  {
    const int nwg = gridDim.x;
    if ((nwg & 7) == 0) id = (id & 7) * (nwg >> 3) + (id >> 3);  // XCD chunk swizzle
  }
  const int per = gnx * gny;
  const int b = id / per;
  const int rem = id - b * per;
  const int by = rem % gny;        // m-block fastest
  const int bx = rem / gny;        // n-block
  A += b * sA; B += b * sB; C += b * sC;
  const int m0 = by * 128, n0 = bx * 128;

  const int t = threadIdx.x;
  const int w = t >> 6, lane = t & 63;
  const int wr = w >> 1, wc = w & 1;
  const int lr = lane & 15, lq = lane >> 4;

  const int sar = t >> 1, sak = (t & 1) * 16;   // A staging: 128 rows x 32 k
  const int kg2 = t >> 4, ng = t & 15;          // B staging: 2 k-rows x 8 n per thread

  const float gA = scaleA ? scaleA[b * sBias + m0 + sar] : 1.f;

  float ra[16];
  float rb[16];

  auto loadA = [&](int k0) {
    const float* p = A + (long long)(m0 + sar) * K + (k0 + sak);
    #pragma unroll
    for (int i = 0; i < 4; ++i) {
      float4 v = *(const float4*)(p + i * 4);
      ra[i*4+0] = v.x; ra[i*4+1] = v.y; ra[i*4+2] = v.z; ra[i*4+3] = v.w;
    }
  };
  auto loadB = [&](int k0) {
    const float* p = B + (long long)(k0 + kg2 * 2) * N + (n0 + ng * 8);
    #pragma unroll
    for (int i = 0; i < 2; ++i) {
      float4 v0 = *(const float4*)(p + (long long)i * N);
      float4 v1 = *(const float4*)(p + (long long)i * N + 4);
      rb[i*8+0]=v0.x; rb[i*8+1]=v0.y; rb[i*8+2]=v0.z; rb[i*8+3]=v0.w;
      rb[i*8+4]=v1.x; rb[i*8+5]=v1.y; rb[i*8+6]=v1.z; rb[i*8+7]=v1.w;
    }
  };

  auto stage = [&]() {
    {   // A rows sar, k-local sak..sak+15 -> two swizzled 8-blocks (x gA)
      const int f = fsw(sar);
      #pragma unroll
      for (int h = 0; h < 2; ++h) {
        const int col = ((((sak >> 3) + h) ^ f) << 3);
        union { unsigned int u[4]; short8v v; } H, L;
        #pragma unroll
        for (int p = 0; p < 4; ++p)
          cvt2(ra[h*8+2*p] * gA, ra[h*8+2*p+1] * gA, H.u[p], L.u[p]);
        *(short8v*)&Asm_[0][sar][col] = H.v;
        *(short8v*)&Asm_[1][sar][col] = L.v;
      }
    }
    {   // B: 2 consecutive k per n, one u32 write per limb per n
      const int blk = kg2 >> 2, sub = 2 * (kg2 & 3);
      #pragma unroll
      for (int j = 0; j < 8; ++j) {
        const int n = ng * 8 + j;
        const int col = ((blk ^ fsw(n)) << 3) + sub;
        unsigned int H, L;
        cvt2(rb[j], rb[8 + j], H, L);
        *(unsigned int*)&Bsm_[0][n][col] = H;
        *(unsigned int*)&Bsm_[1][n][col] = L;
      }
    }
  };

  f32x4 acc[4][4];
  #pragma unroll
  for (int im = 0; im < 4; ++im)
    #pragma unroll
    for (int in = 0; in < 4; ++in)
      acc[im][in] = f32x4{0.f, 0.f, 0.f, 0.f};

  loadA(0); loadB(0);
  for (int k0 = 0; k0 < K; k0 += 32) {
    stage();
    if (k0 + 32 < K) { loadA(k0 + 32); loadB(k0 + 32); }
    __syncthreads();
    short8v af[2][4];
    #pragma unroll
    for (int im = 0; im < 4; ++im) {
      const int r = wr * 64 + im * 16 + lr;
      const int col = ((lq ^ fsw(r)) << 3);
      af[0][im] = *(const short8v*)&Asm_[0][r][col];
      af[1][im] = *(const short8v*)&Asm_[1][r][col];
    }
    #pragma unroll
    for (int in = 0; in < 4; ++in) {
      const int rB = wc * 64 + in * 16 + lr;
      const int colB = ((lq ^ fsw(rB)) << 3);
      short8v bh = *(const short8v*)&Bsm_[0][rB][colB];
      short8v bl = *(const short8v*)&Bsm_[1][rB][colB];
      #pragma unroll
      for (int im = 0; im < 4; ++im) {
        acc[im][in] = mfma_bf16_16x16x32(af[0][im], bh, acc[im][in]);  // hi*hi
        acc[im][in] = mfma_bf16_16x16x32(af[0][im], bl, acc[im][in]);  // hi*lo
        acc[im][in] = mfma_bf16_16x16x32(af[1][im], bh, acc[im][in]);  // lo*hi
      }
    }
    __syncthreads();
  }
  asm volatile("s_nop 7\n\ts_nop 7\n\ts_nop 7");  // MFMA->VALU/VMEM read hazard guard

  if constexpr (OMODE == 1) {
    // transposed store: C[n][128]; d = wr*64+im*16+lq*4+{0..3} contiguous per lane
    const float* bb = biasRow + (long long)b * sBias;
    #pragma unroll
    for (int im = 0; im < 4; ++im) {
      #pragma unroll
      for (int in = 0; in < 4; ++in) {
        const f32x4 a = acc[im][in];
        const int gc = n0 + wc * 64 + in * 16 + lr;
        const int d0b = wr * 64 + im * 16 + lq * 4;
        float4 v = make_float4(a[0] + bb[d0b + 0], a[1] + bb[d0b + 1],
                               a[2] + bb[d0b + 2], a[3] + bb[d0b + 3]);
        storeC4(&C[(long long)gc * Dd + d0b], v);
      }
    }
  } else {
    #pragma unroll
    for (int im = 0; im < 4; ++im) {
      #pragma unroll
      for (int in = 0; in < 4; ++in) {
        const f32x4 a = acc[im][in];
        const int gc = n0 + wc * 64 + in * 16 + lr;   // C/D: col = lane&15
        #pragma unroll
        for (int p = 0; p < 4; ++p) {
          const int gr = m0 + wr * 64 + im * 16 + lq * 4 + p;  // row = (lane>>4)*4+reg
          float v = a[p];
          if (biasRow) v += biasRow[b * sBias + gr];
          if (ADDI && gr == gc) v += 1.f;
          C[(long long)gr * N + gc] = v;
        }
      }
    }
  }
}

// ---------------- G = X X^T, symmetric, split-K partials (no atomics) --------
// 128x64 blocks: pair selects (i-tile, j-tile), jh selects column half of j-tile.
// Diag/jh==0 blocks also accumulate row sums of X into sOut (rowsum fold).
__device__ __constant__ int PIa[10] = {0,0,0,0,1,1,1,2,2,3};
__device__ __constant__ int PJa[10] = {0,1,2,3,1,2,3,2,3,3};

__global__ __launch_bounds__(256, 3) void gxxt_kernel(
    const float* __restrict__ X, float* __restrict__ part,
    int numKS, int kChunk, float* __restrict__ sOut)
{
  __shared__ __align__(16) u16 Asm_[2][128][40];
  __shared__ __align__(16) u16 Bsm_[2][64][40];

  int id = blockIdx.x;
  {
    const int nwg = gridDim.x;
    if ((nwg & 7) == 0) id = (id & 7) * (nwg >> 3) + (id >> 3);  // one batch per XCD
  }
  const int sub = id % 20;
  const int pair = sub >> 1, jh = sub & 1;
  const int rest = id / 20;
  const int ks = rest % numKS;
  const int b = rest / numKS;
  const int i0 = PIa[pair] * 128, j0 = PJa[pair] * 128;
  const bool same = (i0 == j0);
  const bool doSum = same && (jh == 0);
  const float* Xb = X + (long long)b * Cc * Nn;
  const int kBeg = ks * kChunk, kEnd = kBeg + kChunk;

  const int t = threadIdx.x;
  const int w = t >> 6, lane = t & 63;
  const int wr = w >> 1, wc = w & 1;
  const int lr = lane & 15, lq = lane >> 4;
  const int sar = t >> 1, sak = (t & 1) * 16;   // A: 128 rows x 32 k
  const int sbr = t >> 2, sbk = (t & 3) * 8;    // B: 64 rows x 32 k (8 k per thread)

  float ra[16], rb[8];
  float rs = 0.f;

  auto loadA = [&](int k0) {
    const float* p = Xb + (long long)(i0 + sar) * Nn + (k0 + sak);
    #pragma unroll
    for (int i = 0; i < 4; ++i) {
      float4 v = *(const float4*)(p + i * 4);
      ra[i*4+0] = v.x; ra[i*4+1] = v.y; ra[i*4+2] = v.z; ra[i*4+3] = v.w;
    }
  };
  auto loadB = [&](int k0) {
    const float* p = Xb + (long long)(j0 + jh * 64 + sbr) * Nn + (k0 + sbk);
    float4 v0 = *(const float4*)(p);
    float4 v1 = *(const float4*)(p + 4);
    rb[0]=v0.x; rb[1]=v0.y; rb[2]=v0.z; rb[3]=v0.w;
    rb[4]=v1.x; rb[5]=v1.y; rb[6]=v1.z; rb[7]=v1.w;
  };
  auto stageA = [&]() {
    const int f = fsw(sar);
    #pragma unroll
    for (int h = 0; h < 2; ++h) {
      const int col = ((((sak >> 3) + h) ^ f) << 3);
      union { unsigned int u[4]; short8v v; } Hv, Lv;
      #pragma unroll
      for (int p = 0; p < 4; ++p) cvt2(ra[h*8+2*p], ra[h*8+2*p+1], Hv.u[p], Lv.u[p]);
      *(short8v*)&Asm_[0][sar][col] = Hv.v;
      *(short8v*)&Asm_[1][sar][col] = Lv.v;
    }
  };
  auto stageB = [&]() {
    const int col = (((sbk >> 3) ^ fsw(sbr)) << 3);
    union { unsigned int u[4]; short8v v; } Hv, Lv;
    #pragma unroll
    for (int p = 0; p < 4; ++p) cvt2(rb[2*p], rb[2*p+1], Hv.u[p], Lv.u[p]);
    *(short8v*)&Bsm_[0][sbr][col] = Hv.v;
    *(short8v*)&Bsm_[1][sbr][col] = Lv.v;
  };

  f32x4 acc[4][2];
  #pragma unroll
  for (int im = 0; im < 4; ++im)
    #pragma unroll
    for (int in = 0; in < 2; ++in)
      acc[im][in] = f32x4{0.f, 0.f, 0.f, 0.f};

  loadA(kBeg);
  if (!same) loadB(kBeg);
  for (int k0 = kBeg; k0 < kEnd; k0 += 32) {
    if (doSum) {
      #pragma unroll
      for (int j = 0; j < 16; ++j) rs += ra[j];
    }
    stageA();
    if (!same) stageB();
    if (k0 + 32 < kEnd) { loadA(k0 + 32); if (!same) loadB(k0 + 32); }
    __syncthreads();
    short8v af[2][4];
    #pragma unroll
    for (int im = 0; im < 4; ++im) {
      const int r = wr * 64 + im * 16 + lr;
      const int col = ((lq ^ fsw(r)) << 3);
      af[0][im] = *(const short8v*)&Asm_[0][r][col];
      af[1][im] = *(const short8v*)&Asm_[1][r][col];
    }
    #pragma unroll
    for (int in = 0; in < 2; ++in) {
      const int rloc = wc * 32 + in * 16 + lr;
      short8v bh, bl;
      if (same) {
        const int r = jh * 64 + rloc;
        const int colB = ((lq ^ fsw(r)) << 3);
        bh = *(const short8v*)&Asm_[0][r][colB];
        bl = *(const short8v*)&Asm_[1][r][colB];
      } else {
        const int colB = ((lq ^ fsw(rloc)) << 3);
        bh = *(const short8v*)&Bsm_[0][rloc][colB];
        bl = *(const short8v*)&Bsm_[1][rloc][colB];
      }
      #pragma unroll
      for (int im = 0; im < 4; ++im) {
        acc[im][in] = mfma_bf16_16x16x32(af[0][im], bh, acc[im][in]);
        acc[im][in] = mfma_bf16_16x16x32(af[0][im], bl, acc[im][in]);
        acc[im][in] = mfma_bf16_16x16x32(af[1][im], bh, acc[im][in]);
      }
    }
    __syncthreads();
  }
  asm volatile("s_nop 7\n\ts_nop 7\n\ts_nop 7");

  if (doSum) atomicAdd(&sOut[b * Cc + i0 + sar], rs);

  float* Cp = part + ((long long)(ks * Bb + b) * 10 + pair) * 16384 + jh * 64;
  #pragma unroll
  for (int im = 0; im < 4; ++im) {
    #pragma unroll
    for (int in = 0; in < 2; ++in) {
      const f32x4 a = acc[im][in];
      const int gc = wc * 32 + in * 16 + lr;
      #pragma unroll
      for (int p = 0; p < 4; ++p) {
        const int gr = wr * 64 + im * 16 + lq * 4 + p;
        Cp[gr * 128 + gc] = a[p];
      }
    }
  }
}

// Reduce partials -> G (both triangles). One block per (b, pair).
__global__ __launch_bounds__(256) void gred_kernel(const float* __restrict__ part,
    float* __restrict__ G, int numKS) {
  __shared__ float sm[64][129];
  const int pair = blockIdx.x % 10, b = blockIdx.x / 10;
  const int i0 = PIa[pair] * 128, j0 = PJa[pair] * 128;
  float* Gb = G + (long long)b * Cc * Cc;
  const long long ksStr = (long long)Bb * 10 * 16384;
  const float* p0 = part + ((long long)b * 10 + pair) * 16384;
  const int t = threadIdx.x;
  for (int half = 0; half < 2; ++half) {
    const int r0 = half * 64;
    __syncthreads();
    for (int rep = 0; rep < 32; ++rep) {
      int idx = r0 * 128 + rep * 256 + t;
      float s = 0.f;
      for (int ks = 0; ks < numKS; ++ks) s += p0[(long long)ks * ksStr + idx];
      int r = (idx >> 7) - r0, c = idx & 127;
      sm[r][c] = s;
      Gb[(long long)(i0 + r0 + r) * Cc + (j0 + c)] = s;
    }
    if (i0 != j0) {
      __syncthreads();
      for (int rep = 0; rep < 32; ++rep) {
        int o = rep * 256 + t;
        int rr = o >> 6, cc = o & 63;
        Gb[(long long)(j0 + rr) * Cc + (i0 + r0 + cc)] = sm[cc][rr];
      }
    }
  }
}

// ---------------- generic 64x64 tiled GEMM, fp32 (L only) ----------------
template<bool TRANSB>
__global__ __launch_bounds__(256) void gemm64(
    const float* __restrict__ A, const float* __restrict__ B, float* __restrict__ C,
    int M, int N, int K,
    long long sA, long long sB, long long sC,
    const float* __restrict__ biasRow, long long sBias)
{
  const int bz = blockIdx.z;
  A += (long long)bz * sA;
  B += (long long)bz * sB;
  C += (long long)bz * sC;
  const int m0 = blockIdx.y * 64, n0 = blockIdx.x * 64;
  __shared__ __align__(16) float As[16][64];
  __shared__ __align__(16) float Bs[16][64];
  const int t = threadIdx.x;
  const int lr = t >> 2, lk = (t & 3) << 2;
  const int tm = (t >> 4) << 2, tn = (t & 15) << 2;
  float acc[4][4] = {};
  for (int k0 = 0; k0 < K; k0 += 16) {
    {
      float4 a = load4(A + (long long)(m0 + lr) * K + (k0 + lk));
      As[lk + 0][lr] = a.x; As[lk + 1][lr] = a.y; As[lk + 2][lr] = a.z; As[lk + 3][lr] = a.w;
    }
    if (TRANSB) {
      float4 b = load4(B + (long long)(n0 + lr) * K + (k0 + lk));
      Bs[lk + 0][lr] = b.x; Bs[lk + 1][lr] = b.y; Bs[lk + 2][lr] = b.z; Bs[lk + 3][lr] = b.w;
    } else {
      const int kr = t >> 4, nc = (t & 15) << 2;
      float4 b = load4(B + (long long)(k0 + kr) * N + (n0 + nc));
      *(float4*)&Bs[kr][nc] = b;
    }
    __syncthreads();
    #pragma unroll
    for (int kk = 0; kk < 16; ++kk) {
      const float4 av = *(const float4*)&As[kk][tm];
      const float4 bv = *(const float4*)&Bs[kk][tn];
      acc[0][0] = fmaf(av.x, bv.x, acc[0][0]);
      acc[0][1] = fmaf(av.x, bv.y, acc[0][1]);
      acc[0][2] = fmaf(av.x, bv.z, acc[0][2]);
      acc[0][3] = fmaf(av.x, bv.w, acc[0][3]);
      acc[1][0] = fmaf(av.y, bv.x, acc[1][0]);
      acc[1][1] = fmaf(av.y, bv.y, acc[1][1]);
      acc[1][2] = fmaf(av.y, bv.z, acc[1][2]);
      acc[1][3] = fmaf(av.y, bv.w, acc[1][3]);
      acc[2][0] = fmaf(av.z, bv.x, acc[2][0]);
      acc[2][1] = fmaf(av.z, bv.y, acc[2][1]);
      acc[2][2] = fmaf(av.z, bv.z, acc[2][2]);
      acc[2][3] = fmaf(av.z, bv.w, acc[2][3]);
      acc[3][0] = fmaf(av.w, bv.x, acc[3][0]);
      acc[3][1] = fmaf(av.w, bv.y, acc[3][1]);
      acc[3][2] = fmaf(av.w, bv.z, acc[3][2]);
      acc[3][3] = fmaf(av.w, bv.w, acc[3][3]);
    }
    __syncthreads();
  }
  #pragma unroll
  for (int i = 0; i < 4; ++i) {
    const int m = m0 + tm + i;
    float bias = biasRow ? biasRow[bz * sBias + m] : 0.f;
    store4(C + (long long)m * N + (n0 + tn),
           acc[i][0] + bias, acc[i][1] + bias, acc[i][2] + bias, acc[i][3] + bias);
  }
}

// ---------------- small kernels ----------------
// u[b,i] = sum Wth[i,:]*s[b,:]  (sel 0), v[b,i] = sum Wph[i,:]*s[b,:] (sel 1)
__global__ __launch_bounds__(256) void gemv2_kernel(const float* __restrict__ Wth,
    const float* __restrict__ Wph, const float* __restrict__ s,
    float* __restrict__ u, float* __restrict__ v) {
  int b = blockIdx.x & 7, sel = blockIdx.x >> 3;
  const float* W = sel ? Wph : Wth;
  float* out = sel ? v : u;
  __shared__ float ssm[Cc];
  for (int i = threadIdx.x; i < Cc; i += 256) ssm[i] = s[b * Cc + i];
  __syncthreads();
  int i = threadIdx.x;
  const float* wr = W + i * Cc;
  float acc = 0.f;
  for (int k = 0; k < Cc; ++k) acc = fmaf(wr[k], ssm[k], acc);
  out[b * C1 + i] = acc;
}

// softmax over rows of L with bias terms; also emits w[b,i] = sum_j f * bg[j]
__global__ __launch_bounds__(256) void softmax_kernel(float* __restrict__ L,
    const float* __restrict__ bth, const float* __restrict__ bph,
    const float* __restrict__ u, const float* __restrict__ v,
    const float* __restrict__ bg, float* __restrict__ w) {
  __shared__ float bgs[C1];
  int row = blockIdx.x;                 // b*256 + i
  int b = row >> 8, i = row & 255;
  int j = threadIdx.x;
  bgs[j] = bg[j];
  float bt = bth[i], bp = bph[j];
  long long idx = (long long)row * C1 + j;
  float val = L[idx] + bt * v[b * C1 + j] + u[b * C1 + i] * bp + (float)Nn * bt * bp;
  float mx = blockMax256(val);
  float p = expf(val - mx);
  float sm = blockSum256(p);
  float f = p / sm;
  L[idx] = f;
  float ws = blockSum256(f * bgs[j]);
  if (j == 0) w[row] = ws;
}

__global__ __launch_bounds__(256) void q_kernel(const float* __restrict__ W2,
                                                const float* __restrict__ b2v,
                                                const float* __restrict__ w,
                                                float* __restrict__ q) {
  int gi = blockIdx.x * 256 + threadIdx.x;
  int b = gi >> 9, c = gi & 511;
  __shared__ float wsm[C1];
  wsm[threadIdx.x] = w[b * C1 + threadIdx.x];
  __syncthreads();
  const float* wr = W2 + c * C1;
  float acc = b2v[c];
  for (int i = 0; i < C1; ++i) acc = fmaf(wr[i], wsm[i], acc);
  q[gi] = acc;
}

// zqb[b][d] = b3[d] + sum_c W3[d][c] * q[b][c]
__global__ __launch_bounds__(256) void zqbias_kernel(const float* __restrict__ W3,
    const float* __restrict__ b3, const float* __restrict__ q, float* __restrict__ zqb) {
  int gi = blockIdx.x * 256 + threadIdx.x;   // [0, 1024)
  int b = gi >> 7, d = gi & 127;
  const float* wr = W3 + d * Cc;
  const float* qr = q + b * Cc;
  float acc = b3[d];
  for (int c = 0; c < Cc; ++c) acc = fmaf(wr[c], qr[c], acc);
  zqb[gi] = acc;
}

// Deep-TEN soft-assign + aggregation. zq is PIXEL-MAJOR [B][N][D].
// Eraw8/Asum8: 8-slot replicated accumulators (slot = n-tile & 7) to cut atomic contention.
template<typename ZT>
__global__ __launch_bounds__(256) void enc_kernel(
    const ZT* __restrict__ zq,      // [B][N][D]
    const float* __restrict__ cw,   // [K][D]
    const float* __restrict__ sc,   // [K]
    float* __restrict__ Eraw8,      // [8][B][K][D] pre-zeroed
    float* __restrict__ Asum8)      // [8][B][K]    pre-zeroed
{
  __shared__ float csm[Kk][Dd + 1];
  __shared__ float cc[Kk], ssm[Kk];
  __shared__ float sA[Kk][256 + 1];
  __shared__ float zs[16][Dd + 4];
  const int tid = threadIdx.x;
  const int b = blockIdx.y;
  const int slot = blockIdx.x & 7;
  const int n0 = blockIdx.x * 256;

  #pragma unroll
  for (int r = 0; r < 16; ++r) {
    int idx = r * 256 + tid;
    csm[idx >> 7][idx & 127] = cw[idx];
  }
  if (tid < Kk) ssm[tid] = sc[tid];
  __syncthreads();
  if (tid < Kk) {
    float a = 0.f;
    for (int d = 0; d < Dd; ++d) { float cv = csm[tid][d]; a = fmaf(cv, cv, a); }
    cc[tid] = a;
  }
  __syncthreads();

  // pass 1: one pixel per thread, contiguous row read
  const ZT* zrow = zq + ((long long)b * Nn + n0 + tid) * Dd;
  float dots[Kk];
  #pragma unroll
  for (int k = 0; k < Kk; ++k) dots[k] = 0.f;
  float xx = 0.f;
  for (int d = 0; d < Dd; d += 4) {
    float4 xv = load4(zrow + d);
    xx = fmaf(xv.x, xv.x, xx); xx = fmaf(xv.y, xv.y, xx);
    xx = fmaf(xv.z, xv.z, xx); xx = fmaf(xv.w, xv.w, xx);
    #pragma unroll
    for (int k = 0; k < Kk; ++k) {
      float dk = dots[k];
      dk = fmaf(csm[k][d + 0], xv.x, dk);
      dk = fmaf(csm[k][d + 1], xv.y, dk);
      dk = fmaf(csm[k][d + 2], xv.z, dk);
      dk = fmaf(csm[k][d + 3], xv.w, dk);
      dots[k] = dk;
    }
  }
  float mx = -1e30f;
  #pragma unroll
  for (int k = 0; k < Kk; ++k) {
    float l = ssm[k] * (xx - 2.f * dots[k] + cc[k]);
    dots[k] = l;
    mx = fmaxf(mx, l);
  }
  float sum = 0.f;
  #pragma unroll
  for (int k = 0; k < Kk; ++k) { float p = expf(dots[k] - mx); dots[k] = p; sum += p; }
  float inv = 1.f / sum;
  #pragma unroll
  for (int k = 0; k < Kk; ++k) sA[k][tid] = dots[k] * inv;
  __syncthreads();
  if (tid < Kk) {
    float s = 0.f;
    for (int p = 0; p < 256; ++p) s += sA[tid][p];
    atomicAdd(&Asum8[((long long)slot * Bb + b) * Kk + tid], s);
  }

  // pass 2: E_part[k][d0..d0+15] over this tile's 256 pixels (16 px per stage)
  float acc[16];
  #pragma unroll
  for (int j = 0; j < 16; ++j) acc[j] = 0.f;
  const int k = tid & 31, d0 = (tid >> 5) * 16;
  const int spx = tid >> 4, sd = (tid & 15) * 8;   // staging: 16 px x 128 d, coalesced
  for (int it = 0; it < 16; ++it) {
    __syncthreads();
    {
      const ZT* src = zq + ((long long)b * Nn + n0 + it * 16 + spx) * Dd + sd;
      float4 a4 = load4(src);
      float4 b4 = load4(src + 4);
      *(float4*)&zs[spx][sd] = a4;
      *(float4*)&zs[spx][sd + 4] = b4;
    }
    __syncthreads();
    #pragma unroll
    for (int p = 0; p < 16; ++p) {
      float a = sA[k][it * 16 + p];
      #pragma unroll
      for (int j = 0; j < 16; ++j) acc[j] = fmaf(a, zs[p][d0 + j], acc[j]);
    }
  }
  float* Ep = Eraw8 + (((long long)slot * Bb + b) * Kk + k) * Dd + d0;
  #pragma unroll
  for (int j = 0; j < 16; ++j) atomicAdd(Ep + j, acc[j]);
}

// per-k BN over (b,d) with 8-slot reduction, relu, Es[b,d] += e
__global__ __launch_bounds__(256) void bn_kernel(const float* __restrict__ Eraw8,
    const float* __restrict__ Asum8, const float* __restrict__ cw, float* __restrict__ Es) {
  __shared__ float sas[8];
  int k = blockIdx.x, tid = threadIdx.x;
  if (tid < 8) {
    float a = 0.f;
    for (int sl = 0; sl < 8; ++sl) a += Asum8[((long long)sl * Bb + tid) * Kk + k];
    sas[tid] = a;
  }
  __syncthreads();
  float vals[4], s = 0.f, s2 = 0.f;
  #pragma unroll
  for (int r = 0; r < 4; ++r) {
    int i = r * 256 + tid;
    int b = i >> 7, d = i & 127;
    float e = 0.f;
    for (int sl = 0; sl < 8; ++sl)
      e += Eraw8[(((long long)sl * Bb + b) * Kk + k) * Dd + d];
    e -= sas[b] * cw[k * Dd + d];
    vals[r] = e; s += e; s2 = fmaf(e, e, s2);
  }
  s = blockSum256(s);
  s2 = blockSum256(s2);
  float mean = s * (1.f / 1024.f);
  float var = fmaxf(s2 * (1.f / 1024.f) - mean * mean, 0.f);
  float rs = rsqrtf(var + 1e-5f);
  #pragma unroll
  for (int r = 0; r < 4; ++r) {
    int i = r * 256 + tid;
    int b = i >> 7, d = i & 127;
    float e = (vals[r] - mean) * rs;
    if (e > 0.f) atomicAdd(&Es[b * Dd + d], e);
  }
}

// gamma = sigmoid(Es @ Wfc^T + bfc); also folds gamma into q (q <- q*gamma)
__global__ __launch_bounds__(256) void gamma_kernel(const float* __restrict__ Es,
    const float* __restrict__ Wfc, const float* __restrict__ bfc,
    float* __restrict__ gam, float* __restrict__ q) {
  int gi = blockIdx.x * 256 + threadIdx.x;
  int b = gi >> 9, c = gi & 511;
  __shared__ float esm[Dd];
  if (threadIdx.x < Dd) esm[threadIdx.x] = Es[b * Dd + threadIdx.x];
  __syncthreads();
  const float* wr = Wfc + c * Dd;
  float acc = bfc[c];
  for (int d = 0; d < Dd; ++d) acc = fmaf(wr[d], esm[d], acc);
  float g = 1.f / (1.f + expf(-acc));
  gam[gi] = g;
  q[gi] *= g;
}

// ---------------- host launcher ----------------
extern "C" void kernel_launch(void* const* d_in, const int* in_sizes, int n_in,
                              void* d_out, int out_size, void* d_ws, size_t ws_size,
                              hipStream_t stream) {
  const float* X   = (const float*)d_in[0];
  const float* Wth = (const float*)d_in[1];
  const float* bth = (const float*)d_in[2];
  const float* Wph = (const float*)d_in[3];
  const float* bph = (const float*)d_in[4];
  const float* Wg  = (const float*)d_in[5];
  const float* bg  = (const float*)d_in[6];
  const float* W2  = (const float*)d_in[7];
  const float* b2v = (const float*)d_in[8];
  const float* W3  = (const float*)d_in[9];
  const float* b3v = (const float*)d_in[10];
  const float* CW  = (const float*)d_in[11];
  const float* SC  = (const float*)d_in[12];
  const float* Wfc = (const float*)d_in[13];
  const float* bfc = (const float*)d_in[14];
  float* out = (float*)d_out;
  float* wsf = (float*)d_ws;

  const long long szL   = (long long)Bb * C1 * C1;   // 524288
  const long long szRA  = (long long)Bb * Cc * Cc;   // 2097152
  const long long szRB  = (long long)Bb * C1 * Cc;   // 1048576
  long long off = 0;
  float* s_   = wsf + off; off += Bb * Cc;
  float* u_   = wsf + off; off += Bb * C1;
  float* v_   = wsf + off; off += Bb * C1;
  float* w_   = wsf + off; off += Bb * C1;
  float* q_   = wsf + off; off += Bb * Cc;
  float* Eraw_= wsf + off; off += (long long)Bb * Kk * Dd;   // legacy slot (unused)
  float* EsL_ = wsf + off; off += Bb * Dd;                   // legacy slot (unused)
  float* Asum_= wsf + off; off += Bb * Kk;                   // legacy slot (unused)
  float* gam_ = wsf + off; off += Bb * Cc;
  float* L_   = wsf + off; off += szL;
  float* regA = wsf + off; off += szRA;
  float* regB = wsf + off; off += szRB;
  const long long baseFloats = off;
  // tail region: G split-K partials, later aliased by zq (pixel-major [B][N][D])
  float* tail = wsf + off;
  const long long ZQ_F  = (long long)Bb * Dd * Nn;      // 9437184
  const long long tailFloats = (long long)(ws_size / 4) - baseFloats;
  const bool big = tailFloats >= ZQ_F;    // big: fp32 zq + splitK=4; small: bf16 zq + splitK=2
  const int numKS = big ? 4 : 2;          // partials: numKS*8*10*16384 floats (5.2M / 2.6M)
  float* part = tail;
  float* zqf  = tail;
  u16*   zqh  = (u16*)tail;
  float* R_   = L_;     // alias: f dead after Mm-GEMM; R born after P-GEMM
  float* zqb_ = u_;     // alias: u dead after softmax
  float* E8_  = regB;                       // 8*8*32*128 = 262144 floats (regB dead post-P)
  float* A8_  = regB + 262144;              // 8*8*32 = 2048 floats
  float* Es_  = regB + 264192;              // 8*128 = 1024 floats (merged memset region)
  (void)Eraw_; (void)Asum_; (void)EsL_;

  const long long strX = (long long)Cc * Nn;
  const long long sG = (long long)Cc * Cc;
  const long long sU = (long long)C1 * Cc;
  const long long sL = (long long)C1 * C1;
  const long long sR = (long long)Dd * Cc;

  // G = X X^T (symmetric): 128x64 tile-pair-half partials -> reduce into regA.
  // Diagonal jh==0 blocks also accumulate X row sums into s_ (rowsum fold).
  hipMemsetAsync(s_, 0, (size_t)(Bb * Cc) * 4, stream);
  gxxt_kernel<<<dim3(20 * numKS * Bb), 256, 0, stream>>>(X, part, numKS, Nn / numKS, s_);
  gred_kernel<<<dim3(10 * Bb), 256, 0, stream>>>(part, regA, numKS);
  // U = Wth @ G -> regB  (M=256 N=512 K=512)
  gemm_mfma<float, 0, false><<<dim3(64), 256, 0, stream>>>(
      Wth, regA, regB, Cc, Cc, 0, sG, sU, nullptr, 0, nullptr, 4, 2);
  gemv2_kernel<<<16, 256, 0, stream>>>(Wth, Wph, s_, u_, v_);
  // L = U @ Wph^T  (small, fp32)
  gemm64<true><<<dim3(4, 4, Bb), 256, 0, stream>>>(
      regB, Wph, L_, C1, C1, Cc, sU, 0, sL, nullptr, 0);
  softmax_kernel<<<Bb * C1, 256, 0, stream>>>(L_, bth, bph, u_, v_, bg, w_);
  // Mm = f @ Wg -> regB (U dead)  (M=256 N=512 K=256)
  gemm_mfma<float, 0, false><<<dim3(64), 256, 0, stream>>>(
      L_, Wg, regB, Cc, C1, sL, 0, sU, nullptr, 0, nullptr, 4, 2);
  q_kernel<<<16, 256, 0, stream>>>(W2, b2v, w_, q_);
  // P' = W2 @ Mm + I -> regA (G dead; identity fused in epilogue)
  gemm_mfma<float, 0, true><<<dim3(128), 256, 0, stream>>>(
      W2, regB, regA, Cc, C1, 0, sU, sG, nullptr, 0, nullptr, 4, 4);
  // regB dead: becomes 8-slot enc accumulators + Es (one merged memset)
  hipMemsetAsync(regB, 0, (size_t)(262144 + 2048 + 1024) * 4, stream);
  // R = W3 @ P' -> R_ (alias L_)  (M=128 N=512 K=512) ; zq bias = W3 q + b3
  gemm_mfma<float, 0, false><<<dim3(32), 256, 0, stream>>>(
      W3, regA, R_, Cc, Cc, 0, sG, sR, nullptr, 0, nullptr, 4, 1);
  zqbias_kernel<<<4, 256, 0, stream>>>(W3, b3v, q_, zqb_);
  // zq = R @ X + zqb, stored pixel-major [B][N][D]  (partials dead -> tail reused)
  if (big) {
    gemm_mfma<float, 1, false><<<dim3(576), 256, 0, stream>>>(
        R_, X, zqf, Nn, Cc, sR, strX, (long long)Dd * Nn, zqb_, Dd, nullptr, 72, 1);
    enc_kernel<float><<<dim3(36, Bb), 256, 0, stream>>>(zqf, CW, SC, E8_, A8_);
  } else {
    gemm_mfma<u16, 1, false><<<dim3(576), 256, 0, stream>>>(
        R_, X, zqh, Nn, Cc, sR, strX, (long long)Dd * Nn, zqb_, Dd, nullptr, 72, 1);
    enc_kernel<u16><<<dim3(36, Bb), 256, 0, stream>>>(zqh, CW, SC, E8_, A8_);
  }
  bn_kernel<<<Kk, 256, 0, stream>>>(E8_, A8_, CW, Es_);
  gamma_kernel<<<16, 256, 0, stream>>>(Es_, Wfc, bfc, gam_, q_);   // q <- q*gamma
  // z*gamma = (gamma.P') @ X + (gamma.q) -> out  (gamma applied in A-staging)
  gemm_mfma<float, 0, false><<<dim3(2304), 256, 0, stream>>>(
      regA, X, out, Nn, Cc, sG, strX, strX, q_, Cc, gam_, 72, 4);
  (void)in_sizes; (void)n_in; (void)out_size;
}

// Round 12
// 895.914 us; speedup vs baseline: 1.6265x; 1.0529x over previous
//
#include <hip/hip_runtime.h>

// NLCE: non-local (channel attention) + Deep-TEN encoding, B=8 C=512 C1=256 D=128 K=32 N=9216.
// All inputs/outputs fp32. Big GEMMs on matrix cores via 2-limb bf16 split
// (hi/lo via v_cvt_pk_bf16_f32; products hi*hi+hi*lo+lo*hi, ~1e-5 rel).
// Round 12: revert scaleA gamma-fold (cost +16us in z staging; round-10 "scaleP=134MB"
// was arithmetic error -- P' is 8.4 MB, scaleP ~4us). z-GEMM = round-9 config (157us).
// Rowsum fold now plain-stores per-ks slots (no atomics, no s_ memset).

typedef unsigned short u16;

#define Bb 8
#define Cc 512
#define C1 256
#define Dd 128
#define Kk 32
#define Nn 9216

typedef __attribute__((ext_vector_type(8))) short short8v;
typedef __attribute__((ext_vector_type(4))) short short4v;
typedef __attribute__((ext_vector_type(4))) float f32x4;

__device__ __forceinline__ float b2f(u16 u) {
  union { unsigned int i; float f; } v; v.i = ((unsigned int)u) << 16; return v.f;
}
__device__ __forceinline__ u16 f2b(float f) {
  union { float f; unsigned int i; } v; v.f = f;
  unsigned int x = v.i;
  return (u16)((x + 0x7fffu + ((x >> 16) & 1u)) >> 16);  // RNE
}

__device__ __forceinline__ float4 load4(const float* p) { return *(const float4*)p; }
__device__ __forceinline__ float4 load4(const u16* p) {
  ushort4 q = *(const ushort4*)p;
  return make_float4(b2f(q.x), b2f(q.y), b2f(q.z), b2f(q.w));
}
__device__ __forceinline__ void store4(float* p, float a, float b, float c, float d) {
  *(float4*)p = make_float4(a, b, c, d);
}

__device__ __forceinline__ float waveSum(float v) {
  #pragma unroll
  for (int o = 32; o > 0; o >>= 1) v += __shfl_xor(v, o);
  return v;
}
__device__ __forceinline__ float waveMax(float v) {
  #pragma unroll
  for (int o = 32; o > 0; o >>= 1) v = fmaxf(v, __shfl_xor(v, o));
  return v;
}
__device__ __forceinline__ float blockSum256(float v) {
  __shared__ float sm[4];
  v = waveSum(v);
  if ((threadIdx.x & 63) == 0) sm[threadIdx.x >> 6] = v;
  __syncthreads();
  float r = sm[0] + sm[1] + sm[2] + sm[3];
  __syncthreads();
  return r;
}
__device__ __forceinline__ float blockMax256(float v) {
  __shared__ float sm[4];
  v = waveMax(v);
  if ((threadIdx.x & 63) == 0) sm[threadIdx.x >> 6] = v;
  __syncthreads();
  float r = fmaxf(fmaxf(sm[0], sm[1]), fmaxf(sm[2], sm[3]));
  __syncthreads();
  return r;
}

// ---------------- MFMA split-bf16 common ----------------
__device__ __forceinline__ f32x4 mfma_bf16_16x16x32(short8v a, short8v b, f32x4 c) {
  asm("v_mfma_f32_16x16x32_bf16 %0, %1, %2, %0" : "+v"(c) : "v"(a), "v"(b));
  return c;
}

__device__ __forceinline__ int fsw(int r) { return (r ^ (r >> 2) ^ (r >> 4)) & 3; }

// 2 floats -> packed bf16 hi limbs (h) and lo limbs (l), 1 cvt_pk each + exact residual
__device__ __forceinline__ void cvt2(float x0, float x1, unsigned int& h, unsigned int& l) {
  asm("v_cvt_pk_bf16_f32 %0, %1, %2" : "=v"(h) : "v"(x0), "v"(x1));
  union { unsigned int u; float f; } fa, fb;
  fa.u = h << 16; fb.u = h & 0xffff0000u;
  float r0 = x0 - fa.f, r1 = x1 - fb.f;
  asm("v_cvt_pk_bf16_f32 %0, %1, %2" : "=v"(l) : "v"(r0), "v"(r1));
}

__device__ __forceinline__ void storeC4(float* p, float4 v) { *(float4*)p = v; }
__device__ __forceinline__ void storeC4(u16* p, float4 v) {
  ushort4 q; q.x = f2b(v.x); q.y = f2b(v.y); q.z = f2b(v.z); q.w = f2b(v.w);
  *(ushort4*)p = q;
}

// ---------------- generic MFMA GEMM (BN=128) ----------------
// C[b] = A[b] @ B[b]; fp32 in, TO out, 2-limb bf16 MFMA inside.
// BM = 128, BN = 128, BK = 32. 256 threads = 4 waves (2x2), wave tile 64x64.
// OMODE 0: row-major C[M][N], +biasRow[gr]; ADDI adds identity (gr==gc).
// OMODE 1: transposed C[N][128] (requires gny==1, M==128), +biasRow[d].
template<typename TO, int OMODE, bool ADDI>
__global__ __launch_bounds__(256, 3) void gemm_mfma(
    const float* __restrict__ A, const float* __restrict__ B, TO* __restrict__ C,
    int N, int K,
    long long sA, long long sB, long long sC,
    const float* __restrict__ biasRow, long long sBias,
    int gnx, int gny)
{
  // element (row,k) at column ((k>>3) ^ fsw(row))*8 + (k&7); stride 40 ushorts (80 B,
  // multiple of 16 -> b128-aligned frag reads).
  __shared__ __align__(16) u16 Asm_[2][128][40];
  __shared__ __align__(16) u16 Bsm_[2][128][40];

  int id = blockIdx.x;
  {
    const int nwg = gridDim.x;
    if ((nwg & 7) == 0) id = (id & 7) * (nwg >> 3) + (id >> 3);  // XCD chunk swizzle
  }
  const int per = gnx * gny;
  const int b = id / per;
  const int rem = id - b * per;
  const int by = rem % gny;        // m-block fastest
  const int bx = rem / gny;        // n-block
  A += b * sA; B += b * sB; C += b * sC;
  const int m0 = by * 128, n0 = bx * 128;

  const int t = threadIdx.x;
  const int w = t >> 6, lane = t & 63;
  const int wr = w >> 1, wc = w & 1;
  const int lr = lane & 15, lq = lane >> 4;

  const int sar = t >> 1, sak = (t & 1) * 16;   // A staging: 128 rows x 32 k
  const int kg2 = t >> 4, ng = t & 15;          // B staging: 2 k-rows x 8 n per thread

  float ra[16];
  float rb[16];

  auto loadA = [&](int k0) {
    const float* p = A + (long long)(m0 + sar) * K + (k0 + sak);
    #pragma unroll
    for (int i = 0; i < 4; ++i) {
      float4 v = *(const float4*)(p + i * 4);
      ra[i*4+0] = v.x; ra[i*4+1] = v.y; ra[i*4+2] = v.z; ra[i*4+3] = v.w;
    }
  };
  auto loadB = [&](int k0) {
    const float* p = B + (long long)(k0 + kg2 * 2) * N + (n0 + ng * 8);
    #pragma unroll
    for (int i = 0; i < 2; ++i) {
      float4 v0 = *(const float4*)(p + (long long)i * N);
      float4 v1 = *(const float4*)(p + (long long)i * N + 4);
      rb[i*8+0]=v0.x; rb[i*8+1]=v0.y; rb[i*8+2]=v0.z; rb[i*8+3]=v0.w;
      rb[i*8+4]=v1.x; rb[i*8+5]=v1.y; rb[i*8+6]=v1.z; rb[i*8+7]=v1.w;
    }
  };

  auto stage = [&]() {
    {   // A rows sar, k-local sak..sak+15 -> two swizzled 8-blocks
      const int f = fsw(sar);
      #pragma unroll
      for (int h = 0; h < 2; ++h) {
        const int col = ((((sak >> 3) + h) ^ f) << 3);
        union { unsigned int u[4]; short8v v; } H, L;
        #pragma unroll
        for (int p = 0; p < 4; ++p) cvt2(ra[h*8+2*p], ra[h*8+2*p+1], H.u[p], L.u[p]);
        *(short8v*)&Asm_[0][sar][col] = H.v;
        *(short8v*)&Asm_[1][sar][col] = L.v;
      }
    }
    {   // B: 2 consecutive k per n, one u32 write per limb per n
      const int blk = kg2 >> 2, sub = 2 * (kg2 & 3);
      #pragma unroll
      for (int j = 0; j < 8; ++j) {
        const int n = ng * 8 + j;
        const int col = ((blk ^ fsw(n)) << 3) + sub;
        unsigned int H, L;
        cvt2(rb[j], rb[8 + j], H, L);
        *(unsigned int*)&Bsm_[0][n][col] = H;
        *(unsigned int*)&Bsm_[1][n][col] = L;
      }
    }
  };

  f32x4 acc[4][4];
  #pragma unroll
  for (int im = 0; im < 4; ++im)
    #pragma unroll
    for (int in = 0; in < 4; ++in)
      acc[im][in] = f32x4{0.f, 0.f, 0.f, 0.f};

  loadA(0); loadB(0);
  for (int k0 = 0; k0 < K; k0 += 32) {
    stage();
    if (k0 + 32 < K) { loadA(k0 + 32); loadB(k0 + 32); }
    __syncthreads();
    short8v af[2][4];
    #pragma unroll
    for (int im = 0; im < 4; ++im) {
      const int r = wr * 64 + im * 16 + lr;
      const int col = ((lq ^ fsw(r)) << 3);
      af[0][im] = *(const short8v*)&Asm_[0][r][col];
      af[1][im] = *(const short8v*)&Asm_[1][r][col];
    }
    #pragma unroll
    for (int in = 0; in < 4; ++in) {
      const int rB = wc * 64 + in * 16 + lr;
      const int colB = ((lq ^ fsw(rB)) << 3);
      short8v bh = *(const short8v*)&Bsm_[0][rB][colB];
      short8v bl = *(const short8v*)&Bsm_[1][rB][colB];
      #pragma unroll
      for (int im = 0; im < 4; ++im) {
        acc[im][in] = mfma_bf16_16x16x32(af[0][im], bh, acc[im][in]);  // hi*hi
        acc[im][in] = mfma_bf16_16x16x32(af[0][im], bl, acc[im][in]);  // hi*lo
        acc[im][in] = mfma_bf16_16x16x32(af[1][im], bh, acc[im][in]);  // lo*hi
      }
    }
    __syncthreads();
  }
  asm volatile("s_nop 7\n\ts_nop 7\n\ts_nop 7");  // MFMA->VALU/VMEM read hazard guard

  if constexpr (OMODE == 1) {
    // transposed store: C[n][128]; d = wr*64+im*16+lq*4+{0..3} contiguous per lane
    const float* bb = biasRow + (long long)b * sBias;
    #pragma unroll
    for (int im = 0; im < 4; ++im) {
      #pragma unroll
      for (int in = 0; in < 4; ++in) {
        const f32x4 a = acc[im][in];
        const int gc = n0 + wc * 64 + in * 16 + lr;
        const int d0b = wr * 64 + im * 16 + lq * 4;
        float4 v = make_float4(a[0] + bb[d0b + 0], a[1] + bb[d0b + 1],
                               a[2] + bb[d0b + 2], a[3] + bb[d0b + 3]);
        storeC4(&C[(long long)gc * Dd + d0b], v);
      }
    }
  } else {
    #pragma unroll
    for (int im = 0; im < 4; ++im) {
      #pragma unroll
      for (int in = 0; in < 4; ++in) {
        const f32x4 a = acc[im][in];
        const int gc = n0 + wc * 64 + in * 16 + lr;   // C/D: col = lane&15
        #pragma unroll
        for (int p = 0; p < 4; ++p) {
          const int gr = m0 + wr * 64 + im * 16 + lq * 4 + p;  // row = (lane>>4)*4+reg
          float v = a[p];
          if (biasRow) v += biasRow[b * sBias + gr];
          if (ADDI && gr == gc) v += 1.f;
          C[(long long)gr * N + gc] = v;
        }
      }
    }
  }
}

// ---------------- G = X X^T, symmetric, split-K partials (no atomics) --------
// 128x64 blocks: pair selects (i-tile, j-tile), jh selects column half of j-tile.
// Diag/jh==0 blocks also plain-store per-ks X row sums into sP[ks][b][row].
__device__ __constant__ int PIa[10] = {0,0,0,0,1,1,1,2,2,3};
__device__ __constant__ int PJa[10] = {0,1,2,3,1,2,3,2,3,3};

__global__ __launch_bounds__(256, 3) void gxxt_kernel(
    const float* __restrict__ X, float* __restrict__ part,
    int numKS, int kChunk, float* __restrict__ sP)
{
  __shared__ __align__(16) u16 Asm_[2][128][40];
  __shared__ __align__(16) u16 Bsm_[2][64][40];

  int id = blockIdx.x;
  {
    const int nwg = gridDim.x;
    if ((nwg & 7) == 0) id = (id & 7) * (nwg >> 3) + (id >> 3);  // one batch per XCD
  }
  const int sub = id % 20;
  const int pair = sub >> 1, jh = sub & 1;
  const int rest = id / 20;
  const int ks = rest % numKS;
  const int b = rest / numKS;
  const int i0 = PIa[pair] * 128, j0 = PJa[pair] * 128;
  const bool same = (i0 == j0);
  const bool doSum = same && (jh == 0);
  const float* Xb = X + (long long)b * Cc * Nn;
  const int kBeg = ks * kChunk, kEnd = kBeg + kChunk;

  const int t = threadIdx.x;
  const int w = t >> 6, lane = t & 63;
  const int wr = w >> 1, wc = w & 1;
  const int lr = lane & 15, lq = lane >> 4;
  const int sar = t >> 1, sak = (t & 1) * 16;   // A: 128 rows x 32 k
  const int sbr = t >> 2, sbk = (t & 3) * 8;    // B: 64 rows x 32 k (8 k per thread)

  float ra[16], rb[8];
  float rs = 0.f;

  auto loadA = [&](int k0) {
    const float* p = Xb + (long long)(i0 + sar) * Nn + (k0 + sak);
    #pragma unroll
    for (int i = 0; i < 4; ++i) {
      float4 v = *(const float4*)(p + i * 4);
      ra[i*4+0] = v.x; ra[i*4+1] = v.y; ra[i*4+2] = v.z; ra[i*4+3] = v.w;
    }
  };
  auto loadB = [&](int k0) {
    const float* p = Xb + (long long)(j0 + jh * 64 + sbr) * Nn + (k0 + sbk);
    float4 v0 = *(const float4*)(p);
    float4 v1 = *(const float4*)(p + 4);
    rb[0]=v0.x; rb[1]=v0.y; rb[2]=v0.z; rb[3]=v0.w;
    rb[4]=v1.x; rb[5]=v1.y; rb[6]=v1.z; rb[7]=v1.w;
  };
  auto stageA = [&]() {
    const int f = fsw(sar);
    #pragma unroll
    for (int h = 0; h < 2; ++h) {
      const int col = ((((sak >> 3) + h) ^ f) << 3);
      union { unsigned int u[4]; short8v v; } Hv, Lv;
      #pragma unroll
      for (int p = 0; p < 4; ++p) cvt2(ra[h*8+2*p], ra[h*8+2*p+1], Hv.u[p], Lv.u[p]);
      *(short8v*)&Asm_[0][sar][col] = Hv.v;
      *(short8v*)&Asm_[1][sar][col] = Lv.v;
    }
  };
  auto stageB = [&]() {
    const int col = (((sbk >> 3) ^ fsw(sbr)) << 3);
    union { unsigned int u[4]; short8v v; } Hv, Lv;
    #pragma unroll
    for (int p = 0; p < 4; ++p) cvt2(rb[2*p], rb[2*p+1], Hv.u[p], Lv.u[p]);
    *(short8v*)&Bsm_[0][sbr][col] = Hv.v;
    *(short8v*)&Bsm_[1][sbr][col] = Lv.v;
  };

  f32x4 acc[4][2];
  #pragma unroll
  for (int im = 0; im < 4; ++im)
    #pragma unroll
    for (int in = 0; in < 2; ++in)
      acc[im][in] = f32x4{0.f, 0.f, 0.f, 0.f};

  loadA(kBeg);
  if (!same) loadB(kBeg);
  for (int k0 = kBeg; k0 < kEnd; k0 += 32) {
    if (doSum) {
      #pragma unroll
      for (int j = 0; j < 16; ++j) rs += ra[j];
    }
    stageA();
    if (!same) stageB();
    if (k0 + 32 < kEnd) { loadA(k0 + 32); if (!same) loadB(k0 + 32); }
    __syncthreads();
    short8v af[2][4];
    #pragma unroll
    for (int im = 0; im < 4; ++im) {
      const int r = wr * 64 + im * 16 + lr;
      const int col = ((lq ^ fsw(r)) << 3);
      af[0][im] = *(const short8v*)&Asm_[0][r][col];
      af[1][im] = *(const short8v*)&Asm_[1][r][col];
    }
    #pragma unroll
    for (int in = 0; in < 2; ++in) {
      const int rloc = wc * 32 + in * 16 + lr;
      short8v bh, bl;
      if (same) {
        const int r = jh * 64 + rloc;
        const int colB = ((lq ^ fsw(r)) << 3);
        bh = *(const short8v*)&Asm_[0][r][colB];
        bl = *(const short8v*)&Asm_[1][r][colB];
      } else {
        const int colB = ((lq ^ fsw(rloc)) << 3);
        bh = *(const short8v*)&Bsm_[0][rloc][colB];
        bl = *(const short8v*)&Bsm_[1][rloc][colB];
      }
      #pragma unroll
      for (int im = 0; im < 4; ++im) {
        acc[im][in] = mfma_bf16_16x16x32(af[0][im], bh, acc[im][in]);
        acc[im][in] = mfma_bf16_16x16x32(af[0][im], bl, acc[im][in]);
        acc[im][in] = mfma_bf16_16x16x32(af[1][im], bh, acc[im][in]);
      }
    }
    __syncthreads();
  }
  asm volatile("s_nop 7\n\ts_nop 7\n\ts_nop 7");

  if (doSum) sP[((long long)ks * Bb + b) * Cc + i0 + sar] = rs;  // written once per row

  float* Cp = part + ((long long)(ks * Bb + b) * 10 + pair) * 16384 + jh * 64;
  #pragma unroll
  for (int im = 0; im < 4; ++im) {
    #pragma unroll
    for (int in = 0; in < 2; ++in) {
      const f32x4 a = acc[im][in];
      const int gc = wc * 32 + in * 16 + lr;
      #pragma unroll
      for (int p = 0; p < 4; ++p) {
        const int gr = wr * 64 + im * 16 + lq * 4 + p;
        Cp[gr * 128 + gc] = a[p];
      }
    }
  }
}

// Reduce partials -> G (both triangles). One block per (b, pair).
__global__ __launch_bounds__(256) void gred_kernel(const float* __restrict__ part,
    float* __restrict__ G, int numKS) {
  __shared__ float sm[64][129];
  const int pair = blockIdx.x % 10, b = blockIdx.x / 10;
  const int i0 = PIa[pair] * 128, j0 = PJa[pair] * 128;
  float* Gb = G + (long long)b * Cc * Cc;
  const long long ksStr = (long long)Bb * 10 * 16384;
  const float* p0 = part + ((long long)b * 10 + pair) * 16384;
  const int t = threadIdx.x;
  for (int half = 0; half < 2; ++half) {
    const int r0 = half * 64;
    __syncthreads();
    for (int rep = 0; rep < 32; ++rep) {
      int idx = r0 * 128 + rep * 256 + t;
      float s = 0.f;
      for (int ks = 0; ks < numKS; ++ks) s += p0[(long long)ks * ksStr + idx];
      int r = (idx >> 7) - r0, c = idx & 127;
      sm[r][c] = s;
      Gb[(long long)(i0 + r0 + r) * Cc + (j0 + c)] = s;
    }
    if (i0 != j0) {
      __syncthreads();
      for (int rep = 0; rep < 32; ++rep) {
        int o = rep * 256 + t;
        int rr = o >> 6, cc = o & 63;
        Gb[(long long)(j0 + rr) * Cc + (i0 + r0 + cc)] = sm[cc][rr];
      }
    }
  }
}

// ---------------- generic 64x64 tiled GEMM, fp32 (L only) ----------------
template<bool TRANSB>
__global__ __launch_bounds__(256) void gemm64(
    const float* __restrict__ A, const float* __restrict__ B, float* __restrict__ C,
    int M, int N, int K,
    long long sA, long long sB, long long sC,
    const float* __restrict__ biasRow, long long sBias)
{
  const int bz = blockIdx.z;
  A += (long long)bz * sA;
  B += (long long)bz * sB;
  C += (long long)bz * sC;
  const int m0 = blockIdx.y * 64, n0 = blockIdx.x * 64;
  __shared__ __align__(16) float As[16][64];
  __shared__ __align__(16) float Bs[16][64];
  const int t = threadIdx.x;
  const int lr = t >> 2, lk = (t & 3) << 2;
  const int tm = (t >> 4) << 2, tn = (t & 15) << 2;
  float acc[4][4] = {};
  for (int k0 = 0; k0 < K; k0 += 16) {
    {
      float4 a = load4(A + (long long)(m0 + lr) * K + (k0 + lk));
      As[lk + 0][lr] = a.x; As[lk + 1][lr] = a.y; As[lk + 2][lr] = a.z; As[lk + 3][lr] = a.w;
    }
    if (TRANSB) {
      float4 b = load4(B + (long long)(n0 + lr) * K + (k0 + lk));
      Bs[lk + 0][lr] = b.x; Bs[lk + 1][lr] = b.y; Bs[lk + 2][lr] = b.z; Bs[lk + 3][lr] = b.w;
    } else {
      const int kr = t >> 4, nc = (t & 15) << 2;
      float4 b = load4(B + (long long)(k0 + kr) * N + (n0 + nc));
      *(float4*)&Bs[kr][nc] = b;
    }
    __syncthreads();
    #pragma unroll
    for (int kk = 0; kk < 16; ++kk) {
      const float4 av = *(const float4*)&As[kk][tm];
      const float4 bv = *(const float4*)&Bs[kk][tn];
      acc[0][0] = fmaf(av.x, bv.x, acc[0][0]);
      acc[0][1] = fmaf(av.x, bv.y, acc[0][1]);
      acc[0][2] = fmaf(av.x, bv.z, acc[0][2]);
      acc[0][3] = fmaf(av.x, bv.w, acc[0][3]);
      acc[1][0] = fmaf(av.y, bv.x, acc[1][0]);
      acc[1][1] = fmaf(av.y, bv.y, acc[1][1]);
      acc[1][2] = fmaf(av.y, bv.z, acc[1][2]);
      acc[1][3] = fmaf(av.y, bv.w, acc[1][3]);
      acc[2][0] = fmaf(av.z, bv.x, acc[2][0]);
      acc[2][1] = fmaf(av.z, bv.y, acc[2][1]);
      acc[2][2] = fmaf(av.z, bv.z, acc[2][2]);
      acc[2][3] = fmaf(av.z, bv.w, acc[2][3]);
      acc[3][0] = fmaf(av.w, bv.x, acc[3][0]);
      acc[3][1] = fmaf(av.w, bv.y, acc[3][1]);
      acc[3][2] = fmaf(av.w, bv.z, acc[3][2]);
      acc[3][3] = fmaf(av.w, bv.w, acc[3][3]);
    }
    __syncthreads();
  }
  #pragma unroll
  for (int i = 0; i < 4; ++i) {
    const int m = m0 + tm + i;
    float bias = biasRow ? biasRow[bz * sBias + m] : 0.f;
    store4(C + (long long)m * N + (n0 + tn),
           acc[i][0] + bias, acc[i][1] + bias, acc[i][2] + bias, acc[i][3] + bias);
  }
}

// ---------------- small kernels ----------------
// u[b,i] = sum Wth[i,:]*s[b,:]  (sel 0), v[b,i] = sum Wph[i,:]*s[b,:] (sel 1)
// s reconstructed by summing numKS plain-stored slots sP[ks][b][:].
__global__ __launch_bounds__(256) void gemv2_kernel(const float* __restrict__ Wth,
    const float* __restrict__ Wph, const float* __restrict__ sP, int numKS,
    float* __restrict__ u, float* __restrict__ v) {
  int b = blockIdx.x & 7, sel = blockIdx.x >> 3;
  const float* W = sel ? Wph : Wth;
  float* out = sel ? v : u;
  __shared__ float ssm[Cc];
  for (int i = threadIdx.x; i < Cc; i += 256) {
    float s = 0.f;
    for (int ks = 0; ks < numKS; ++ks) s += sP[((long long)ks * Bb + b) * Cc + i];
    ssm[i] = s;
  }
  __syncthreads();
  int i = threadIdx.x;
  const float* wr = W + i * Cc;
  float acc = 0.f;
  for (int k = 0; k < Cc; ++k) acc = fmaf(wr[k], ssm[k], acc);
  out[b * C1 + i] = acc;
}

// softmax over rows of L with bias terms; also emits w[b,i] = sum_j f * bg[j]
__global__ __launch_bounds__(256) void softmax_kernel(float* __restrict__ L,
    const float* __restrict__ bth, const float* __restrict__ bph,
    const float* __restrict__ u, const float* __restrict__ v,
    const float* __restrict__ bg, float* __restrict__ w) {
  __shared__ float bgs[C1];
  int row = blockIdx.x;                 // b*256 + i
  int b = row >> 8, i = row & 255;
  int j = threadIdx.x;
  bgs[j] = bg[j];
  float bt = bth[i], bp = bph[j];
  long long idx = (long long)row * C1 + j;
  float val = L[idx] + bt * v[b * C1 + j] + u[b * C1 + i] * bp + (float)Nn * bt * bp;
  float mx = blockMax256(val);
  float p = expf(val - mx);
  float sm = blockSum256(p);
  float f = p / sm;
  L[idx] = f;
  float ws = blockSum256(f * bgs[j]);
  if (j == 0) w[row] = ws;
}

__global__ __launch_bounds__(256) void q_kernel(const float* __restrict__ W2,
                                                const float* __restrict__ b2v,
                                                const float* __restrict__ w,
                                                float* __restrict__ q) {
  int gi = blockIdx.x * 256 + threadIdx.x;
  int b = gi >> 9, c = gi & 511;
  __shared__ float wsm[C1];
  wsm[threadIdx.x] = w[b * C1 + threadIdx.x];
  __syncthreads();
  const float* wr = W2 + c * C1;
  float acc = b2v[c];
  for (int i = 0; i < C1; ++i) acc = fmaf(wr[i], wsm[i], acc);
  q[gi] = acc;
}

// zqb[b][d] = b3[d] + sum_c W3[d][c] * q[b][c]
__global__ __launch_bounds__(256) void zqbias_kernel(const float* __restrict__ W3,
    const float* __restrict__ b3, const float* __restrict__ q, float* __restrict__ zqb) {
  int gi = blockIdx.x * 256 + threadIdx.x;   // [0, 1024)
  int b = gi >> 7, d = gi & 127;
  const float* wr = W3 + d * Cc;
  const float* qr = q + b * Cc;
  float acc = b3[d];
  for (int c = 0; c < Cc; ++c) acc = fmaf(wr[c], qr[c], acc);
  zqb[gi] = acc;
}

// Deep-TEN soft-assign + aggregation. zq is PIXEL-MAJOR [B][N][D].
// Eraw8/Asum8: 8-slot replicated accumulators (slot = n-tile & 7) to cut atomic contention.
template<typename ZT>
__global__ __launch_bounds__(256) void enc_kernel(
    const ZT* __restrict__ zq,      // [B][N][D]
    const float* __restrict__ cw,   // [K][D]
    const float* __restrict__ sc,   // [K]
    float* __restrict__ Eraw8,      // [8][B][K][D] pre-zeroed
    float* __restrict__ Asum8)      // [8][B][K]    pre-zeroed
{
  __shared__ float csm[Kk][Dd + 1];
  __shared__ float cc[Kk], ssm[Kk];
  __shared__ float sA[Kk][256 + 1];
  __shared__ float zs[16][Dd + 4];
  const int tid = threadIdx.x;
  const int b = blockIdx.y;
  const int slot = blockIdx.x & 7;
  const int n0 = blockIdx.x * 256;

  #pragma unroll
  for (int r = 0; r < 16; ++r) {
    int idx = r * 256 + tid;
    csm[idx >> 7][idx & 127] = cw[idx];
  }
  if (tid < Kk) ssm[tid] = sc[tid];
  __syncthreads();
  if (tid < Kk) {
    float a = 0.f;
    for (int d = 0; d < Dd; ++d) { float cv = csm[tid][d]; a = fmaf(cv, cv, a); }
    cc[tid] = a;
  }
  __syncthreads();

  // pass 1: one pixel per thread, contiguous row read
  const ZT* zrow = zq + ((long long)b * Nn + n0 + tid) * Dd;
  float dots[Kk];
  #pragma unroll
  for (int k = 0; k < Kk; ++k) dots[k] = 0.f;
  float xx = 0.f;
  for (int d = 0; d < Dd; d += 4) {
    float4 xv = load4(zrow + d);
    xx = fmaf(xv.x, xv.x, xx); xx = fmaf(xv.y, xv.y, xx);
    xx = fmaf(xv.z, xv.z, xx); xx = fmaf(xv.w, xv.w, xx);
    #pragma unroll
    for (int k = 0; k < Kk; ++k) {
      float dk = dots[k];
      dk = fmaf(csm[k][d + 0], xv.x, dk);
      dk = fmaf(csm[k][d + 1], xv.y, dk);
      dk = fmaf(csm[k][d + 2], xv.z, dk);
      dk = fmaf(csm[k][d + 3], xv.w, dk);
      dots[k] = dk;
    }
  }
  float mx = -1e30f;
  #pragma unroll
  for (int k = 0; k < Kk; ++k) {
    float l = ssm[k] * (xx - 2.f * dots[k] + cc[k]);
    dots[k] = l;
    mx = fmaxf(mx, l);
  }
  float sum = 0.f;
  #pragma unroll
  for (int k = 0; k < Kk; ++k) { float p = expf(dots[k] - mx); dots[k] = p; sum += p; }
  float inv = 1.f / sum;
  #pragma unroll
  for (int k = 0; k < Kk; ++k) sA[k][tid] = dots[k] * inv;
  __syncthreads();
  if (tid < Kk) {
    float s = 0.f;
    for (int p = 0; p < 256; ++p) s += sA[tid][p];
    atomicAdd(&Asum8[((long long)slot * Bb + b) * Kk + tid], s);
  }

  // pass 2: E_part[k][d0..d0+15] over this tile's 256 pixels (16 px per stage)
  float acc[16];
  #pragma unroll
  for (int j = 0; j < 16; ++j) acc[j] = 0.f;
  const int k = tid & 31, d0 = (tid >> 5) * 16;
  const int spx = tid >> 4, sd = (tid & 15) * 8;   // staging: 16 px x 128 d, coalesced
  for (int it = 0; it < 16; ++it) {
    __syncthreads();
    {
      const ZT* src = zq + ((long long)b * Nn + n0 + it * 16 + spx) * Dd + sd;
      float4 a4 = load4(src);
      float4 b4 = load4(src + 4);
      *(float4*)&zs[spx][sd] = a4;
      *(float4*)&zs[spx][sd + 4] = b4;
    }
    __syncthreads();
    #pragma unroll
    for (int p = 0; p < 16; ++p) {
      float a = sA[k][it * 16 + p];
      #pragma unroll
      for (int j = 0; j < 16; ++j) acc[j] = fmaf(a, zs[p][d0 + j], acc[j]);
    }
  }
  float* Ep = Eraw8 + (((long long)slot * Bb + b) * Kk + k) * Dd + d0;
  #pragma unroll
  for (int j = 0; j < 16; ++j) atomicAdd(Ep + j, acc[j]);
}

// per-k BN over (b,d) with 8-slot reduction, relu, Es[b,d] += e
__global__ __launch_bounds__(256) void bn_kernel(const float* __restrict__ Eraw8,
    const float* __restrict__ Asum8, const float* __restrict__ cw, float* __restrict__ Es) {
  __shared__ float sas[8];
  int k = blockIdx.x, tid = threadIdx.x;
  if (tid < 8) {
    float a = 0.f;
    for (int sl = 0; sl < 8; ++sl) a += Asum8[((long long)sl * Bb + tid) * Kk + k];
    sas[tid] = a;
  }
  __syncthreads();
  float vals[4], s = 0.f, s2 = 0.f;
  #pragma unroll
  for (int r = 0; r < 4; ++r) {
    int i = r * 256 + tid;
    int b = i >> 7, d = i & 127;
    float e = 0.f;
    for (int sl = 0; sl < 8; ++sl)
      e += Eraw8[(((long long)sl * Bb + b) * Kk + k) * Dd + d];
    e -= sas[b] * cw[k * Dd + d];
    vals[r] = e; s += e; s2 = fmaf(e, e, s2);
  }
  s = blockSum256(s);
  s2 = blockSum256(s2);
  float mean = s * (1.f / 1024.f);
  float var = fmaxf(s2 * (1.f / 1024.f) - mean * mean, 0.f);
  float rs = rsqrtf(var + 1e-5f);
  #pragma unroll
  for (int r = 0; r < 4; ++r) {
    int i = r * 256 + tid;
    int b = i >> 7, d = i & 127;
    float e = (vals[r] - mean) * rs;
    if (e > 0.f) atomicAdd(&Es[b * Dd + d], e);
  }
}

// gamma = sigmoid(Es @ Wfc^T + bfc); also folds gamma into q (q <- q*gamma)
__global__ __launch_bounds__(256) void gamma_kernel(const float* __restrict__ Es,
    const float* __restrict__ Wfc, const float* __restrict__ bfc,
    float* __restrict__ gam, float* __restrict__ q) {
  int gi = blockIdx.x * 256 + threadIdx.x;
  int b = gi >> 9, c = gi & 511;
  __shared__ float esm[Dd];
  if (threadIdx.x < Dd) esm[threadIdx.x] = Es[b * Dd + threadIdx.x];
  __syncthreads();
  const float* wr = Wfc + c * Dd;
  float acc = bfc[c];
  for (int d = 0; d < Dd; ++d) acc = fmaf(wr[d], esm[d], acc);
  float g = 1.f / (1.f + expf(-acc));
  gam[gi] = g;
  q[gi] *= g;
}

// P[b][c][:] *= gam[b][c]  (fold output scale into the GEMM A-operand; 8.4 MB total)
__global__ __launch_bounds__(256) void scaleP_kernel(float* __restrict__ P,
    const float* __restrict__ gam) {
  long long f = ((long long)blockIdx.x * 256 + threadIdx.x) * 4;  // 8*512*512 total
  int b = (int)(f >> 18), c = (int)((f >> 9) & 511);
  float g = gam[b * Cc + c];
  float4 v = *(const float4*)(P + f);
  store4(P + f, v.x * g, v.y * g, v.z * g, v.w * g);
}

// ---------------- host launcher ----------------
extern "C" void kernel_launch(void* const* d_in, const int* in_sizes, int n_in,
                              void* d_out, int out_size, void* d_ws, size_t ws_size,
                              hipStream_t stream) {
  const float* X   = (const float*)d_in[0];
  const float* Wth = (const float*)d_in[1];
  const float* bth = (const float*)d_in[2];
  const float* Wph = (const float*)d_in[3];
  const float* bph = (const float*)d_in[4];
  const float* Wg  = (const float*)d_in[5];
  const float* bg  = (const float*)d_in[6];
  const float* W2  = (const float*)d_in[7];
  const float* b2v = (const float*)d_in[8];
  const float* W3  = (const float*)d_in[9];
  const float* b3v = (const float*)d_in[10];
  const float* CW  = (const float*)d_in[11];
  const float* SC  = (const float*)d_in[12];
  const float* Wfc = (const float*)d_in[13];
  const float* bfc = (const float*)d_in[14];
  float* out = (float*)d_out;
  float* wsf = (float*)d_ws;

  const long long szL   = (long long)Bb * C1 * C1;   // 524288
  const long long szRA  = (long long)Bb * Cc * Cc;   // 2097152
  const long long szRB  = (long long)Bb * C1 * Cc;   // 1048576
  long long off = 0;
  float* s_   = wsf + off; off += Bb * Cc;                   // legacy (unused)
  float* u_   = wsf + off; off += Bb * C1;
  float* v_   = wsf + off; off += Bb * C1;
  float* w_   = wsf + off; off += Bb * C1;
  float* q_   = wsf + off; off += Bb * Cc;
  float* sP_  = wsf + off; off += (long long)Bb * Kk * Dd;   // 32768 floats: rowsum slots
  float* EsL_ = wsf + off; off += Bb * Dd;                   // legacy slot (unused)
  float* Asum_= wsf + off; off += Bb * Kk;                   // legacy slot (unused)
  float* gam_ = wsf + off; off += Bb * Cc;
  float* L_   = wsf + off; off += szL;
  float* regA = wsf + off; off += szRA;
  float* regB = wsf + off; off += szRB;
  const long long baseFloats = off;
  // tail region: G split-K partials, later aliased by zq (pixel-major [B][N][D])
  float* tail = wsf + off;
  const long long ZQ_F  = (long long)Bb * Dd * Nn;      // 9437184
  const long long tailFloats = (long long)(ws_size / 4) - baseFloats;
  const bool big = tailFloats >= ZQ_F;    // big: fp32 zq + splitK=4; small: bf16 zq + splitK=2
  const int numKS = big ? 4 : 2;          // partials: numKS*8*10*16384 floats (5.2M / 2.6M)
  float* part = tail;
  float* zqf  = tail;
  u16*   zqh  = (u16*)tail;
  float* R_   = L_;     // alias: f dead after Mm-GEMM; R born after P-GEMM
  float* zqb_ = u_;     // alias: u dead after softmax
  float* E8_  = regB;                       // 8*8*32*128 = 262144 floats (regB dead post-P)
  float* A8_  = regB + 262144;              // 8*8*32 = 2048 floats
  float* Es_  = regB + 264192;              // 8*128 = 1024 floats (merged memset region)
  (void)s_; (void)Asum_; (void)EsL_;

  const long long strX = (long long)Cc * Nn;
  const long long sG = (long long)Cc * Cc;
  const long long sU = (long long)C1 * Cc;
  const long long sL = (long long)C1 * C1;
  const long long sR = (long long)Dd * Cc;

  // G = X X^T (symmetric): 128x64 tile-pair-half partials -> reduce into regA.
  // Diagonal jh==0 blocks plain-store per-ks X row sums into sP_ (no memset needed).
  gxxt_kernel<<<dim3(20 * numKS * Bb), 256, 0, stream>>>(X, part, numKS, Nn / numKS, sP_);
  gred_kernel<<<dim3(10 * Bb), 256, 0, stream>>>(part, regA, numKS);
  // U = Wth @ G -> regB  (M=256 N=512 K=512)
  gemm_mfma<float, 0, false><<<dim3(64), 256, 0, stream>>>(
      Wth, regA, regB, Cc, Cc, 0, sG, sU, nullptr, 0, 4, 2);
  gemv2_kernel<<<16, 256, 0, stream>>>(Wth, Wph, sP_, numKS, u_, v_);
  // L = U @ Wph^T  (small, fp32)
  gemm64<true><<<dim3(4, 4, Bb), 256, 0, stream>>>(
      regB, Wph, L_, C1, C1, Cc, sU, 0, sL, nullptr, 0);
  softmax_kernel<<<Bb * C1, 256, 0, stream>>>(L_, bth, bph, u_, v_, bg, w_);
  // Mm = f @ Wg -> regB (U dead)  (M=256 N=512 K=256)
  gemm_mfma<float, 0, false><<<dim3(64), 256, 0, stream>>>(
      L_, Wg, regB, Cc, C1, sL, 0, sU, nullptr, 0, 4, 2);
  q_kernel<<<16, 256, 0, stream>>>(W2, b2v, w_, q_);
  // P' = W2 @ Mm + I -> regA (G dead; identity fused in epilogue)
  gemm_mfma<float, 0, true><<<dim3(128), 256, 0, stream>>>(
      W2, regB, regA, Cc, C1, 0, sU, sG, nullptr, 0, 4, 4);
  // regB dead: becomes 8-slot enc accumulators + Es (one merged memset)
  hipMemsetAsync(regB, 0, (size_t)(262144 + 2048 + 1024) * 4, stream);
  // R = W3 @ P' -> R_ (alias L_)  (M=128 N=512 K=512) ; zq bias = W3 q + b3
  gemm_mfma<float, 0, false><<<dim3(32), 256, 0, stream>>>(
      W3, regA, R_, Cc, Cc, 0, sG, sR, nullptr, 0, 4, 1);
  zqbias_kernel<<<4, 256, 0, stream>>>(W3, b3v, q_, zqb_);
  // zq = R @ X + zqb, stored pixel-major [B][N][D]  (partials dead -> tail reused)
  if (big) {
    gemm_mfma<float, 1, false><<<dim3(576), 256, 0, stream>>>(
        R_, X, zqf, Nn, Cc, sR, strX, (long long)Dd * Nn, zqb_, Dd, 72, 1);
    enc_kernel<float><<<dim3(36, Bb), 256, 0, stream>>>(zqf, CW, SC, E8_, A8_);
  } else {
    gemm_mfma<u16, 1, false><<<dim3(576), 256, 0, stream>>>(
        R_, X, zqh, Nn, Cc, sR, strX, (long long)Dd * Nn, zqb_, Dd, 72, 1);
    enc_kernel<u16><<<dim3(36, Bb), 256, 0, stream>>>(zqh, CW, SC, E8_, A8_);
  }
  bn_kernel<<<Kk, 256, 0, stream>>>(E8_, A8_, CW, Es_);
  gamma_kernel<<<16, 256, 0, stream>>>(Es_, Wfc, bfc, gam_, q_);   // q <- q*gamma
  // fold gamma into P' rows (8.4 MB, ~4us), then z*gamma = (gamma.P') @ X + (gamma.q)
  scaleP_kernel<<<2048, 256, 0, stream>>>(regA, gam_);
  gemm_mfma<float, 0, false><<<dim3(2304), 256, 0, stream>>>(
      regA, X, out, Nn, Cc, sG, strX, strX, q_, Cc, 72, 4);
  (void)in_sizes; (void)n_in; (void)out_size;
}